// Round 4
// baseline (613.485 us; speedup 1.0000x reference)
//
#include <hip/hip_runtime.h>
#include <hip/hip_bf16.h>

// Problem: b=2, s=4096, d_model=512, heads=8, d_head=64.
// Inputs/outputs FLOAT32; internal compute bf16 MFMA.
// Attention uses split-KV (flash-decode style): chunks of 16 KV-tiles (1024 p)
// produce partial (m, l, Z) merged by a combine kernel.

typedef __attribute__((ext_vector_type(4))) float  f32x4;
typedef __attribute__((ext_vector_type(8))) __bf16 bf16x8;
typedef __attribute__((ext_vector_type(8))) unsigned short u16x8;

#define MFMA16(a, b, c) __builtin_amdgcn_mfma_f32_16x16x32_bf16((a), (b), (c), 0, 0, 0)

#define SLOTS_PER_BH 160   // sum over qt of ceil((qt+1)/16), qt=0..63

static __device__ __forceinline__ bf16x8 ld8(const __hip_bfloat16* p) {
    return *reinterpret_cast<const bf16x8*>(p);
}
static __device__ __forceinline__ __hip_bfloat16 tobf(float f) {
    return __float2bfloat16(f);
}

// compact slot index for (bh, qt, chunk c): offset(qt) = qt + 8a(a-1) + a*b
static __device__ __forceinline__ int slot_of(int bh, int qt, int c) {
    const int a = qt >> 4, b = qt & 15;
    return bh * SLOTS_PER_BH + qt + 8 * a * (a - 1) + a * b + c;
}

// ---------------------------------------------------------------------------
// Cast kernel: float32 -> bf16, 8 elements per thread.
// ---------------------------------------------------------------------------
__global__ __launch_bounds__(256) void cast_f32_bf16(
    const float* __restrict__ in, __hip_bfloat16* __restrict__ out, int n8)
{
    const int i = blockIdx.x * 256 + threadIdx.x;
    if (i >= n8) return;
    const float4 a = *reinterpret_cast<const float4*>(in + (size_t)i * 8);
    const float4 b = *reinterpret_cast<const float4*>(in + (size_t)i * 8 + 4);
    u16x8 o;
    o[0] = __bfloat16_as_ushort(tobf(a.x));
    o[1] = __bfloat16_as_ushort(tobf(a.y));
    o[2] = __bfloat16_as_ushort(tobf(a.z));
    o[3] = __bfloat16_as_ushort(tobf(a.w));
    o[4] = __bfloat16_as_ushort(tobf(b.x));
    o[5] = __bfloat16_as_ushort(tobf(b.y));
    o[6] = __bfloat16_as_ushort(tobf(b.z));
    o[7] = __bfloat16_as_ushort(tobf(b.w));
    *reinterpret_cast<u16x8*>(out + (size_t)i * 8) = o;
}

// ---------------------------------------------------------------------------
// Kernel 1: QKV projection. grid = (128 m-tiles, 8 heads, 3 {K,Q,V}), block 256.
// ---------------------------------------------------------------------------
__global__ __launch_bounds__(256) void qkv_proj(
    const __hip_bfloat16* __restrict__ x,
    const __hip_bfloat16* __restrict__ Wk,
    const __hip_bfloat16* __restrict__ Wq,
    const __hip_bfloat16* __restrict__ Wv,
    __hip_bfloat16* __restrict__ Qo,   // [16][4096][64]
    __hip_bfloat16* __restrict__ Ko,   // [16][4096][64]
    __hip_bfloat16* __restrict__ Vt)   // [16][64][4096]
{
    const int w    = threadIdx.x >> 6;
    const int lane = threadIdx.x & 63;
    const int l16  = lane & 15;
    const int lg   = lane >> 4;
    const int mt   = blockIdx.x;
    const int h    = blockIdx.y;
    const int z    = blockIdx.z;

    const __hip_bfloat16* W =
        (z == 0 ? Wk : (z == 1 ? Wq : Wv)) + (size_t)h * 64 * 512;

    const int arow = mt * 64 + w * 16 + l16;
    const __hip_bfloat16* Ap = x + (size_t)arow * 512 + lg * 8;

    f32x4 acc[4] = {};
    for (int k0 = 0; k0 < 512; k0 += 32) {
        bf16x8 a = ld8(Ap + k0);
#pragma unroll
        for (int nf = 0; nf < 4; ++nf) {
            bf16x8 b = ld8(W + (size_t)(nf * 16 + l16) * 512 + k0 + lg * 8);
            acc[nf] = MFMA16(a, b, acc[nf]);
        }
    }

    const int rowbase = mt * 64 + w * 16 + lg * 4;
    const float scale = (z == 1) ? 0.125f : 1.0f;
#pragma unroll
    for (int nf = 0; nf < 4; ++nf) {
#pragma unroll
        for (int r = 0; r < 4; ++r) {
            const int row  = rowbase + r;
            const int bq   = row >> 12;
            const int srow = row & 4095;
            const int bh   = bq * 8 + h;
            const int col  = nf * 16 + l16;
            const float v  = acc[nf][r] * scale;
            if (z == 2) {
                Vt[((size_t)bh * 64 + col) * 4096 + srow] = tobf(v);
            } else if (z == 0) {
                Ko[((size_t)bh * 4096 + srow) * 64 + col] = tobf(v);
            } else {
                Qo[((size_t)bh * 4096 + srow) * 64 + col] = tobf(v);
            }
        }
    }
}

// ---------------------------------------------------------------------------
// Kernel 2a: attention partial pass (split-KV).
// grid = (256, 16): x encodes (qt deep-first, chunk c in 0..3), y = bh.
// Chunk = up to 16 KV tiles (1024 p). Each block: 4 waves x 16 q-rows.
// Swapped QK^T: lane owns q-row = qbase + (lane&15); softmax in-lane + 2 shfl.
// Only the diagonal tile is masked. l-sum deferred to chunk epilogue.
// Writes partial m,l (f32) and Z (bf16, un-normalized) to compact slots.
// ---------------------------------------------------------------------------
__global__ __launch_bounds__(256) void attn_part(
    const __hip_bfloat16* __restrict__ Q,
    const __hip_bfloat16* __restrict__ K,
    const __hip_bfloat16* __restrict__ Vt,
    __hip_bfloat16* __restrict__ Zp,   // [2560][64 q][64 d] bf16
    float* __restrict__ ML)            // [2560][2][64]  (m then l)
{
    __shared__ __hip_bfloat16 lds_p[4][16][72];   // wave-private [w][q][p]

    const int qt = 63 - ((int)blockIdx.x >> 2);   // deep q-tiles first
    const int c  = blockIdx.x & 3;
    const int a  = qt >> 4;
    if (c > a) return;                            // chunk beyond diagonal
    const int bh = blockIdx.y;

    const int w    = threadIdx.x >> 6;
    const int lane = threadIdx.x & 63;
    const int l16  = lane & 15;
    const int lg   = lane >> 4;
    const int qbase = qt * 64 + w * 16;

    const __hip_bfloat16* Qb = Q  + (size_t)bh * 4096 * 64;
    const __hip_bfloat16* Kb = K  + (size_t)bh * 4096 * 64;
    const __hip_bfloat16* Vb = Vt + (size_t)bh * 64 * 4096;

    bf16x8 qf[2];
#pragma unroll
    for (int ks = 0; ks < 2; ++ks)
        qf[ks] = ld8(Qb + (size_t)(qbase + l16) * 64 + ks * 32 + lg * 8);

    f32x4 zacc[4] = {};
    float m_s = -3.0e38f;   // running max for q-row (q = qbase + l16), lg-uniform
    float l_ln = 0.0f;      // per-lane partial denominator
    const int qrow_s = qbase + l16;

    const int t0    = c * 16;
    const bool diag = (c == a);
    const int nfull = diag ? (qt & 15) : 16;   // unmasked tiles

    auto iter = [&](int t, bool masked) {
        const int p0 = t * 64;

        // ---- S^T = mfma(K, Q) : lane holds 16 p-vals of its q-row ----
        f32x4 sacc[4] = {};
#pragma unroll
        for (int pf = 0; pf < 4; ++pf) {
#pragma unroll
            for (int ks = 0; ks < 2; ++ks) {
                bf16x8 kf = ld8(Kb + (size_t)(p0 + pf * 16 + l16) * 64 + ks * 32 + lg * 8);
                sacc[pf] = MFMA16(kf, qf[ks], sacc[pf]);
            }
        }

        float rm = -3.0e38f;
        if (masked) {
#pragma unroll
            for (int pf = 0; pf < 4; ++pf)
#pragma unroll
                for (int r = 0; r < 4; ++r) {
                    const int p = p0 + pf * 16 + lg * 4 + r;
                    float s = sacc[pf][r];
                    s = (p <= qrow_s) ? s : -1.0e30f;
                    sacc[pf][r] = s;
                    rm = fmaxf(rm, s);
                }
        } else {
#pragma unroll
            for (int pf = 0; pf < 4; ++pf)
#pragma unroll
                for (int r = 0; r < 4; ++r) rm = fmaxf(rm, sacc[pf][r]);
        }
        rm = fmaxf(rm, __shfl_xor(rm, 16));
        rm = fmaxf(rm, __shfl_xor(rm, 32));

        const float mnew  = fmaxf(m_s, rm);
        const float alpha = __expf(m_s - mnew);
        m_s = mnew;

        float rs = 0.0f;
        float pv[4][4];
#pragma unroll
        for (int pf = 0; pf < 4; ++pf)
#pragma unroll
            for (int r = 0; r < 4; ++r) {
                const float e = __expf(sacc[pf][r] - mnew);
                pv[pf][r] = e;
                rs += e;
            }
        l_ln = l_ln * alpha + rs;   // per-lane partial; reduced at epilogue

        // ---- P^T slice to wave-private LDS ----
#pragma unroll
        for (int pf = 0; pf < 4; ++pf) {
            ushort4 pk;
            pk.x = __bfloat16_as_ushort(tobf(pv[pf][0]));
            pk.y = __bfloat16_as_ushort(tobf(pv[pf][1]));
            pk.z = __bfloat16_as_ushort(tobf(pv[pf][2]));
            pk.w = __bfloat16_as_ushort(tobf(pv[pf][3]));
            *reinterpret_cast<ushort4*>(&lds_p[w][l16][pf * 16 + lg * 4]) = pk;
        }

        // ---- rescale Z (q = lg*4 + r) ----
        float alpha_q[4];
#pragma unroll
        for (int r = 0; r < 4; ++r) alpha_q[r] = __shfl(alpha, lg * 4 + r);
#pragma unroll
        for (int df = 0; df < 4; ++df)
#pragma unroll
            for (int r = 0; r < 4; ++r) zacc[df][r] *= alpha_q[r];

        // ---- Z += P V ----
        bf16x8 pa[2];
#pragma unroll
        for (int ks = 0; ks < 2; ++ks)
            pa[ks] = *reinterpret_cast<const bf16x8*>(&lds_p[w][l16][ks * 32 + lg * 8]);

#pragma unroll
        for (int df = 0; df < 4; ++df) {
#pragma unroll
            for (int ks = 0; ks < 2; ++ks) {
                bf16x8 vf = ld8(Vb + (size_t)(df * 16 + l16) * 4096 + p0 + ks * 32 + lg * 8);
                zacc[df] = MFMA16(pa[ks], vf, zacc[df]);
            }
        }
    };

    for (int i = 0; i < nfull; ++i) iter(t0 + i, false);
    if (diag) iter(qt, true);

    // ---- epilogue: reduce l across lg, write partials ----
    float l_tot = l_ln;
    l_tot += __shfl_xor(l_tot, 16);
    l_tot += __shfl_xor(l_tot, 32);

    const int slot = slot_of(bh, qt, c);
    if (lg == 0) {
        ML[(size_t)slot * 128 +      l16 + w * 16] = m_s;
        ML[(size_t)slot * 128 + 64 + l16 + w * 16] = l_tot;
    }
#pragma unroll
    for (int df = 0; df < 4; ++df)
#pragma unroll
        for (int r = 0; r < 4; ++r)
            Zp[(size_t)slot * 4096 + (w * 16 + lg * 4 + r) * 64 + df * 16 + l16] =
                tobf(zacc[df][r]);
}

// ---------------------------------------------------------------------------
// Kernel 2b: combine partials. grid = (64 qt, 16 bh), block 256.
// Thread: q = tid>>2, d-group = tid&3 (16 d each).
// ---------------------------------------------------------------------------
__global__ __launch_bounds__(256) void attn_combine(
    const __hip_bfloat16* __restrict__ Zp,
    const float* __restrict__ ML,
    __hip_bfloat16* __restrict__ Z)    // [b][s][h*64]
{
    const int qt = blockIdx.x;
    const int bh = blockIdx.y;
    const int nc = (qt >> 4) + 1;

    const int q  = threadIdx.x >> 2;
    const int dg = threadIdx.x & 3;
    const int qrow = qt * 64 + q;

    const int slot0 = slot_of(bh, qt, 0);

    float m_i[4], l_i[4];
    float M = -3.0e38f;
    for (int i = 0; i < nc; ++i) {
        m_i[i] = ML[(size_t)(slot0 + i) * 128 + q];
        l_i[i] = ML[(size_t)(slot0 + i) * 128 + 64 + q];
        M = fmaxf(M, m_i[i]);
    }
    float L = 0.0f;
    float acc[16];
#pragma unroll
    for (int j = 0; j < 16; ++j) acc[j] = 0.0f;

    for (int i = 0; i < nc; ++i) {
        const float wgt = __expf(m_i[i] - M);
        L += wgt * l_i[i];
        const __hip_bfloat16* zp =
            Zp + (size_t)(slot0 + i) * 4096 + q * 64 + dg * 16;
        bf16x8 z0 = ld8(zp);
        bf16x8 z1 = ld8(zp + 8);
#pragma unroll
        for (int j = 0; j < 8; ++j) {
            acc[j]     += wgt * (float)z0[j];
            acc[8 + j] += wgt * (float)z1[j];
        }
    }

    const float inv = 1.0f / L;
    const int b = bh >> 3, h = bh & 7;
    u16x8 o0, o1;
#pragma unroll
    for (int j = 0; j < 8; ++j) {
        o0[j] = __bfloat16_as_ushort(tobf(acc[j] * inv));
        o1[j] = __bfloat16_as_ushort(tobf(acc[8 + j] * inv));
    }
    __hip_bfloat16* zo = Z + ((size_t)b * 4096 + qrow) * 512 + h * 64 + dg * 16;
    *reinterpret_cast<u16x8*>(zo)     = o0;
    *reinterpret_cast<u16x8*>(zo + 8) = o1;
}

// ---------------------------------------------------------------------------
// Kernel 3: output projection -> FLOAT32 out.
// ---------------------------------------------------------------------------
__global__ __launch_bounds__(256) void out_proj(
    const __hip_bfloat16* __restrict__ Zf,   // [8192][512]
    const __hip_bfloat16* __restrict__ Wo,   // [512][512] bf16
    float* __restrict__ out)                 // [8192][512] f32
{
    const int w    = threadIdx.x >> 6;
    const int lane = threadIdx.x & 63;
    const int l16  = lane & 15;
    const int lg   = lane >> 4;
    const int r0   = blockIdx.x * 64 + w * 16;
    const int n0   = blockIdx.y * 64;

    f32x4 acc[4] = {};
    const __hip_bfloat16* Ap = Zf + (size_t)(r0 + l16) * 512 + lg * 8;
    for (int k0 = 0; k0 < 512; k0 += 32) {
        bf16x8 a = ld8(Ap + k0);
#pragma unroll
        for (int nf = 0; nf < 4; ++nf) {
            bf16x8 b = ld8(Wo + (size_t)(n0 + nf * 16 + l16) * 512 + k0 + lg * 8);
            acc[nf] = MFMA16(a, b, acc[nf]);
        }
    }
#pragma unroll
    for (int nf = 0; nf < 4; ++nf)
#pragma unroll
        for (int r = 0; r < 4; ++r)
            out[(size_t)(r0 + lg * 4 + r) * 512 + n0 + nf * 16 + l16] = acc[nf][r];
}

// ---------------------------------------------------------------------------
extern "C" void kernel_launch(void* const* d_in, const int* in_sizes, int n_in,
                              void* d_out, int out_size, void* d_ws, size_t ws_size,
                              hipStream_t stream)
{
    const float* x_f  = (const float*)d_in[0];
    const float* Wk_f = (const float*)d_in[1];
    const float* Wq_f = (const float*)d_in[2];
    const float* Wv_f = (const float*)d_in[3];
    const float* Wo_f = (const float*)d_in[4];
    float* out = (float*)d_out;

    char* ws = (char*)d_ws;
    const size_t szQKV = (size_t)16 * 4096 * 64 * sizeof(__hip_bfloat16);    // 8 MB
    const size_t szX   = (size_t)8192 * 512 * sizeof(__hip_bfloat16);       // 8 MB
    const size_t szW   = (size_t)8 * 64 * 512 * sizeof(__hip_bfloat16);     // 0.5 MB
    const size_t szZp  = (size_t)16 * SLOTS_PER_BH * 4096 * sizeof(__hip_bfloat16); // 21 MB
    const size_t szML  = (size_t)16 * SLOTS_PER_BH * 128 * sizeof(float);   // 1.3 MB
    size_t off = 0;
    __hip_bfloat16* Qb  = (__hip_bfloat16*)(ws + off); off += szQKV;
    __hip_bfloat16* Kb  = (__hip_bfloat16*)(ws + off); off += szQKV;
    __hip_bfloat16* Vt  = (__hip_bfloat16*)(ws + off); off += szQKV;
    __hip_bfloat16* Zb  = (__hip_bfloat16*)(ws + off); off += szX;
    __hip_bfloat16* xb  = (__hip_bfloat16*)(ws + off); off += szX;
    __hip_bfloat16* Wkb = (__hip_bfloat16*)(ws + off); off += szW;
    __hip_bfloat16* Wqb = (__hip_bfloat16*)(ws + off); off += szW;
    __hip_bfloat16* Wvb = (__hip_bfloat16*)(ws + off); off += szW;
    __hip_bfloat16* Wob = (__hip_bfloat16*)(ws + off); off += szW;
    __hip_bfloat16* Zp  = (__hip_bfloat16*)(ws + off); off += szZp;
    float*          ML  = (float*)(ws + off);          off += szML;

    {
        const int nx = 8192 * 512 / 8;
        cast_f32_bf16<<<nx / 256, 256, 0, stream>>>(x_f, xb, nx);
        const int nw = 8 * 64 * 512 / 8;
        cast_f32_bf16<<<nw / 256, 256, 0, stream>>>(Wk_f, Wkb, nw);
        cast_f32_bf16<<<nw / 256, 256, 0, stream>>>(Wq_f, Wqb, nw);
        cast_f32_bf16<<<nw / 256, 256, 0, stream>>>(Wv_f, Wvb, nw);
        cast_f32_bf16<<<nw / 256, 256, 0, stream>>>(Wo_f, Wob, nw);
    }

    qkv_proj<<<dim3(128, 8, 3), 256, 0, stream>>>(xb, Wkb, Wqb, Wvb, Qb, Kb, Vt);
    attn_part<<<dim3(256, 16),  256, 0, stream>>>(Qb, Kb, Vt, Zp, ML);
    attn_combine<<<dim3(64, 16), 256, 0, stream>>>(Zp, ML, Zb);
    out_proj<<<dim3(128, 8),    256, 0, stream>>>(Zb, Wob, out);
}

// Round 5
// 310.839 us; speedup vs baseline: 1.9736x; 1.9736x over previous
//
#include <hip/hip_runtime.h>
#include <hip/hip_bf16.h>

// b=2, s=4096, d_model=512, heads=8, d_head=64. I/O f32; compute bf16 MFMA.
// attn: 32x32x16 MFMA, LDS-staged K/V (global_load_lds, dbuf, XOR-swizzle),
// swapped QK^T in-register softmax, defer-max, split-KV (chunks of 16 tiles).

typedef __attribute__((ext_vector_type(4)))  float  f32x4;
typedef __attribute__((ext_vector_type(16))) float  f32x16;
typedef __attribute__((ext_vector_type(8)))  __bf16 bf16x8;
typedef __attribute__((ext_vector_type(8)))  unsigned short u16x8;

#define MFMA16(a, b, c) __builtin_amdgcn_mfma_f32_16x16x32_bf16((a), (b), (c), 0, 0, 0)
#define MFMA32(a, b, c) __builtin_amdgcn_mfma_f32_32x32x16_bf16((a), (b), (c), 0, 0, 0)
#define SWZ(g, r) ((g) ^ ((r) & 7))
#define SLOTS_BH 80   // per-bh chunk slots: sum over 32 q-tiles of (qi>>3)+1

static __device__ __forceinline__ bf16x8 ld8(const __hip_bfloat16* p) {
    return *reinterpret_cast<const bf16x8*>(p);
}
static __device__ __forceinline__ __hip_bfloat16 tobf(float f) {
    return __float2bfloat16(f);
}
static __device__ __forceinline__ unsigned pack2(float a, float b) {
    return (unsigned)__bfloat16_as_ushort(tobf(a)) |
           ((unsigned)__bfloat16_as_ushort(tobf(b)) << 16);
}
static __device__ __forceinline__ void gl_lds16(const __hip_bfloat16* g, __hip_bfloat16* l) {
    typedef __attribute__((address_space(1))) const unsigned int GU;
    typedef __attribute__((address_space(3))) unsigned int LU;
    __builtin_amdgcn_global_load_lds((GU*)(const void*)g, (LU*)(void*)l, 16, 0, 0);
}
static __device__ __forceinline__ int slot_off(int qi) {
    const int a = qi >> 3;
    return 4 * a * (a + 1) + (a + 1) * (qi - 8 * a);
}

// ---------------------------------------------------------------------------
__global__ __launch_bounds__(256) void cast_f32_bf16(
    const float* __restrict__ in, __hip_bfloat16* __restrict__ out, int n8)
{
    const int i = blockIdx.x * 256 + threadIdx.x;
    if (i >= n8) return;
    const float4 a = *reinterpret_cast<const float4*>(in + (size_t)i * 8);
    const float4 b = *reinterpret_cast<const float4*>(in + (size_t)i * 8 + 4);
    u16x8 o;
    o[0] = __bfloat16_as_ushort(tobf(a.x));
    o[1] = __bfloat16_as_ushort(tobf(a.y));
    o[2] = __bfloat16_as_ushort(tobf(a.z));
    o[3] = __bfloat16_as_ushort(tobf(a.w));
    o[4] = __bfloat16_as_ushort(tobf(b.x));
    o[5] = __bfloat16_as_ushort(tobf(b.y));
    o[6] = __bfloat16_as_ushort(tobf(b.z));
    o[7] = __bfloat16_as_ushort(tobf(b.w));
    *reinterpret_cast<u16x8*>(out + (size_t)i * 8) = o;
}

// ---------------------------------------------------------------------------
__global__ __launch_bounds__(256) void qkv_proj(
    const __hip_bfloat16* __restrict__ x,
    const __hip_bfloat16* __restrict__ Wk,
    const __hip_bfloat16* __restrict__ Wq,
    const __hip_bfloat16* __restrict__ Wv,
    __hip_bfloat16* __restrict__ Qo,   // [16][4096][64]
    __hip_bfloat16* __restrict__ Ko,   // [16][4096][64]
    __hip_bfloat16* __restrict__ Vt)   // [16][64][4096]
{
    const int w    = threadIdx.x >> 6;
    const int lane = threadIdx.x & 63;
    const int l16  = lane & 15;
    const int lg   = lane >> 4;
    const int mt   = blockIdx.x;
    const int h    = blockIdx.y;
    const int z    = blockIdx.z;

    const __hip_bfloat16* W =
        (z == 0 ? Wk : (z == 1 ? Wq : Wv)) + (size_t)h * 64 * 512;

    const int arow = mt * 64 + w * 16 + l16;
    const __hip_bfloat16* Ap = x + (size_t)arow * 512 + lg * 8;

    f32x4 acc[4] = {};
    for (int k0 = 0; k0 < 512; k0 += 32) {
        bf16x8 a = ld8(Ap + k0);
#pragma unroll
        for (int nf = 0; nf < 4; ++nf) {
            bf16x8 b = ld8(W + (size_t)(nf * 16 + l16) * 512 + k0 + lg * 8);
            acc[nf] = MFMA16(a, b, acc[nf]);
        }
    }

    const int rowbase = mt * 64 + w * 16 + lg * 4;
    const float scale = (z == 1) ? 0.125f : 1.0f;
#pragma unroll
    for (int nf = 0; nf < 4; ++nf) {
#pragma unroll
        for (int r = 0; r < 4; ++r) {
            const int row  = rowbase + r;
            const int bq   = row >> 12;
            const int srow = row & 4095;
            const int bh   = bq * 8 + h;
            const int col  = nf * 16 + l16;
            const float v  = acc[nf][r] * scale;
            if (z == 2) {
                Vt[((size_t)bh * 64 + col) * 4096 + srow] = tobf(v);
            } else if (z == 0) {
                Ko[((size_t)bh * 4096 + srow) * 64 + col] = tobf(v);
            } else {
                Qo[((size_t)bh * 4096 + srow) * 64 + col] = tobf(v);
            }
        }
    }
}

// ---------------------------------------------------------------------------
// attn_part: grid=(128, 16): x encodes (qi deep-first, chunk c), y=bh. 256 thr.
// Block = 128 q-rows (4 waves x 32). KV tile = 64, chunk = 16 tiles.
// ---------------------------------------------------------------------------
__global__ __launch_bounds__(256) void attn_part(
    const __hip_bfloat16* __restrict__ Q,
    const __hip_bfloat16* __restrict__ K,
    const __hip_bfloat16* __restrict__ Vt,
    __hip_bfloat16* __restrict__ Zp,   // [slots][128 q][64 d] bf16
    float* __restrict__ ML)            // [slots][2][128]
{
    __shared__ __hip_bfloat16 Klds[2][64][64];
    __shared__ __hip_bfloat16 Vlds[2][64][64];   // V^T tile: [d][p]
    __shared__ __hip_bfloat16 Plds[4][32][64];   // per-wave P, swizzled granules
    __shared__ float als[4][32];

    const int qi = 31 - ((int)blockIdx.x >> 2);   // deep q-tiles first
    const int c  = blockIdx.x & 3;
    const int a  = qi >> 3;
    if (c > a) return;
    const int bh = blockIdx.y;

    const int w    = threadIdx.x >> 6;
    const int lane = threadIdx.x & 63;
    const int q31  = lane & 31;
    const int hi   = lane >> 5;

    const __hip_bfloat16* Qb = Q  + (size_t)bh * 4096 * 64;
    const __hip_bfloat16* Kb = K  + (size_t)bh * 4096 * 64;
    const __hip_bfloat16* Vb = Vt + (size_t)bh * 64 * 4096;

    const int qrow = qi * 128 + w * 32 + q31;   // this lane's softmax q-row

    // Q B-fragments (col=lane&31=q, k=d)
    bf16x8 qf[4];
#pragma unroll
    for (int ks = 0; ks < 4; ++ks)
        qf[ks] = ld8(Qb + (size_t)qrow * 64 + ks * 16 + hi * 8);

    f32x16 za0 = {}, za1 = {};
    float m_s  = -3.0e38f;
    float l_ln = 0.0f;

    const int t0   = c * 16;
    const int tend = min(t0 + 16, 2 * qi + 2);
    const int nt   = tend - t0;

    // ---- staging helper: K tile + V^T tile -> LDS[buf], pre-swizzled src ----
    const int gcol = lane & 7;
    auto stage = [&](int buf, int t) {
        const int p0 = t * 64;
#pragma unroll
        for (int j = 0; j < 2; ++j) {
            const int r = w * 8 + j * 32 + (lane >> 3);   // local row 0..63
            const int cg = gcol ^ (r & 7);                // source granule
            gl_lds16(Kb + (size_t)(p0 + r) * 64 + cg * 8, &Klds[buf][w * 8 + j * 32][0]);
            gl_lds16(Vb + (size_t)r * 4096 + p0 + cg * 8, &Vlds[buf][w * 8 + j * 32][0]);
        }
    };

    stage(0, t0);

    for (int it = 0; it < nt; ++it) {
        const int t   = t0 + it;
        const int buf = it & 1;

        asm volatile("s_waitcnt vmcnt(0)" ::: "memory");
        __syncthreads();
        if (it + 1 < nt) stage(buf ^ 1, t + 1);

        // ---- S^T = mfma(K, Q): 2 p-tiles x 4 k-slots ----
        f32x16 sa0 = {}, sa1 = {};
#pragma unroll
        for (int ks = 0; ks < 4; ++ks) {
            const int gs = SWZ(2 * ks + hi, q31) * 8;
            bf16x8 k0 = *(const bf16x8*)&Klds[buf][q31][gs];
            bf16x8 k1 = *(const bf16x8*)&Klds[buf][32 + q31][gs];
            sa0 = MFMA32(k0, qf[ks], sa0);
            sa1 = MFMA32(k1, qf[ks], sa1);
        }

        // ---- causal mask (diag tiles only) + row max ----
        if (t >= 2 * qi) {
#pragma unroll
            for (int reg = 0; reg < 16; ++reg) {
                const int pl = (reg & 3) + 8 * (reg >> 2) + 4 * hi;
                const int p  = t * 64 + pl;
                sa0[reg] = (p      <= qrow) ? sa0[reg] : -1.0e30f;
                sa1[reg] = (p + 32 <= qrow) ? sa1[reg] : -1.0e30f;
            }
        }
        float mx = -3.0e38f;
#pragma unroll
        for (int reg = 0; reg < 16; ++reg)
            mx = fmaxf(mx, fmaxf(sa0[reg], sa1[reg]));
        mx = fmaxf(mx, __shfl_xor(mx, 32));

        // ---- defer-max: rescale only when max grew past threshold ----
        if (!__all(mx <= m_s + 8.0f)) {
            const float mnew  = fmaxf(m_s, mx);
            const float alpha = __expf(m_s - mnew);
            m_s = mnew;
            l_ln *= alpha;
            if (hi == 0) als[w][q31] = alpha;
#pragma unroll
            for (int reg = 0; reg < 16; ++reg) {
                const int q = (reg & 3) + 8 * (reg >> 2) + 4 * hi;
                const float av = als[w][q];
                za0[reg] *= av;
                za1[reg] *= av;
            }
        }

        // ---- P = exp(S - m), in-lane l partial ----
        float ls = 0.0f;
#pragma unroll
        for (int reg = 0; reg < 16; ++reg) {
            sa0[reg] = __expf(sa0[reg] - m_s);
            sa1[reg] = __expf(sa1[reg] - m_s);
            ls += sa0[reg] + sa1[reg];
        }
        l_ln += ls;

        // ---- P -> wave-private LDS (bf16, swizzled granules) ----
#pragma unroll
        for (int r1 = 0; r1 < 4; ++r1) {
            uint2 w0, w1;
            w0.x = pack2(sa0[4 * r1 + 0], sa0[4 * r1 + 1]);
            w0.y = pack2(sa0[4 * r1 + 2], sa0[4 * r1 + 3]);
            w1.x = pack2(sa1[4 * r1 + 0], sa1[4 * r1 + 1]);
            w1.y = pack2(sa1[4 * r1 + 2], sa1[4 * r1 + 3]);
            *(uint2*)&Plds[w][q31][SWZ(r1,     q31) * 8 + hi * 4] = w0;
            *(uint2*)&Plds[w][q31][SWZ(4 + r1, q31) * 8 + hi * 4] = w1;
        }

        // ---- Z += P V (A=P row=q, B=V^T col=d) ----
#pragma unroll
        for (int ks = 0; ks < 4; ++ks) {
            const int gs = SWZ(2 * ks + hi, q31) * 8;
            bf16x8 pa = *(const bf16x8*)&Plds[w][q31][gs];
            bf16x8 v0 = *(const bf16x8*)&Vlds[buf][q31][gs];
            bf16x8 v1 = *(const bf16x8*)&Vlds[buf][32 + q31][gs];
            za0 = MFMA32(pa, v0, za0);
            za1 = MFMA32(pa, v1, za1);
        }
    }

    // ---- epilogue ----
    float lt = l_ln + __shfl_xor(l_ln, 32);
    const int slot = bh * SLOTS_BH + slot_off(qi) + c;
    if (hi == 0) {
        ML[(size_t)slot * 256 +       w * 32 + q31] = m_s;
        ML[(size_t)slot * 256 + 128 + w * 32 + q31] = lt;
    }
#pragma unroll
    for (int reg = 0; reg < 16; ++reg) {
        const int q = (reg & 3) + 8 * (reg >> 2) + 4 * hi;
        const size_t base = (size_t)slot * 8192 + (size_t)(w * 32 + q) * 64 + q31;
        Zp[base]      = tobf(za0[reg]);
        Zp[base + 32] = tobf(za1[reg]);
    }
}

// ---------------------------------------------------------------------------
// attn_combine: grid=(32 qi, 16 bh), block 256. thread: q=tid>>1, half=tid&1.
// ---------------------------------------------------------------------------
__global__ __launch_bounds__(256) void attn_combine(
    const __hip_bfloat16* __restrict__ Zp,
    const float* __restrict__ ML,
    __hip_bfloat16* __restrict__ Z)    // [b][s][h*64]
{
    const int qi = blockIdx.x;
    const int bh = blockIdx.y;
    const int nc = (qi >> 3) + 1;
    const int q    = threadIdx.x >> 1;
    const int half = threadIdx.x & 1;

    const int slot0 = bh * SLOTS_BH + slot_off(qi);

    float m_i[4], l_i[4];
    float M = -3.0e38f;
    for (int i = 0; i < nc; ++i) {
        m_i[i] = ML[(size_t)(slot0 + i) * 256 + q];
        l_i[i] = ML[(size_t)(slot0 + i) * 256 + 128 + q];
        M = fmaxf(M, m_i[i]);
    }
    float L = 0.0f;
    float acc[32];
#pragma unroll
    for (int j = 0; j < 32; ++j) acc[j] = 0.0f;

    for (int i = 0; i < nc; ++i) {
        const float wgt = __expf(m_i[i] - M);
        L += wgt * l_i[i];
        const __hip_bfloat16* zp =
            Zp + (size_t)(slot0 + i) * 8192 + (size_t)q * 64 + half * 32;
#pragma unroll
        for (int v = 0; v < 4; ++v) {
            bf16x8 z = ld8(zp + v * 8);
#pragma unroll
            for (int j = 0; j < 8; ++j) acc[v * 8 + j] += wgt * (float)z[j];
        }
    }

    const float inv = 1.0f / L;
    const int b = bh >> 3, h = bh & 7;
    __hip_bfloat16* zo =
        Z + ((size_t)b * 4096 + qi * 128 + q) * 512 + h * 64 + half * 32;
#pragma unroll
    for (int v = 0; v < 4; ++v) {
        u16x8 o;
#pragma unroll
        for (int j = 0; j < 8; ++j)
            o[j] = __bfloat16_as_ushort(tobf(acc[v * 8 + j] * inv));
        *reinterpret_cast<u16x8*>(zo + v * 8) = o;
    }
}

// ---------------------------------------------------------------------------
__global__ __launch_bounds__(256) void out_proj(
    const __hip_bfloat16* __restrict__ Zf,   // [8192][512]
    const __hip_bfloat16* __restrict__ Wo,   // [512][512] bf16
    float* __restrict__ out)                 // [8192][512] f32
{
    const int w    = threadIdx.x >> 6;
    const int lane = threadIdx.x & 63;
    const int l16  = lane & 15;
    const int lg   = lane >> 4;
    const int r0   = blockIdx.x * 64 + w * 16;
    const int n0   = blockIdx.y * 64;

    f32x4 acc[4] = {};
    const __hip_bfloat16* Ap = Zf + (size_t)(r0 + l16) * 512 + lg * 8;
    for (int k0 = 0; k0 < 512; k0 += 32) {
        bf16x8 a = ld8(Ap + k0);
#pragma unroll
        for (int nf = 0; nf < 4; ++nf) {
            bf16x8 b = ld8(Wo + (size_t)(n0 + nf * 16 + l16) * 512 + k0 + lg * 8);
            acc[nf] = MFMA16(a, b, acc[nf]);
        }
    }
#pragma unroll
    for (int nf = 0; nf < 4; ++nf)
#pragma unroll
        for (int r = 0; r < 4; ++r)
            out[(size_t)(r0 + lg * 4 + r) * 512 + n0 + nf * 16 + l16] = acc[nf][r];
}

// ---------------------------------------------------------------------------
extern "C" void kernel_launch(void* const* d_in, const int* in_sizes, int n_in,
                              void* d_out, int out_size, void* d_ws, size_t ws_size,
                              hipStream_t stream)
{
    const float* x_f  = (const float*)d_in[0];
    const float* Wk_f = (const float*)d_in[1];
    const float* Wq_f = (const float*)d_in[2];
    const float* Wv_f = (const float*)d_in[3];
    const float* Wo_f = (const float*)d_in[4];
    float* out = (float*)d_out;

    char* ws = (char*)d_ws;
    const size_t szQKV = (size_t)16 * 4096 * 64 * sizeof(__hip_bfloat16);   // 8 MB
    const size_t szX   = (size_t)8192 * 512 * sizeof(__hip_bfloat16);       // 8 MB
    const size_t szW   = (size_t)8 * 64 * 512 * sizeof(__hip_bfloat16);     // 0.5 MB
    const size_t szZp  = (size_t)16 * SLOTS_BH * 128 * 64 * sizeof(__hip_bfloat16); // 21 MB
    const size_t szML  = (size_t)16 * SLOTS_BH * 256 * sizeof(float);       // 1.3 MB
    size_t off = 0;
    __hip_bfloat16* Qb  = (__hip_bfloat16*)(ws + off); off += szQKV;
    __hip_bfloat16* Kb  = (__hip_bfloat16*)(ws + off); off += szQKV;
    __hip_bfloat16* Vt  = (__hip_bfloat16*)(ws + off); off += szQKV;
    __hip_bfloat16* Zb  = (__hip_bfloat16*)(ws + off); off += szX;
    __hip_bfloat16* xb  = (__hip_bfloat16*)(ws + off); off += szX;
    __hip_bfloat16* Wkb = (__hip_bfloat16*)(ws + off); off += szW;
    __hip_bfloat16* Wqb = (__hip_bfloat16*)(ws + off); off += szW;
    __hip_bfloat16* Wvb = (__hip_bfloat16*)(ws + off); off += szW;
    __hip_bfloat16* Wob = (__hip_bfloat16*)(ws + off); off += szW;
    __hip_bfloat16* Zp  = (__hip_bfloat16*)(ws + off); off += szZp;
    float*          ML  = (float*)(ws + off);          off += szML;

    {
        const int nx = 8192 * 512 / 8;
        cast_f32_bf16<<<nx / 256, 256, 0, stream>>>(x_f, xb, nx);
        const int nw = 8 * 64 * 512 / 8;
        cast_f32_bf16<<<nw / 256, 256, 0, stream>>>(Wk_f, Wkb, nw);
        cast_f32_bf16<<<nw / 256, 256, 0, stream>>>(Wq_f, Wqb, nw);
        cast_f32_bf16<<<nw / 256, 256, 0, stream>>>(Wv_f, Wvb, nw);
        cast_f32_bf16<<<nw / 256, 256, 0, stream>>>(Wo_f, Wob, nw);
    }

    qkv_proj<<<dim3(128, 8, 3), 256, 0, stream>>>(xb, Wkb, Wqb, Wvb, Qb, Kb, Vt);
    attn_part<<<dim3(128, 16),  256, 0, stream>>>(Qb, Kb, Vt, Zp, ML);
    attn_combine<<<dim3(32, 16), 256, 0, stream>>>(Zp, ML, Zb);
    out_proj<<<dim3(128, 8),    256, 0, stream>>>(Zb, Wob, out);
}

// Round 6
// 305.639 us; speedup vs baseline: 2.0072x; 1.0170x over previous
//
#include <hip/hip_runtime.h>
#include <hip/hip_bf16.h>

// b=2, s=4096, d_model=512, heads=8, d_head=64. I/O f32; compute bf16 MFMA.
// attn: 32x32x16 MFMA, LDS-staged K/V (global_load_lds, dbuf, XOR-swizzle),
// swapped QK^T, in-register softmax (base-2, tree reduce, defer-max),
// in-register P transpose via cvt_pk_bf16 + permlane32_swap, split-KV.

typedef __attribute__((ext_vector_type(4)))  float  f32x4;
typedef __attribute__((ext_vector_type(16))) float  f32x16;
typedef __attribute__((ext_vector_type(8)))  __bf16 bf16x8;
typedef __attribute__((ext_vector_type(8)))  unsigned short u16x8;
typedef __attribute__((ext_vector_type(4)))  unsigned int u32x4;

#define MFMA16(a, b, c) __builtin_amdgcn_mfma_f32_16x16x32_bf16((a), (b), (c), 0, 0, 0)
#define MFMA32(a, b, c) __builtin_amdgcn_mfma_f32_32x32x16_bf16((a), (b), (c), 0, 0, 0)
#define SWZ(g, r) ((g) ^ ((r) & 7))
#define SLOTS_BH 80   // per-bh chunk slots: sum over 32 q-tiles of (qi>>3)+1

static __device__ __forceinline__ bf16x8 ld8(const __hip_bfloat16* p) {
    return *reinterpret_cast<const bf16x8*>(p);
}
static __device__ __forceinline__ __hip_bfloat16 tobf(float f) {
    return __float2bfloat16(f);
}
static __device__ __forceinline__ unsigned cvt_pk(float lo, float hi) {
    unsigned r;
    asm("v_cvt_pk_bf16_f32 %0, %1, %2" : "=v"(r) : "v"(lo), "v"(hi));
    return r;
}
static __device__ __forceinline__ void pl32swap(unsigned& a, unsigned& b) {
    asm("v_permlane32_swap_b32 %0, %1" : "+v"(a), "+v"(b));
}
static __device__ __forceinline__ void gl_lds16(const __hip_bfloat16* g, __hip_bfloat16* l) {
    typedef __attribute__((address_space(1))) const unsigned int GU;
    typedef __attribute__((address_space(3))) unsigned int LU;
    __builtin_amdgcn_global_load_lds((GU*)(const void*)g, (LU*)(void*)l, 16, 0, 0);
}
static __device__ __forceinline__ int slot_off(int qi) {
    const int a = qi >> 3;
    return 4 * a * (a + 1) + (a + 1) * (qi - 8 * a);
}

// ---------------------------------------------------------------------------
// Fused cast: f32 -> bf16 for x (2048 blocks) + 4 weights (128 blocks each).
// ---------------------------------------------------------------------------
__global__ __launch_bounds__(256) void cast_all(
    const float* __restrict__ x,  const float* __restrict__ wk,
    const float* __restrict__ wq, const float* __restrict__ wv,
    const float* __restrict__ wo,
    __hip_bfloat16* __restrict__ xb,  __hip_bfloat16* __restrict__ wkb,
    __hip_bfloat16* __restrict__ wqb, __hip_bfloat16* __restrict__ wvb,
    __hip_bfloat16* __restrict__ wob)
{
    const int bid = blockIdx.x;
    const float* src;
    __hip_bfloat16* dst;
    int base;
    if (bid < 2048) { src = x; dst = xb; base = bid; }
    else {
        const int r = (bid - 2048) >> 7;
        base = (bid - 2048) & 127;
        src = (r == 0) ? wk : (r == 1) ? wq : (r == 2) ? wv : wo;
        dst = (r == 0) ? wkb : (r == 1) ? wqb : (r == 2) ? wvb : wob;
    }
    const size_t i = (size_t)base * 256 + threadIdx.x;
    const float4 a = *reinterpret_cast<const float4*>(src + i * 8);
    const float4 b = *reinterpret_cast<const float4*>(src + i * 8 + 4);
    u16x8 o;
    o[0] = __bfloat16_as_ushort(tobf(a.x));
    o[1] = __bfloat16_as_ushort(tobf(a.y));
    o[2] = __bfloat16_as_ushort(tobf(a.z));
    o[3] = __bfloat16_as_ushort(tobf(a.w));
    o[4] = __bfloat16_as_ushort(tobf(b.x));
    o[5] = __bfloat16_as_ushort(tobf(b.y));
    o[6] = __bfloat16_as_ushort(tobf(b.z));
    o[7] = __bfloat16_as_ushort(tobf(b.w));
    *reinterpret_cast<u16x8*>(dst + i * 8) = o;
}

// ---------------------------------------------------------------------------
__global__ __launch_bounds__(256) void qkv_proj(
    const __hip_bfloat16* __restrict__ x,
    const __hip_bfloat16* __restrict__ Wk,
    const __hip_bfloat16* __restrict__ Wq,
    const __hip_bfloat16* __restrict__ Wv,
    __hip_bfloat16* __restrict__ Qo,   // [16][4096][64]  (pre-scaled, base-2)
    __hip_bfloat16* __restrict__ Ko,   // [16][4096][64]
    __hip_bfloat16* __restrict__ Vt)   // [16][64][4096]
{
    const int w    = threadIdx.x >> 6;
    const int lane = threadIdx.x & 63;
    const int l16  = lane & 15;
    const int lg   = lane >> 4;
    const int mt   = blockIdx.x;
    const int h    = blockIdx.y;
    const int z    = blockIdx.z;

    const __hip_bfloat16* W =
        (z == 0 ? Wk : (z == 1 ? Wq : Wv)) + (size_t)h * 64 * 512;

    const int arow = mt * 64 + w * 16 + l16;
    const __hip_bfloat16* Ap = x + (size_t)arow * 512 + lg * 8;

    f32x4 acc[4] = {};
#pragma unroll 2
    for (int k0 = 0; k0 < 512; k0 += 32) {
        bf16x8 a = ld8(Ap + k0);
#pragma unroll
        for (int nf = 0; nf < 4; ++nf) {
            bf16x8 b = ld8(W + (size_t)(nf * 16 + l16) * 512 + k0 + lg * 8);
            acc[nf] = MFMA16(a, b, acc[nf]);
        }
    }

    const int rowbase = mt * 64 + w * 16 + lg * 4;
    // Q scale: 1/sqrt(64) * 1/ln(2)  (base-2 softmax domain)
    const float scale = (z == 1) ? 0.18033688f : 1.0f;
#pragma unroll
    for (int nf = 0; nf < 4; ++nf) {
#pragma unroll
        for (int r = 0; r < 4; ++r) {
            const int row  = rowbase + r;
            const int bq   = row >> 12;
            const int srow = row & 4095;
            const int bh   = bq * 8 + h;
            const int col  = nf * 16 + l16;
            const float v  = acc[nf][r] * scale;
            if (z == 2) {
                Vt[((size_t)bh * 64 + col) * 4096 + srow] = tobf(v);
            } else if (z == 0) {
                Ko[((size_t)bh * 4096 + srow) * 64 + col] = tobf(v);
            } else {
                Qo[((size_t)bh * 4096 + srow) * 64 + col] = tobf(v);
            }
        }
    }
}

// ---------------------------------------------------------------------------
// attn_part: grid=(128, 16): x encodes (qi deep-first, chunk c), y=bh. 256 thr.
// Block = 128 q-rows (4 waves x 32). KV tile = 64, chunk = 16 tiles.
// ---------------------------------------------------------------------------
__global__ __launch_bounds__(256) void attn_part(
    const __hip_bfloat16* __restrict__ Q,
    const __hip_bfloat16* __restrict__ K,
    const __hip_bfloat16* __restrict__ Vt,
    __hip_bfloat16* __restrict__ Zp,   // [slots][128 q][64 d] bf16
    float* __restrict__ ML)            // [slots][2][128]
{
    __shared__ __hip_bfloat16 Klds[2][64][64];
    __shared__ __hip_bfloat16 Vlds[2][64][64];   // V^T tile: [d][p]
    __shared__ float als[4][32];

    const int qi = 31 - ((int)blockIdx.x >> 2);   // deep q-tiles first
    const int c  = blockIdx.x & 3;
    const int a  = qi >> 3;
    if (c > a) return;
    const int bh = blockIdx.y;

    const int w    = threadIdx.x >> 6;
    const int lane = threadIdx.x & 63;
    const int q31  = lane & 31;
    const int hi   = lane >> 5;

    const __hip_bfloat16* Qb = Q  + (size_t)bh * 4096 * 64;
    const __hip_bfloat16* Kb = K  + (size_t)bh * 4096 * 64;
    const __hip_bfloat16* Vb = Vt + (size_t)bh * 64 * 4096;

    const int qrow  = qi * 128 + w * 32 + q31;   // this lane's softmax q-row
    const int wqmax = qi * 128 + w * 32 + 31;    // wave's deepest q-row

    // Q B-fragments (col=lane&31=q, k=d)
    bf16x8 qf[4];
#pragma unroll
    for (int ks = 0; ks < 4; ++ks)
        qf[ks] = ld8(Qb + (size_t)qrow * 64 + ks * 16 + hi * 8);

    f32x16 za0 = {}, za1 = {};
    float m_s  = -3.0e38f;
    float l_ln = 0.0f;

    const int t0   = c * 16;
    const int tend = min(t0 + 16, 2 * qi + 2);
    const int nt   = tend - t0;

    // ---- staging: hoisted per-lane source addresses (pre-swizzled) ----
    const int r0l = w * 8 + (lane >> 3);          // local row, j=0 (j=1: +32)
    const int cg  = (lane & 7) ^ (r0l & 7);       // source granule (same for both j)
    const __hip_bfloat16* Ksrc = Kb + (size_t)r0l * 64 + cg * 8;
    const __hip_bfloat16* Vsrc = Vb + (size_t)r0l * 4096 + cg * 8;

    auto stage = [&](int buf, int t) {
        const int p0 = t * 64;
        gl_lds16(Ksrc + (size_t)p0 * 64,            &Klds[buf][w * 8][0]);
        gl_lds16(Ksrc + (size_t)p0 * 64 + 32 * 64,  &Klds[buf][w * 8 + 32][0]);
        gl_lds16(Vsrc + p0,                          &Vlds[buf][w * 8][0]);
        gl_lds16(Vsrc + p0 + (size_t)32 * 4096,      &Vlds[buf][w * 8 + 32][0]);
    };

    stage(0, t0);

    for (int it = 0; it < nt; ++it) {
        const int t   = t0 + it;
        const int buf = it & 1;

        asm volatile("s_waitcnt vmcnt(0)" ::: "memory");
        __syncthreads();
        if (it + 1 < nt) stage(buf ^ 1, t + 1);

        const int p0 = t * 64;
        if (p0 > wqmax) continue;   // wave fully masked (barriers stay uniform)

        // ---- S^T = mfma(K, Q): 2 p-tiles x 4 k-slots ----
        f32x16 sa0 = {}, sa1 = {};
#pragma unroll
        for (int ks = 0; ks < 4; ++ks) {
            const int gs = SWZ(2 * ks + hi, q31) * 8;
            bf16x8 k0 = *(const bf16x8*)&Klds[buf][q31][gs];
            bf16x8 k1 = *(const bf16x8*)&Klds[buf][32 + q31][gs];
            sa0 = MFMA32(k0, qf[ks], sa0);
            sa1 = MFMA32(k1, qf[ks], sa1);
        }

        // ---- causal mask (diag tiles only) ----
        if (t >= 2 * qi) {
#pragma unroll
            for (int reg = 0; reg < 16; ++reg) {
                const int pl = (reg & 3) + 8 * (reg >> 2) + 4 * hi;
                const int p  = p0 + pl;
                sa0[reg] = (p      <= qrow) ? sa0[reg] : -1.0e30f;
                sa1[reg] = (p + 32 <= qrow) ? sa1[reg] : -1.0e30f;
            }
        }

        // ---- row max: tree reduce (depth 5) + cross-half ----
        float tm[8];
#pragma unroll
        for (int i = 0; i < 8; ++i)
            tm[i] = fmaxf(fmaxf(sa0[i], sa0[i + 8]), fmaxf(sa1[i], sa1[i + 8]));
#pragma unroll
        for (int s = 4; s; s >>= 1)
#pragma unroll
            for (int i = 0; i < s; ++i) tm[i] = fmaxf(tm[i], tm[i + s]);
        float mx = fmaxf(tm[0], __shfl_xor(tm[0], 32));

        // ---- defer-max: rescale only when max grew past threshold ----
        if (!__all(mx <= m_s + 8.0f)) {
            const float mnew  = fmaxf(m_s, mx);
            const float alpha = exp2f(m_s - mnew);
            m_s = mnew;
            l_ln *= alpha;
            if (hi == 0) als[w][q31] = alpha;
#pragma unroll
            for (int reg = 0; reg < 16; ++reg) {
                const int q = (reg & 3) + 8 * (reg >> 2) + 4 * hi;
                const float av = als[w][q];
                za0[reg] *= av;
                za1[reg] *= av;
            }
        }

        // ---- P = 2^(S - m), tree l-sum ----
#pragma unroll
        for (int reg = 0; reg < 16; ++reg) {
            sa0[reg] = exp2f(sa0[reg] - m_s);
            sa1[reg] = exp2f(sa1[reg] - m_s);
        }
        float ts[8];
#pragma unroll
        for (int i = 0; i < 8; ++i)
            ts[i] = (sa0[i] + sa0[i + 8]) + (sa1[i] + sa1[i + 8]);
#pragma unroll
        for (int s = 4; s; s >>= 1)
#pragma unroll
            for (int i = 0; i < s; ++i) ts[i] += ts[i + s];
        l_ln += ts[0];

        // ---- in-register P transpose -> A-frags (cvt_pk + permlane32_swap) --
        bf16x8 pfrag[4];
#pragma unroll
        for (int kb = 0; kb < 4; ++kb) {
            const int e = (kb & 1) * 8;
            unsigned px, py, pu, pv;
            if (kb < 2) {
                px = cvt_pk(sa0[e + 0], sa0[e + 1]);
                py = cvt_pk(sa0[e + 2], sa0[e + 3]);
                pu = cvt_pk(sa0[e + 4], sa0[e + 5]);
                pv = cvt_pk(sa0[e + 6], sa0[e + 7]);
            } else {
                px = cvt_pk(sa1[e + 0], sa1[e + 1]);
                py = cvt_pk(sa1[e + 2], sa1[e + 3]);
                pu = cvt_pk(sa1[e + 4], sa1[e + 5]);
                pv = cvt_pk(sa1[e + 6], sa1[e + 7]);
            }
            pl32swap(px, pu);
            pl32swap(py, pv);
            u32x4 fw;
            fw[0] = px; fw[1] = py; fw[2] = pu; fw[3] = pv;
            pfrag[kb] = __builtin_bit_cast(bf16x8, fw);
        }

        // ---- Z += P V (A=P row=q, B=V^T col=d) ----
#pragma unroll
        for (int kb = 0; kb < 4; ++kb) {
            const int gs = SWZ(2 * kb + hi, q31) * 8;
            bf16x8 v0 = *(const bf16x8*)&Vlds[buf][q31][gs];
            bf16x8 v1 = *(const bf16x8*)&Vlds[buf][32 + q31][gs];
            za0 = MFMA32(pfrag[kb], v0, za0);
            za1 = MFMA32(pfrag[kb], v1, za1);
        }
    }

    // ---- epilogue ----
    float lt = l_ln + __shfl_xor(l_ln, 32);
    const int slot = bh * SLOTS_BH + slot_off(qi) + c;
    if (hi == 0) {
        ML[(size_t)slot * 256 +       w * 32 + q31] = m_s;
        ML[(size_t)slot * 256 + 128 + w * 32 + q31] = lt;
    }
#pragma unroll
    for (int reg = 0; reg < 16; ++reg) {
        const int q = (reg & 3) + 8 * (reg >> 2) + 4 * hi;
        const size_t base = (size_t)slot * 8192 + (size_t)(w * 32 + q) * 64 + q31;
        Zp[base]      = tobf(za0[reg]);
        Zp[base + 32] = tobf(za1[reg]);
    }
}

// ---------------------------------------------------------------------------
// attn_combine: grid=(32 qi, 16 bh), block 256. thread: q=tid>>1, half=tid&1.
// ---------------------------------------------------------------------------
__global__ __launch_bounds__(256) void attn_combine(
    const __hip_bfloat16* __restrict__ Zp,
    const float* __restrict__ ML,
    __hip_bfloat16* __restrict__ Z)    // [b][s][h*64]
{
    const int qi = blockIdx.x;
    const int bh = blockIdx.y;
    const int nc = (qi >> 3) + 1;
    const int q    = threadIdx.x >> 1;
    const int half = threadIdx.x & 1;

    const int slot0 = bh * SLOTS_BH + slot_off(qi);

    float m_i[4], l_i[4];
    float M = -3.0e38f;
    for (int i = 0; i < nc; ++i) {
        m_i[i] = ML[(size_t)(slot0 + i) * 256 + q];
        l_i[i] = ML[(size_t)(slot0 + i) * 256 + 128 + q];
        M = fmaxf(M, m_i[i]);
    }
    float L = 0.0f;
    float acc[32];
#pragma unroll
    for (int j = 0; j < 32; ++j) acc[j] = 0.0f;

    for (int i = 0; i < nc; ++i) {
        const float wgt = exp2f(m_i[i] - M);
        L += wgt * l_i[i];
        const __hip_bfloat16* zp =
            Zp + (size_t)(slot0 + i) * 8192 + (size_t)q * 64 + half * 32;
#pragma unroll
        for (int v = 0; v < 4; ++v) {
            bf16x8 z = ld8(zp + v * 8);
#pragma unroll
            for (int j = 0; j < 8; ++j) acc[v * 8 + j] += wgt * (float)z[j];
        }
    }

    const float inv = 1.0f / L;
    const int b = bh >> 3, h = bh & 7;
    __hip_bfloat16* zo =
        Z + ((size_t)b * 4096 + qi * 128 + q) * 512 + h * 64 + half * 32;
#pragma unroll
    for (int v = 0; v < 4; ++v) {
        u16x8 o;
#pragma unroll
        for (int j = 0; j < 8; ++j)
            o[j] = __bfloat16_as_ushort(tobf(acc[v * 8 + j] * inv));
        *reinterpret_cast<u16x8*>(zo + v * 8) = o;
    }
}

// ---------------------------------------------------------------------------
__global__ __launch_bounds__(256) void out_proj(
    const __hip_bfloat16* __restrict__ Zf,   // [8192][512]
    const __hip_bfloat16* __restrict__ Wo,   // [512][512] bf16
    float* __restrict__ out)                 // [8192][512] f32
{
    const int w    = threadIdx.x >> 6;
    const int lane = threadIdx.x & 63;
    const int l16  = lane & 15;
    const int lg   = lane >> 4;
    const int r0   = blockIdx.x * 64 + w * 16;
    const int n0   = blockIdx.y * 64;

    f32x4 acc[4] = {};
    const __hip_bfloat16* Ap = Zf + (size_t)(r0 + l16) * 512 + lg * 8;
#pragma unroll 2
    for (int k0 = 0; k0 < 512; k0 += 32) {
        bf16x8 a = ld8(Ap + k0);
#pragma unroll
        for (int nf = 0; nf < 4; ++nf) {
            bf16x8 b = ld8(Wo + (size_t)(n0 + nf * 16 + l16) * 512 + k0 + lg * 8);
            acc[nf] = MFMA16(a, b, acc[nf]);
        }
    }
#pragma unroll
    for (int nf = 0; nf < 4; ++nf)
#pragma unroll
        for (int r = 0; r < 4; ++r)
            out[(size_t)(r0 + lg * 4 + r) * 512 + n0 + nf * 16 + l16] = acc[nf][r];
}

// ---------------------------------------------------------------------------
extern "C" void kernel_launch(void* const* d_in, const int* in_sizes, int n_in,
                              void* d_out, int out_size, void* d_ws, size_t ws_size,
                              hipStream_t stream)
{
    const float* x_f  = (const float*)d_in[0];
    const float* Wk_f = (const float*)d_in[1];
    const float* Wq_f = (const float*)d_in[2];
    const float* Wv_f = (const float*)d_in[3];
    const float* Wo_f = (const float*)d_in[4];
    float* out = (float*)d_out;

    char* ws = (char*)d_ws;
    const size_t szQKV = (size_t)16 * 4096 * 64 * sizeof(__hip_bfloat16);   // 8 MB
    const size_t szX   = (size_t)8192 * 512 * sizeof(__hip_bfloat16);       // 8 MB
    const size_t szW   = (size_t)8 * 64 * 512 * sizeof(__hip_bfloat16);     // 0.5 MB
    const size_t szZp  = (size_t)16 * SLOTS_BH * 128 * 64 * sizeof(__hip_bfloat16); // 21 MB
    const size_t szML  = (size_t)16 * SLOTS_BH * 256 * sizeof(float);       // 1.3 MB
    size_t off = 0;
    __hip_bfloat16* Qb  = (__hip_bfloat16*)(ws + off); off += szQKV;
    __hip_bfloat16* Kb  = (__hip_bfloat16*)(ws + off); off += szQKV;
    __hip_bfloat16* Vt  = (__hip_bfloat16*)(ws + off); off += szQKV;
    __hip_bfloat16* Zb  = (__hip_bfloat16*)(ws + off); off += szX;
    __hip_bfloat16* xb  = (__hip_bfloat16*)(ws + off); off += szX;
    __hip_bfloat16* Wkb = (__hip_bfloat16*)(ws + off); off += szW;
    __hip_bfloat16* Wqb = (__hip_bfloat16*)(ws + off); off += szW;
    __hip_bfloat16* Wvb = (__hip_bfloat16*)(ws + off); off += szW;
    __hip_bfloat16* Wob = (__hip_bfloat16*)(ws + off); off += szW;
    __hip_bfloat16* Zp  = (__hip_bfloat16*)(ws + off); off += szZp;
    float*          ML  = (float*)(ws + off);          off += szML;

    cast_all<<<2048 + 4 * 128, 256, 0, stream>>>(
        x_f, Wk_f, Wq_f, Wv_f, Wo_f, xb, Wkb, Wqb, Wvb, Wob);

    qkv_proj<<<dim3(128, 8, 3), 256, 0, stream>>>(xb, Wkb, Wqb, Wvb, Qb, Kb, Vt);
    attn_part<<<dim3(128, 16),  256, 0, stream>>>(Qb, Kb, Vt, Zp, ML);
    attn_combine<<<dim3(32, 16), 256, 0, stream>>>(Zp, ML, Zb);
    out_proj<<<dim3(128, 8),    256, 0, stream>>>(Zb, Wob, out);
}

// Round 7
// 282.274 us; speedup vs baseline: 2.1734x; 1.0828x over previous
//
#include <hip/hip_runtime.h>
#include <hip/hip_bf16.h>

// b=2, s=4096, d_model=512, heads=8, d_head=64. I/O f32; compute bf16 MFMA.
// attn: 32x32x16 MFMA, LDS-staged K/V (global_load_lds, dbuf, XOR-swizzle),
// swapped QK^T, in-register softmax (base-2 raw v_exp, tree reduce, defer-max),
// in-register P transpose via cvt_pk_bf16 + permlane32_swap,
// split-KV with UNIFORM 8-tile chunks (balance) + combine pass.

typedef __attribute__((ext_vector_type(4)))  float  f32x4;
typedef __attribute__((ext_vector_type(16))) float  f32x16;
typedef __attribute__((ext_vector_type(8)))  __bf16 bf16x8;
typedef __attribute__((ext_vector_type(8)))  unsigned short u16x8;
typedef __attribute__((ext_vector_type(4)))  unsigned int u32x4;

#define MFMA16(a, b, c) __builtin_amdgcn_mfma_f32_16x16x32_bf16((a), (b), (c), 0, 0, 0)
#define MFMA32(a, b, c) __builtin_amdgcn_mfma_f32_32x32x16_bf16((a), (b), (c), 0, 0, 0)
#define SWZ(g, r) ((g) ^ ((r) & 7))
#define SLOTS_BH 144   // sum over qi=0..31 of (qi>>2)+1

static __device__ __forceinline__ bf16x8 ld8(const __hip_bfloat16* p) {
    return *reinterpret_cast<const bf16x8*>(p);
}
static __device__ __forceinline__ __hip_bfloat16 tobf(float f) {
    return __float2bfloat16(f);
}
static __device__ __forceinline__ float exp2_raw(float x) {
    float r;
    asm("v_exp_f32 %0, %1" : "=v"(r) : "v"(x));
    return r;
}
static __device__ __forceinline__ unsigned cvt_pk(float lo, float hi) {
    unsigned r;
    asm("v_cvt_pk_bf16_f32 %0, %1, %2" : "=v"(r) : "v"(lo), "v"(hi));
    return r;
}
static __device__ __forceinline__ void pl32swap(unsigned& a, unsigned& b) {
    asm("v_permlane32_swap_b32 %0, %1" : "+v"(a), "+v"(b));
}
static __device__ __forceinline__ void gl_lds16(const __hip_bfloat16* g, __hip_bfloat16* l) {
    typedef __attribute__((address_space(1))) const unsigned int GU;
    typedef __attribute__((address_space(3))) unsigned int LU;
    __builtin_amdgcn_global_load_lds((GU*)(const void*)g, (LU*)(void*)l, 16, 0, 0);
}
// chunks of 8 KV-tiles; nchunks(qi) = (qi>>2)+1; slot_off = prefix sum
static __device__ __forceinline__ int slot_off(int qi) {
    const int a = qi >> 2;
    return qi + 2 * a * (a - 1) + a * (qi - 4 * a);
}

// ---------------------------------------------------------------------------
// Fused cast: f32 -> bf16 for x (2048 blocks) + 4 weights (128 blocks each).
// ---------------------------------------------------------------------------
__global__ __launch_bounds__(256) void cast_all(
    const float* __restrict__ x,  const float* __restrict__ wk,
    const float* __restrict__ wq, const float* __restrict__ wv,
    const float* __restrict__ wo,
    __hip_bfloat16* __restrict__ xb,  __hip_bfloat16* __restrict__ wkb,
    __hip_bfloat16* __restrict__ wqb, __hip_bfloat16* __restrict__ wvb,
    __hip_bfloat16* __restrict__ wob)
{
    const int bid = blockIdx.x;
    const float* src;
    __hip_bfloat16* dst;
    int base;
    if (bid < 2048) { src = x; dst = xb; base = bid; }
    else {
        const int r = (bid - 2048) >> 7;
        base = (bid - 2048) & 127;
        src = (r == 0) ? wk : (r == 1) ? wq : (r == 2) ? wv : wo;
        dst = (r == 0) ? wkb : (r == 1) ? wqb : (r == 2) ? wvb : wob;
    }
    const size_t i = (size_t)base * 256 + threadIdx.x;
    const float4 a = *reinterpret_cast<const float4*>(src + i * 8);
    const float4 b = *reinterpret_cast<const float4*>(src + i * 8 + 4);
    u16x8 o;
    o[0] = __bfloat16_as_ushort(tobf(a.x));
    o[1] = __bfloat16_as_ushort(tobf(a.y));
    o[2] = __bfloat16_as_ushort(tobf(a.z));
    o[3] = __bfloat16_as_ushort(tobf(a.w));
    o[4] = __bfloat16_as_ushort(tobf(b.x));
    o[5] = __bfloat16_as_ushort(tobf(b.y));
    o[6] = __bfloat16_as_ushort(tobf(b.z));
    o[7] = __bfloat16_as_ushort(tobf(b.w));
    *reinterpret_cast<u16x8*>(dst + i * 8) = o;
}

// ---------------------------------------------------------------------------
// qkv_proj, z-fused: grid (128 mt, 8 h). Block computes K,Q,V for 64 rows.
// x-tile read ONCE per block (was 3x). W panels stay L2-resident.
// ---------------------------------------------------------------------------
__global__ __launch_bounds__(256) void qkv_proj(
    const __hip_bfloat16* __restrict__ x,
    const __hip_bfloat16* __restrict__ Wk,
    const __hip_bfloat16* __restrict__ Wq,
    const __hip_bfloat16* __restrict__ Wv,
    __hip_bfloat16* __restrict__ Qo,   // [16][4096][64]  (pre-scaled, base-2)
    __hip_bfloat16* __restrict__ Ko,   // [16][4096][64]
    __hip_bfloat16* __restrict__ Vt)   // [16][64][4096]
{
    const int w    = threadIdx.x >> 6;
    const int lane = threadIdx.x & 63;
    const int l16  = lane & 15;
    const int lg   = lane >> 4;
    const int mt   = blockIdx.x;
    const int h    = blockIdx.y;

    const __hip_bfloat16* W0 = Wk + (size_t)h * 64 * 512;
    const __hip_bfloat16* W1 = Wq + (size_t)h * 64 * 512;
    const __hip_bfloat16* W2 = Wv + (size_t)h * 64 * 512;

    const int arow = mt * 64 + w * 16 + l16;
    const __hip_bfloat16* Ap = x + (size_t)arow * 512 + lg * 8;

    f32x4 acc[3][4] = {};
    for (int k0 = 0; k0 < 512; k0 += 32) {
        bf16x8 a = ld8(Ap + k0);
        const size_t bo = k0 + lg * 8;
#pragma unroll
        for (int nf = 0; nf < 4; ++nf) {
            const size_t ro = (size_t)(nf * 16 + l16) * 512 + bo;
            acc[0][nf] = MFMA16(a, ld8(W0 + ro), acc[0][nf]);
            acc[1][nf] = MFMA16(a, ld8(W1 + ro), acc[1][nf]);
            acc[2][nf] = MFMA16(a, ld8(W2 + ro), acc[2][nf]);
        }
    }

    const int rowbase = mt * 64 + w * 16 + lg * 4;
    // Q scale: 1/sqrt(64) * 1/ln(2)  (base-2 softmax domain)
#pragma unroll
    for (int z = 0; z < 3; ++z) {
        const float scale = (z == 1) ? 0.18033688f : 1.0f;
#pragma unroll
        for (int nf = 0; nf < 4; ++nf) {
#pragma unroll
            for (int r = 0; r < 4; ++r) {
                const int row  = rowbase + r;
                const int bq   = row >> 12;
                const int srow = row & 4095;
                const int bh   = bq * 8 + h;
                const int col  = nf * 16 + l16;
                const float v  = acc[z][nf][r] * scale;
                if (z == 2) {
                    Vt[((size_t)bh * 64 + col) * 4096 + srow] = tobf(v);
                } else if (z == 0) {
                    Ko[((size_t)bh * 4096 + srow) * 64 + col] = tobf(v);
                } else {
                    Qo[((size_t)bh * 4096 + srow) * 64 + col] = tobf(v);
                }
            }
        }
    }
}

// ---------------------------------------------------------------------------
// attn_part: grid=(256, 16): x = (31-qi)*8 + c, y = bh. 256 thr, 4 waves.
// Uniform chunks of <=8 KV tiles. Block = 128 q-rows (4 waves x 32).
// ---------------------------------------------------------------------------
__global__ __launch_bounds__(256) void attn_part(
    const __hip_bfloat16* __restrict__ Q,
    const __hip_bfloat16* __restrict__ K,
    const __hip_bfloat16* __restrict__ Vt,
    __hip_bfloat16* __restrict__ Zp,   // [slots][128 q][64 d] bf16
    float* __restrict__ ML)            // [slots][2][128]
{
    __shared__ __hip_bfloat16 Klds[2][64][64];
    __shared__ __hip_bfloat16 Vlds[2][64][64];   // V^T tile: [d][p]
    __shared__ float als[4][32];

    const int qi = 31 - ((int)blockIdx.x >> 3);   // deep q-tiles first
    const int c  = blockIdx.x & 7;
    if (c > (qi >> 2)) return;                    // beyond this row's chunks
    const int bh = blockIdx.y;

    const int w    = threadIdx.x >> 6;
    const int lane = threadIdx.x & 63;
    const int q31  = lane & 31;
    const int hi   = lane >> 5;

    const __hip_bfloat16* Qb = Q  + (size_t)bh * 4096 * 64;
    const __hip_bfloat16* Kb = K  + (size_t)bh * 4096 * 64;
    const __hip_bfloat16* Vb = Vt + (size_t)bh * 64 * 4096;

    const int qrow  = qi * 128 + w * 32 + q31;   // this lane's softmax q-row
    const int wqmax = qi * 128 + w * 32 + 31;    // wave's deepest q-row

    // Q B-fragments (col=lane&31=q, k=d)
    bf16x8 qf[4];
#pragma unroll
    for (int ks = 0; ks < 4; ++ks)
        qf[ks] = ld8(Qb + (size_t)qrow * 64 + ks * 16 + hi * 8);

    f32x16 za0 = {}, za1 = {};
    float m_s  = -3.0e38f;
    float l_ln = 0.0f;

    const int t0   = c * 8;
    const int tend = min(t0 + 8, 2 * qi + 2);
    const int nt   = tend - t0;

    // hoisted swizzled LDS byte-granule offsets (loop-invariant)
    int gsx[4];
#pragma unroll
    for (int ks = 0; ks < 4; ++ks) gsx[ks] = SWZ(2 * ks + hi, q31) * 8;

    // ---- staging: hoisted per-lane source addresses (pre-swizzled) ----
    const int r0l = w * 8 + (lane >> 3);          // local row, j=0 (j=1: +32)
    const int cg  = (lane & 7) ^ (r0l & 7);       // source granule
    const __hip_bfloat16* Ksrc = Kb + (size_t)r0l * 64 + cg * 8;
    const __hip_bfloat16* Vsrc = Vb + (size_t)r0l * 4096 + cg * 8;

    auto stage = [&](int buf, int t) {
        const int p0 = t * 64;
        gl_lds16(Ksrc + (size_t)p0 * 64,            &Klds[buf][w * 8][0]);
        gl_lds16(Ksrc + (size_t)p0 * 64 + 32 * 64,  &Klds[buf][w * 8 + 32][0]);
        gl_lds16(Vsrc + p0,                          &Vlds[buf][w * 8][0]);
        gl_lds16(Vsrc + p0 + (size_t)32 * 4096,      &Vlds[buf][w * 8 + 32][0]);
    };

    stage(0, t0);

    for (int it = 0; it < nt; ++it) {
        const int t   = t0 + it;
        const int buf = it & 1;

        asm volatile("s_waitcnt vmcnt(0)" ::: "memory");
        __syncthreads();
        if (it + 1 < nt) stage(buf ^ 1, t + 1);

        const int p0 = t * 64;
        if (p0 > wqmax) continue;   // wave fully masked (barriers stay uniform)

        const __hip_bfloat16* kb0 = &Klds[buf][q31][0];
        const __hip_bfloat16* kb1 = &Klds[buf][32 + q31][0];

        // ---- S^T = mfma(K, Q): 2 p-tiles x 4 k-slots ----
        f32x16 sa0 = {}, sa1 = {};
        __builtin_amdgcn_s_setprio(1);
#pragma unroll
        for (int ks = 0; ks < 4; ++ks) {
            bf16x8 k0 = *(const bf16x8*)(kb0 + gsx[ks]);
            bf16x8 k1 = *(const bf16x8*)(kb1 + gsx[ks]);
            sa0 = MFMA32(k0, qf[ks], sa0);
            sa1 = MFMA32(k1, qf[ks], sa1);
        }
        __builtin_amdgcn_s_setprio(0);

        // ---- causal mask (diag tiles only) ----
        if (t >= 2 * qi) {
#pragma unroll
            for (int reg = 0; reg < 16; ++reg) {
                const int pl = (reg & 3) + 8 * (reg >> 2) + 4 * hi;
                const int p  = p0 + pl;
                sa0[reg] = (p      <= qrow) ? sa0[reg] : -1.0e30f;
                sa1[reg] = (p + 32 <= qrow) ? sa1[reg] : -1.0e30f;
            }
        }

        // ---- row max: tree reduce + cross-half ----
        float tm[8];
#pragma unroll
        for (int i = 0; i < 8; ++i)
            tm[i] = fmaxf(fmaxf(sa0[i], sa0[i + 8]), fmaxf(sa1[i], sa1[i + 8]));
#pragma unroll
        for (int s = 4; s; s >>= 1)
#pragma unroll
            for (int i = 0; i < s; ++i) tm[i] = fmaxf(tm[i], tm[i + s]);
        float mx = fmaxf(tm[0], __shfl_xor(tm[0], 32));

        // ---- defer-max: rescale only when max grew past threshold ----
        if (!__all(mx <= m_s + 8.0f)) {
            const float mnew  = fmaxf(m_s, mx);
            const float alpha = exp2_raw(m_s - mnew);
            m_s = mnew;
            l_ln *= alpha;
            if (hi == 0) als[w][q31] = alpha;
#pragma unroll
            for (int reg = 0; reg < 16; ++reg) {
                const int q = (reg & 3) + 8 * (reg >> 2) + 4 * hi;
                const float av = als[w][q];
                za0[reg] *= av;
                za1[reg] *= av;
            }
        }

        // ---- P = 2^(S - m), tree l-sum ----
#pragma unroll
        for (int reg = 0; reg < 16; ++reg) {
            sa0[reg] = exp2_raw(sa0[reg] - m_s);
            sa1[reg] = exp2_raw(sa1[reg] - m_s);
        }
        float ts[8];
#pragma unroll
        for (int i = 0; i < 8; ++i)
            ts[i] = (sa0[i] + sa0[i + 8]) + (sa1[i] + sa1[i + 8]);
#pragma unroll
        for (int s = 4; s; s >>= 1)
#pragma unroll
            for (int i = 0; i < s; ++i) ts[i] += ts[i + s];
        l_ln += ts[0];

        // ---- in-register P transpose -> A-frags (cvt_pk + permlane32_swap) --
        bf16x8 pfrag[4];
#pragma unroll
        for (int kb = 0; kb < 4; ++kb) {
            const int e = (kb & 1) * 8;
            unsigned px, py, pu, pv;
            if (kb < 2) {
                px = cvt_pk(sa0[e + 0], sa0[e + 1]);
                py = cvt_pk(sa0[e + 2], sa0[e + 3]);
                pu = cvt_pk(sa0[e + 4], sa0[e + 5]);
                pv = cvt_pk(sa0[e + 6], sa0[e + 7]);
            } else {
                px = cvt_pk(sa1[e + 0], sa1[e + 1]);
                py = cvt_pk(sa1[e + 2], sa1[e + 3]);
                pu = cvt_pk(sa1[e + 4], sa1[e + 5]);
                pv = cvt_pk(sa1[e + 6], sa1[e + 7]);
            }
            pl32swap(px, pu);
            pl32swap(py, pv);
            u32x4 fw;
            fw[0] = px; fw[1] = py; fw[2] = pu; fw[3] = pv;
            pfrag[kb] = __builtin_bit_cast(bf16x8, fw);
        }

        const __hip_bfloat16* vb0 = &Vlds[buf][q31][0];
        const __hip_bfloat16* vb1 = &Vlds[buf][32 + q31][0];

        // ---- Z += P V (A=P row=q, B=V^T col=d) ----
        __builtin_amdgcn_s_setprio(1);
#pragma unroll
        for (int kb = 0; kb < 4; ++kb) {
            bf16x8 v0 = *(const bf16x8*)(vb0 + gsx[kb]);
            bf16x8 v1 = *(const bf16x8*)(vb1 + gsx[kb]);
            za0 = MFMA32(pfrag[kb], v0, za0);
            za1 = MFMA32(pfrag[kb], v1, za1);
        }
        __builtin_amdgcn_s_setprio(0);
    }

    // ---- epilogue ----
    float lt = l_ln + __shfl_xor(l_ln, 32);
    const int slot = bh * SLOTS_BH + slot_off(qi) + c;
    if (hi == 0) {
        ML[(size_t)slot * 256 +       w * 32 + q31] = m_s;
        ML[(size_t)slot * 256 + 128 + w * 32 + q31] = lt;
    }
#pragma unroll
    for (int reg = 0; reg < 16; ++reg) {
        const int q = (reg & 3) + 8 * (reg >> 2) + 4 * hi;
        const size_t base = (size_t)slot * 8192 + (size_t)(w * 32 + q) * 64 + q31;
        Zp[base]      = tobf(za0[reg]);
        Zp[base + 32] = tobf(za1[reg]);
    }
}

// ---------------------------------------------------------------------------
// attn_combine: grid=(32 qi, 16 bh), block 256. thread: q=tid>>1, half=tid&1.
// Two passes over ML (no runtime-indexed register arrays).
// ---------------------------------------------------------------------------
__global__ __launch_bounds__(256) void attn_combine(
    const __hip_bfloat16* __restrict__ Zp,
    const float* __restrict__ ML,
    __hip_bfloat16* __restrict__ Z)    // [b][s][h*64]
{
    const int qi = blockIdx.x;
    const int bh = blockIdx.y;
    const int nc = (qi >> 2) + 1;
    const int q    = threadIdx.x >> 1;
    const int half = threadIdx.x & 1;

    const int slot0 = bh * SLOTS_BH + slot_off(qi);

    float M = -3.0e38f;
    for (int i = 0; i < nc; ++i)
        M = fmaxf(M, ML[(size_t)(slot0 + i) * 256 + q]);

    float L = 0.0f;
    float acc[32];
#pragma unroll
    for (int j = 0; j < 32; ++j) acc[j] = 0.0f;

    for (int i = 0; i < nc; ++i) {
        const float wgt = exp2_raw(ML[(size_t)(slot0 + i) * 256 + q] - M);
        L += wgt * ML[(size_t)(slot0 + i) * 256 + 128 + q];
        const __hip_bfloat16* zp =
            Zp + (size_t)(slot0 + i) * 8192 + (size_t)q * 64 + half * 32;
#pragma unroll
        for (int v = 0; v < 4; ++v) {
            bf16x8 z = ld8(zp + v * 8);
#pragma unroll
            for (int j = 0; j < 8; ++j) acc[v * 8 + j] += wgt * (float)z[j];
        }
    }

    const float inv = 1.0f / L;
    const int b = bh >> 3, h = bh & 7;
    __hip_bfloat16* zo =
        Z + ((size_t)b * 4096 + qi * 128 + q) * 512 + h * 64 + half * 32;
#pragma unroll
    for (int v = 0; v < 4; ++v) {
        u16x8 o;
#pragma unroll
        for (int j = 0; j < 8; ++j)
            o[j] = __bfloat16_as_ushort(tobf(acc[v * 8 + j] * inv));
        *reinterpret_cast<u16x8*>(zo + v * 8) = o;
    }
}

// ---------------------------------------------------------------------------
// out_proj: grid (128 mt, 2 ny), BN=256. A-panel read once per 256 cols.
// ---------------------------------------------------------------------------
__global__ __launch_bounds__(256) void out_proj(
    const __hip_bfloat16* __restrict__ Zf,   // [8192][512]
    const __hip_bfloat16* __restrict__ Wo,   // [512][512] bf16
    float* __restrict__ out)                 // [8192][512] f32
{
    const int w    = threadIdx.x >> 6;
    const int lane = threadIdx.x & 63;
    const int l16  = lane & 15;
    const int lg   = lane >> 4;
    const int r0   = blockIdx.x * 64 + w * 16;
    const int n0   = blockIdx.y * 256;

    f32x4 acc[16] = {};
    const __hip_bfloat16* Ap = Zf + (size_t)(r0 + l16) * 512 + lg * 8;
    for (int k0 = 0; k0 < 512; k0 += 32) {
        bf16x8 a = ld8(Ap + k0);
        const size_t bo = k0 + lg * 8;
#pragma unroll
        for (int nf = 0; nf < 16; ++nf) {
            bf16x8 b = ld8(Wo + (size_t)(n0 + nf * 16 + l16) * 512 + bo);
            acc[nf] = MFMA16(a, b, acc[nf]);
        }
    }
#pragma unroll
    for (int nf = 0; nf < 16; ++nf)
#pragma unroll
        for (int r = 0; r < 4; ++r)
            out[(size_t)(r0 + lg * 4 + r) * 512 + n0 + nf * 16 + l16] = acc[nf][r];
}

// ---------------------------------------------------------------------------
extern "C" void kernel_launch(void* const* d_in, const int* in_sizes, int n_in,
                              void* d_out, int out_size, void* d_ws, size_t ws_size,
                              hipStream_t stream)
{
    const float* x_f  = (const float*)d_in[0];
    const float* Wk_f = (const float*)d_in[1];
    const float* Wq_f = (const float*)d_in[2];
    const float* Wv_f = (const float*)d_in[3];
    const float* Wo_f = (const float*)d_in[4];
    float* out = (float*)d_out;

    char* ws = (char*)d_ws;
    const size_t szQKV = (size_t)16 * 4096 * 64 * sizeof(__hip_bfloat16);   // 8.39 MB
    const size_t szX   = (size_t)8192 * 512 * sizeof(__hip_bfloat16);       // 8.39 MB
    const size_t szW   = (size_t)8 * 64 * 512 * sizeof(__hip_bfloat16);     // 0.5 MB
    const size_t szZp  = (size_t)16 * SLOTS_BH * 128 * 64 * sizeof(__hip_bfloat16); // 37.7 MB
    const size_t szML  = (size_t)16 * SLOTS_BH * 256 * sizeof(float);       // 2.36 MB

    // persistent region
    size_t off = 0;
    __hip_bfloat16* Qb  = (__hip_bfloat16*)(ws + off); off += szQKV;
    __hip_bfloat16* Kb  = (__hip_bfloat16*)(ws + off); off += szQKV;
    __hip_bfloat16* Vt  = (__hip_bfloat16*)(ws + off); off += szQKV;
    __hip_bfloat16* Zb  = (__hip_bfloat16*)(ws + off); off += szX;
    __hip_bfloat16* Wob = (__hip_bfloat16*)(ws + off); off += szW;
    // transient region 1 (dead after qkv_proj): xb + Wk/Wq/Wv casts
    const size_t trans = off;
    __hip_bfloat16* xb  = (__hip_bfloat16*)(ws + trans);
    __hip_bfloat16* Wkb = (__hip_bfloat16*)(ws + trans + szX);
    __hip_bfloat16* Wqb = (__hip_bfloat16*)(ws + trans + szX + szW);
    __hip_bfloat16* Wvb = (__hip_bfloat16*)(ws + trans + szX + 2 * szW);
    // transient region 2 (attention partials) ALIASES region 1
    __hip_bfloat16* Zp  = (__hip_bfloat16*)(ws + trans);
    float*          ML  = (float*)(ws + trans + szZp);

    cast_all<<<2048 + 4 * 128, 256, 0, stream>>>(
        x_f, Wk_f, Wq_f, Wv_f, Wo_f, xb, Wkb, Wqb, Wvb, Wob);

    qkv_proj<<<dim3(128, 8),  256, 0, stream>>>(xb, Wkb, Wqb, Wvb, Qb, Kb, Vt);
    attn_part<<<dim3(256, 16), 256, 0, stream>>>(Qb, Kb, Vt, Zp, ML);
    attn_combine<<<dim3(32, 16), 256, 0, stream>>>(Zp, ML, Zb);
    out_proj<<<dim3(128, 2),  256, 0, stream>>>(Zb, Wob, out);
}

// Round 8
// 229.972 us; speedup vs baseline: 2.6677x; 1.2274x over previous
//
#include <hip/hip_runtime.h>
#include <hip/hip_bf16.h>

// b=2, s=4096, d_model=512, heads=8, d_head=64. I/O f32; compute bf16 MFMA.
// attn: 8-wave 256-q blocks, 32x32x16 MFMA, LDS-staged K/V (global_load_lds,
// dbuf, XOR-swizzle), swapped QK^T, in-register softmax (base-2 raw v_exp,
// tree reduce, defer-max), in-register P transpose (cvt_pk + permlane32_swap),
// split-KV chunks of 16 tiles, direct write for single-chunk rows.

typedef __attribute__((ext_vector_type(4)))  float  f32x4;
typedef __attribute__((ext_vector_type(16))) float  f32x16;
typedef __attribute__((ext_vector_type(8)))  __bf16 bf16x8;
typedef __attribute__((ext_vector_type(8)))  unsigned short u16x8;
typedef __attribute__((ext_vector_type(4)))  unsigned int u32x4;

#define MFMA16(a, b, c) __builtin_amdgcn_mfma_f32_16x16x32_bf16((a), (b), (c), 0, 0, 0)
#define MFMA32(a, b, c) __builtin_amdgcn_mfma_f32_32x32x16_bf16((a), (b), (c), 0, 0, 0)
#define SWZ(g, r) ((g) ^ ((r) & 7))
#define SLOTS_BH 40   // sum over qi=0..15 of (qi>>2)+1

static __device__ __forceinline__ bf16x8 ld8(const __hip_bfloat16* p) {
    return *reinterpret_cast<const bf16x8*>(p);
}
static __device__ __forceinline__ __hip_bfloat16 tobf(float f) {
    return __float2bfloat16(f);
}
static __device__ __forceinline__ float exp2_raw(float x) {
    float r;
    asm("v_exp_f32 %0, %1" : "=v"(r) : "v"(x));
    return r;
}
static __device__ __forceinline__ unsigned cvt_pk(float lo, float hi) {
    unsigned r;
    asm("v_cvt_pk_bf16_f32 %0, %1, %2" : "=v"(r) : "v"(lo), "v"(hi));
    return r;
}
static __device__ __forceinline__ void pl32swap(unsigned& a, unsigned& b) {
    asm("v_permlane32_swap_b32 %0, %1" : "+v"(a), "+v"(b));
}
static __device__ __forceinline__ void gl_lds16(const __hip_bfloat16* g, __hip_bfloat16* l) {
    typedef __attribute__((address_space(1))) const unsigned int GU;
    typedef __attribute__((address_space(3))) unsigned int LU;
    __builtin_amdgcn_global_load_lds((GU*)(const void*)g, (LU*)(void*)l, 16, 0, 0);
}
// chunks of 16 KV-tiles over 256-row q-tiles; nchunks(qi) = (qi>>2)+1
static __device__ __forceinline__ int slot_off(int qi) {
    const int a = qi >> 2;
    return qi + 2 * a * (a - 1) + a * (qi & 3);
}

// ---------------------------------------------------------------------------
// Fused cast: f32 -> bf16 for x (2048 blocks) + 4 weights (128 blocks each).
// ---------------------------------------------------------------------------
__global__ __launch_bounds__(256) void cast_all(
    const float* __restrict__ x,  const float* __restrict__ wk,
    const float* __restrict__ wq, const float* __restrict__ wv,
    const float* __restrict__ wo,
    __hip_bfloat16* __restrict__ xb,  __hip_bfloat16* __restrict__ wkb,
    __hip_bfloat16* __restrict__ wqb, __hip_bfloat16* __restrict__ wvb,
    __hip_bfloat16* __restrict__ wob)
{
    const int bid = blockIdx.x;
    const float* src;
    __hip_bfloat16* dst;
    int base;
    if (bid < 2048) { src = x; dst = xb; base = bid; }
    else {
        const int r = (bid - 2048) >> 7;
        base = (bid - 2048) & 127;
        src = (r == 0) ? wk : (r == 1) ? wq : (r == 2) ? wv : wo;
        dst = (r == 0) ? wkb : (r == 1) ? wqb : (r == 2) ? wvb : wob;
    }
    const size_t i = (size_t)base * 256 + threadIdx.x;
    const float4 a = *reinterpret_cast<const float4*>(src + i * 8);
    const float4 b = *reinterpret_cast<const float4*>(src + i * 8 + 4);
    u16x8 o;
    o[0] = __bfloat16_as_ushort(tobf(a.x));
    o[1] = __bfloat16_as_ushort(tobf(a.y));
    o[2] = __bfloat16_as_ushort(tobf(a.z));
    o[3] = __bfloat16_as_ushort(tobf(a.w));
    o[4] = __bfloat16_as_ushort(tobf(b.x));
    o[5] = __bfloat16_as_ushort(tobf(b.y));
    o[6] = __bfloat16_as_ushort(tobf(b.z));
    o[7] = __bfloat16_as_ushort(tobf(b.w));
    *reinterpret_cast<u16x8*>(dst + i * 8) = o;
}

// ---------------------------------------------------------------------------
// qkv_proj, z-fused: grid (128 mt, 8 h). Block computes K,Q,V for 64 rows.
// ---------------------------------------------------------------------------
__global__ __launch_bounds__(256) void qkv_proj(
    const __hip_bfloat16* __restrict__ x,
    const __hip_bfloat16* __restrict__ Wk,
    const __hip_bfloat16* __restrict__ Wq,
    const __hip_bfloat16* __restrict__ Wv,
    __hip_bfloat16* __restrict__ Qo,   // [16][4096][64]  (pre-scaled, base-2)
    __hip_bfloat16* __restrict__ Ko,   // [16][4096][64]
    __hip_bfloat16* __restrict__ Vt)   // [16][64][4096]
{
    const int w    = threadIdx.x >> 6;
    const int lane = threadIdx.x & 63;
    const int l16  = lane & 15;
    const int lg   = lane >> 4;
    const int mt   = blockIdx.x;
    const int h    = blockIdx.y;

    const __hip_bfloat16* W0 = Wk + (size_t)h * 64 * 512;
    const __hip_bfloat16* W1 = Wq + (size_t)h * 64 * 512;
    const __hip_bfloat16* W2 = Wv + (size_t)h * 64 * 512;

    const int arow = mt * 64 + w * 16 + l16;
    const __hip_bfloat16* Ap = x + (size_t)arow * 512 + lg * 8;

    f32x4 acc[3][4] = {};
    for (int k0 = 0; k0 < 512; k0 += 32) {
        bf16x8 a = ld8(Ap + k0);
        const size_t bo = k0 + lg * 8;
#pragma unroll
        for (int nf = 0; nf < 4; ++nf) {
            const size_t ro = (size_t)(nf * 16 + l16) * 512 + bo;
            acc[0][nf] = MFMA16(a, ld8(W0 + ro), acc[0][nf]);
            acc[1][nf] = MFMA16(a, ld8(W1 + ro), acc[1][nf]);
            acc[2][nf] = MFMA16(a, ld8(W2 + ro), acc[2][nf]);
        }
    }

    const int rowbase = mt * 64 + w * 16 + lg * 4;
#pragma unroll
    for (int z = 0; z < 3; ++z) {
        const float scale = (z == 1) ? 0.18033688f : 1.0f;  // 0.125 / ln2
#pragma unroll
        for (int nf = 0; nf < 4; ++nf) {
#pragma unroll
            for (int r = 0; r < 4; ++r) {
                const int row  = rowbase + r;
                const int bq   = row >> 12;
                const int srow = row & 4095;
                const int bh   = bq * 8 + h;
                const int col  = nf * 16 + l16;
                const float v  = acc[z][nf][r] * scale;
                if (z == 2) {
                    Vt[((size_t)bh * 64 + col) * 4096 + srow] = tobf(v);
                } else if (z == 0) {
                    Ko[((size_t)bh * 4096 + srow) * 64 + col] = tobf(v);
                } else {
                    Qo[((size_t)bh * 4096 + srow) * 64 + col] = tobf(v);
                }
            }
        }
    }
}

// ---------------------------------------------------------------------------
// attn_part: grid=(40, 16) flat deep-first (no empty blocks), 512 thr, 8 waves.
// Block = 256 q-rows (8 waves x 32). KV tile 64; chunk = up to 16 tiles.
// Rows with nc==1 (qi<=3) are normalized and written directly to Z.
// ---------------------------------------------------------------------------
__global__ __launch_bounds__(512) void attn_part(
    const __hip_bfloat16* __restrict__ Q,
    const __hip_bfloat16* __restrict__ K,
    const __hip_bfloat16* __restrict__ Vt,
    __hip_bfloat16* __restrict__ Zp,   // [slots][256 q][64 d] bf16
    float* __restrict__ ML,            // [slots][2][256]
    __hip_bfloat16* __restrict__ Z)    // [b][s][h*64] direct path
{
    __shared__ __hip_bfloat16 Klds[2][64][64];
    __shared__ __hip_bfloat16 Vlds[2][64][64];   // V^T tile: [d][p]
    __shared__ float als[8][32];

    // flat blockIdx.x -> (qi deep-first, chunk c)
    int rem = blockIdx.x, qi = 15, nc;
    for (;;) { nc = (qi >> 2) + 1; if (rem < nc) break; rem -= nc; --qi; }
    const int c  = rem;
    const int bh = blockIdx.y;

    const int w    = threadIdx.x >> 6;    // 0..7
    const int lane = threadIdx.x & 63;
    const int q31  = lane & 31;
    const int hi   = lane >> 5;

    const __hip_bfloat16* Qb = Q  + (size_t)bh * 4096 * 64;
    const __hip_bfloat16* Kb = K  + (size_t)bh * 4096 * 64;
    const __hip_bfloat16* Vb = Vt + (size_t)bh * 64 * 4096;

    const int wbase = qi * 256 + w * 32;   // wave's first q-row
    const int qrow  = wbase + q31;         // this lane's softmax q-row
    const int wqmax = wbase + 31;          // wave's deepest q-row

    // Q B-fragments (col=lane&31=q, k=d)
    bf16x8 qf[4];
#pragma unroll
    for (int ks = 0; ks < 4; ++ks)
        qf[ks] = ld8(Qb + (size_t)qrow * 64 + ks * 16 + hi * 8);

    f32x16 za0 = {}, za1 = {};
    float m_s  = -3.0e38f;
    float l_ln = 0.0f;

    const int t0   = c * 16;
    const int tend = min(t0 + 16, 4 * qi + 4);
    const int nt   = tend - t0;

    // hoisted swizzled LDS byte-granule offsets (loop-invariant)
    int gsx[4];
#pragma unroll
    for (int ks = 0; ks < 4; ++ks) gsx[ks] = SWZ(2 * ks + hi, q31) * 8;

    // ---- staging: wave w owns rows [w*8, w*8+8) of K and V^T tiles ----
    const int r0l = w * 8 + (lane >> 3);
    const int cg  = (lane & 7) ^ (r0l & 7);       // pre-swizzled source granule
    const __hip_bfloat16* Ksrc = Kb + (size_t)r0l * 64 + cg * 8;
    const __hip_bfloat16* Vsrc = Vb + (size_t)r0l * 4096 + cg * 8;

    auto stage = [&](int buf, int t) {
        const int p0 = t * 64;
        gl_lds16(Ksrc + (size_t)p0 * 64, &Klds[buf][w * 8][0]);
        gl_lds16(Vsrc + p0,              &Vlds[buf][w * 8][0]);
    };

    stage(0, t0);

    for (int it = 0; it < nt; ++it) {
        const int t   = t0 + it;
        const int buf = it & 1;

        asm volatile("s_waitcnt vmcnt(0)" ::: "memory");
        __syncthreads();
        if (it + 1 < nt) stage(buf ^ 1, t + 1);

        const int p0 = t * 64;
        if (p0 > wqmax) continue;   // wave fully masked (barriers stay uniform)

        const __hip_bfloat16* kb0 = &Klds[buf][q31][0];
        const __hip_bfloat16* kb1 = &Klds[buf][32 + q31][0];

        // ---- S^T = mfma(K, Q): 2 p-tiles x 4 k-slots ----
        f32x16 sa0 = {}, sa1 = {};
        __builtin_amdgcn_s_setprio(1);
#pragma unroll
        for (int ks = 0; ks < 4; ++ks) {
            bf16x8 k0 = *(const bf16x8*)(kb0 + gsx[ks]);
            bf16x8 k1 = *(const bf16x8*)(kb1 + gsx[ks]);
            sa0 = MFMA32(k0, qf[ks], sa0);
            sa1 = MFMA32(k1, qf[ks], sa1);
        }
        __builtin_amdgcn_s_setprio(0);

        // ---- causal mask (only where tile crosses this wave's diagonal) ----
        if (p0 + 63 > wbase) {
#pragma unroll
            for (int reg = 0; reg < 16; ++reg) {
                const int pl = (reg & 3) + 8 * (reg >> 2) + 4 * hi;
                const int p  = p0 + pl;
                sa0[reg] = (p      <= qrow) ? sa0[reg] : -1.0e30f;
                sa1[reg] = (p + 32 <= qrow) ? sa1[reg] : -1.0e30f;
            }
        }

        // ---- row max: tree reduce + cross-half ----
        float tm[8];
#pragma unroll
        for (int i = 0; i < 8; ++i)
            tm[i] = fmaxf(fmaxf(sa0[i], sa0[i + 8]), fmaxf(sa1[i], sa1[i + 8]));
#pragma unroll
        for (int s = 4; s; s >>= 1)
#pragma unroll
            for (int i = 0; i < s; ++i) tm[i] = fmaxf(tm[i], tm[i + s]);
        float mx = fmaxf(tm[0], __shfl_xor(tm[0], 32));

        // ---- defer-max: rescale only when max grew past threshold ----
        if (!__all(mx <= m_s + 8.0f)) {
            const float mnew  = fmaxf(m_s, mx);
            const float alpha = exp2_raw(m_s - mnew);
            m_s = mnew;
            l_ln *= alpha;
            if (hi == 0) als[w][q31] = alpha;
#pragma unroll
            for (int reg = 0; reg < 16; ++reg) {
                const int q = (reg & 3) + 8 * (reg >> 2) + 4 * hi;
                const float av = als[w][q];
                za0[reg] *= av;
                za1[reg] *= av;
            }
        }

        // ---- P = 2^(S - m), tree l-sum ----
#pragma unroll
        for (int reg = 0; reg < 16; ++reg) {
            sa0[reg] = exp2_raw(sa0[reg] - m_s);
            sa1[reg] = exp2_raw(sa1[reg] - m_s);
        }
        float ts[8];
#pragma unroll
        for (int i = 0; i < 8; ++i)
            ts[i] = (sa0[i] + sa0[i + 8]) + (sa1[i] + sa1[i + 8]);
#pragma unroll
        for (int s = 4; s; s >>= 1)
#pragma unroll
            for (int i = 0; i < s; ++i) ts[i] += ts[i + s];
        l_ln += ts[0];

        // ---- in-register P transpose -> A-frags (cvt_pk + permlane32_swap) --
        bf16x8 pfrag[4];
#pragma unroll
        for (int kb = 0; kb < 4; ++kb) {
            const int e = (kb & 1) * 8;
            unsigned px, py, pu, pv;
            if (kb < 2) {
                px = cvt_pk(sa0[e + 0], sa0[e + 1]);
                py = cvt_pk(sa0[e + 2], sa0[e + 3]);
                pu = cvt_pk(sa0[e + 4], sa0[e + 5]);
                pv = cvt_pk(sa0[e + 6], sa0[e + 7]);
            } else {
                px = cvt_pk(sa1[e + 0], sa1[e + 1]);
                py = cvt_pk(sa1[e + 2], sa1[e + 3]);
                pu = cvt_pk(sa1[e + 4], sa1[e + 5]);
                pv = cvt_pk(sa1[e + 6], sa1[e + 7]);
            }
            pl32swap(px, pu);
            pl32swap(py, pv);
            u32x4 fw;
            fw[0] = px; fw[1] = py; fw[2] = pu; fw[3] = pv;
            pfrag[kb] = __builtin_bit_cast(bf16x8, fw);
        }

        const __hip_bfloat16* vb0 = &Vlds[buf][q31][0];
        const __hip_bfloat16* vb1 = &Vlds[buf][32 + q31][0];

        // ---- Z += P V (A=P row=q, B=V^T col=d) ----
        __builtin_amdgcn_s_setprio(1);
#pragma unroll
        for (int kb = 0; kb < 4; ++kb) {
            bf16x8 v0 = *(const bf16x8*)(vb0 + gsx[kb]);
            bf16x8 v1 = *(const bf16x8*)(vb1 + gsx[kb]);
            za0 = MFMA32(pfrag[kb], v0, za0);
            za1 = MFMA32(pfrag[kb], v1, za1);
        }
        __builtin_amdgcn_s_setprio(0);
    }

    // ---- epilogue ----
    float lt = l_ln + __shfl_xor(l_ln, 32);

    if (nc == 1) {
        // single-chunk row: normalize and write straight to Z
        if (hi == 0) als[w][q31] = 1.0f / lt;
        const int b = bh >> 3, h = bh & 7;
#pragma unroll
        for (int reg = 0; reg < 16; ++reg) {
            const int q = (reg & 3) + 8 * (reg >> 2) + 4 * hi;
            const float inv = als[w][q];
            __hip_bfloat16* zo =
                Z + ((size_t)b * 4096 + qi * 256 + w * 32 + q) * 512 + h * 64 + q31;
            zo[0]  = tobf(za0[reg] * inv);
            zo[32] = tobf(za1[reg] * inv);
        }
    } else {
        const int slot = bh * SLOTS_BH + slot_off(qi) + c;
        if (hi == 0) {
            ML[(size_t)slot * 512 +       w * 32 + q31] = m_s;
            ML[(size_t)slot * 512 + 256 + w * 32 + q31] = lt;
        }
#pragma unroll
        for (int reg = 0; reg < 16; ++reg) {
            const int q = (reg & 3) + 8 * (reg >> 2) + 4 * hi;
            const size_t base =
                (size_t)slot * 16384 + (size_t)(w * 32 + q) * 64 + q31;
            Zp[base]      = tobf(za0[reg]);
            Zp[base + 32] = tobf(za1[reg]);
        }
    }
}

// ---------------------------------------------------------------------------
// attn_combine: grid=(12 qi-4, 16 bh), 512 thr. q = tid>>1, half = tid&1.
// ---------------------------------------------------------------------------
__global__ __launch_bounds__(512) void attn_combine(
    const __hip_bfloat16* __restrict__ Zp,
    const float* __restrict__ ML,
    __hip_bfloat16* __restrict__ Z)    // [b][s][h*64]
{
    const int qi = blockIdx.x + 4;
    const int bh = blockIdx.y;
    const int nc = (qi >> 2) + 1;
    const int q    = threadIdx.x >> 1;
    const int half = threadIdx.x & 1;

    const int slot0 = bh * SLOTS_BH + slot_off(qi);

    float M = -3.0e38f;
    for (int i = 0; i < nc; ++i)
        M = fmaxf(M, ML[(size_t)(slot0 + i) * 512 + q]);

    float L = 0.0f;
    float acc[32];
#pragma unroll
    for (int j = 0; j < 32; ++j) acc[j] = 0.0f;

    for (int i = 0; i < nc; ++i) {
        const float wgt = exp2_raw(ML[(size_t)(slot0 + i) * 512 + q] - M);
        L += wgt * ML[(size_t)(slot0 + i) * 512 + 256 + q];
        const __hip_bfloat16* zp =
            Zp + (size_t)(slot0 + i) * 16384 + (size_t)q * 64 + half * 32;
#pragma unroll
        for (int v = 0; v < 4; ++v) {
            bf16x8 z = ld8(zp + v * 8);
#pragma unroll
            for (int j = 0; j < 8; ++j) acc[v * 8 + j] += wgt * (float)z[j];
        }
    }

    const float inv = 1.0f / L;
    const int b = bh >> 3, h = bh & 7;
    __hip_bfloat16* zo =
        Z + ((size_t)b * 4096 + qi * 256 + q) * 512 + h * 64 + half * 32;
#pragma unroll
    for (int v = 0; v < 4; ++v) {
        u16x8 o;
#pragma unroll
        for (int j = 0; j < 8; ++j)
            o[j] = __bfloat16_as_ushort(tobf(acc[v * 8 + j] * inv));
        *reinterpret_cast<u16x8*>(zo + v * 8) = o;
    }
}

// ---------------------------------------------------------------------------
// out_proj: grid (128 mt, 2 ny), BN=256.
// ---------------------------------------------------------------------------
__global__ __launch_bounds__(256) void out_proj(
    const __hip_bfloat16* __restrict__ Zf,   // [8192][512]
    const __hip_bfloat16* __restrict__ Wo,   // [512][512] bf16
    float* __restrict__ out)                 // [8192][512] f32
{
    const int w    = threadIdx.x >> 6;
    const int lane = threadIdx.x & 63;
    const int l16  = lane & 15;
    const int lg   = lane >> 4;
    const int r0   = blockIdx.x * 64 + w * 16;
    const int n0   = blockIdx.y * 256;

    f32x4 acc[16] = {};
    const __hip_bfloat16* Ap = Zf + (size_t)(r0 + l16) * 512 + lg * 8;
    for (int k0 = 0; k0 < 512; k0 += 32) {
        bf16x8 a = ld8(Ap + k0);
        const size_t bo = k0 + lg * 8;
#pragma unroll
        for (int nf = 0; nf < 16; ++nf) {
            bf16x8 b = ld8(Wo + (size_t)(n0 + nf * 16 + l16) * 512 + bo);
            acc[nf] = MFMA16(a, b, acc[nf]);
        }
    }
#pragma unroll
    for (int nf = 0; nf < 16; ++nf)
#pragma unroll
        for (int r = 0; r < 4; ++r)
            out[(size_t)(r0 + lg * 4 + r) * 512 + n0 + nf * 16 + l16] = acc[nf][r];
}

// ---------------------------------------------------------------------------
extern "C" void kernel_launch(void* const* d_in, const int* in_sizes, int n_in,
                              void* d_out, int out_size, void* d_ws, size_t ws_size,
                              hipStream_t stream)
{
    const float* x_f  = (const float*)d_in[0];
    const float* Wk_f = (const float*)d_in[1];
    const float* Wq_f = (const float*)d_in[2];
    const float* Wv_f = (const float*)d_in[3];
    const float* Wo_f = (const float*)d_in[4];
    float* out = (float*)d_out;

    char* ws = (char*)d_ws;
    const size_t szQKV = (size_t)16 * 4096 * 64 * sizeof(__hip_bfloat16);   // 8.39 MB
    const size_t szX   = (size_t)8192 * 512 * sizeof(__hip_bfloat16);       // 8.39 MB
    const size_t szW   = (size_t)8 * 64 * 512 * sizeof(__hip_bfloat16);     // 0.5 MB
    const size_t szZp  = (size_t)16 * SLOTS_BH * 256 * 64 * sizeof(__hip_bfloat16); // 21 MB
    const size_t szML  = (size_t)16 * SLOTS_BH * 512 * sizeof(float);       // 1.3 MB

    // persistent region
    size_t off = 0;
    __hip_bfloat16* Qb  = (__hip_bfloat16*)(ws + off); off += szQKV;
    __hip_bfloat16* Kb  = (__hip_bfloat16*)(ws + off); off += szQKV;
    __hip_bfloat16* Vt  = (__hip_bfloat16*)(ws + off); off += szQKV;
    __hip_bfloat16* Zb  = (__hip_bfloat16*)(ws + off); off += szX;
    __hip_bfloat16* Wob = (__hip_bfloat16*)(ws + off); off += szW;
    // transient region 1 (dead after qkv_proj): xb + Wk/Wq/Wv casts
    const size_t trans = off;
    __hip_bfloat16* xb  = (__hip_bfloat16*)(ws + trans);
    __hip_bfloat16* Wkb = (__hip_bfloat16*)(ws + trans + szX);
    __hip_bfloat16* Wqb = (__hip_bfloat16*)(ws + trans + szX + szW);
    __hip_bfloat16* Wvb = (__hip_bfloat16*)(ws + trans + szX + 2 * szW);
    // transient region 2 (attention partials) ALIASES region 1
    __hip_bfloat16* Zp  = (__hip_bfloat16*)(ws + trans);
    float*          ML  = (float*)(ws + trans + szZp);

    cast_all<<<2048 + 4 * 128, 256, 0, stream>>>(
        x_f, Wk_f, Wq_f, Wv_f, Wo_f, xb, Wkb, Wqb, Wvb, Wob);

    qkv_proj<<<dim3(128, 8),   256, 0, stream>>>(xb, Wkb, Wqb, Wvb, Qb, Kb, Vt);
    attn_part<<<dim3(40, 16),  512, 0, stream>>>(Qb, Kb, Vt, Zp, ML, Zb);
    attn_combine<<<dim3(12, 16), 512, 0, stream>>>(Zp, ML, Zb);
    out_proj<<<dim3(128, 2),   256, 0, stream>>>(Zb, Wob, out);
}

// Round 9
// 143.285 us; speedup vs baseline: 4.2816x; 1.6050x over previous
//
#include <hip/hip_runtime.h>
#include <hip/hip_bf16.h>

// b=2, s=4096, d_model=512, heads=8, d_head=64. I/O f32; compute bf16 MFMA.
// qkv: LDS-staged 128x128x64 GEMM over [8192x512]@[512x1536]^T (z-major N).
// attn: 8-wave 256-q blocks, 32x32x16 MFMA, LDS K/V (gload_lds, dbuf, XOR swz),
// swapped QK^T, in-register softmax (raw v_exp base-2, tree reduce, defer-max),
// in-register P transpose (cvt_pk + permlane32_swap), split-KV 16-tile chunks.

typedef __attribute__((ext_vector_type(4)))  float  f32x4;
typedef __attribute__((ext_vector_type(16))) float  f32x16;
typedef __attribute__((ext_vector_type(8)))  __bf16 bf16x8;
typedef __attribute__((ext_vector_type(8)))  unsigned short u16x8;
typedef __attribute__((ext_vector_type(4)))  unsigned int u32x4;

#define MFMA16(a, b, c) __builtin_amdgcn_mfma_f32_16x16x32_bf16((a), (b), (c), 0, 0, 0)
#define MFMA32(a, b, c) __builtin_amdgcn_mfma_f32_32x32x16_bf16((a), (b), (c), 0, 0, 0)
#define SWZ(g, r) ((g) ^ ((r) & 7))
#define SLOTS_BH 40   // sum over qi=0..15 of (qi>>2)+1

static __device__ __forceinline__ bf16x8 ld8(const __hip_bfloat16* p) {
    return *reinterpret_cast<const bf16x8*>(p);
}
static __device__ __forceinline__ __hip_bfloat16 tobf(float f) {
    return __float2bfloat16(f);
}
static __device__ __forceinline__ float exp2_raw(float x) {
    float r;
    asm("v_exp_f32 %0, %1" : "=v"(r) : "v"(x));
    return r;
}
static __device__ __forceinline__ unsigned cvt_pk(float lo, float hi) {
    unsigned r;
    asm("v_cvt_pk_bf16_f32 %0, %1, %2" : "=v"(r) : "v"(lo), "v"(hi));
    return r;
}
static __device__ __forceinline__ void pl32swap(unsigned& a, unsigned& b) {
    asm("v_permlane32_swap_b32 %0, %1" : "+v"(a), "+v"(b));
}
static __device__ __forceinline__ void gl_lds16(const __hip_bfloat16* g, __hip_bfloat16* l) {
    typedef __attribute__((address_space(1))) const unsigned int GU;
    typedef __attribute__((address_space(3))) unsigned int LU;
    __builtin_amdgcn_global_load_lds((GU*)(const void*)g, (LU*)(void*)l, 16, 0, 0);
}
// chunks of 16 KV-tiles over 256-row q-tiles; nchunks(qi) = (qi>>2)+1
static __device__ __forceinline__ int slot_off(int qi) {
    const int a = qi >> 2;
    return qi + 2 * a * (a - 1) + a * (qi & 3);
}

// ---------------------------------------------------------------------------
// Fused cast: f32 -> bf16 for x (2048 blocks) + 4 weights (128 blocks each).
// ---------------------------------------------------------------------------
__global__ __launch_bounds__(256) void cast_all(
    const float* __restrict__ x,  const float* __restrict__ wk,
    const float* __restrict__ wq, const float* __restrict__ wv,
    const float* __restrict__ wo,
    __hip_bfloat16* __restrict__ xb,  __hip_bfloat16* __restrict__ wkb,
    __hip_bfloat16* __restrict__ wqb, __hip_bfloat16* __restrict__ wvb,
    __hip_bfloat16* __restrict__ wob)
{
    const int bid = blockIdx.x;
    const float* src;
    __hip_bfloat16* dst;
    int base;
    if (bid < 2048) { src = x; dst = xb; base = bid; }
    else {
        const int r = (bid - 2048) >> 7;
        base = (bid - 2048) & 127;
        src = (r == 0) ? wk : (r == 1) ? wq : (r == 2) ? wv : wo;
        dst = (r == 0) ? wkb : (r == 1) ? wqb : (r == 2) ? wvb : wob;
    }
    const size_t i = (size_t)base * 256 + threadIdx.x;
    const float4 a = *reinterpret_cast<const float4*>(src + i * 8);
    const float4 b = *reinterpret_cast<const float4*>(src + i * 8 + 4);
    u16x8 o;
    o[0] = __bfloat16_as_ushort(tobf(a.x));
    o[1] = __bfloat16_as_ushort(tobf(a.y));
    o[2] = __bfloat16_as_ushort(tobf(a.z));
    o[3] = __bfloat16_as_ushort(tobf(a.w));
    o[4] = __bfloat16_as_ushort(tobf(b.x));
    o[5] = __bfloat16_as_ushort(tobf(b.y));
    o[6] = __bfloat16_as_ushort(tobf(b.z));
    o[7] = __bfloat16_as_ushort(tobf(b.w));
    *reinterpret_cast<u16x8*>(dst + i * 8) = o;
}

// ---------------------------------------------------------------------------
// qkv_gemm: grid (64 mt, 12 ni), 512 thr (8 waves, 4m x 2n).
// C[8192][1536] = x[8192][512] @ W^T, N z-major: n = z*512 + h*64 + dh.
// BM=128 BN=128 BK=64; LDS dbuf 64KB; XOR-swizzled ds_read_b128 fragments.
// Epilogue scatters to Q (scaled), K, or Vt (transposed, ushort4).
// ---------------------------------------------------------------------------
__global__ __launch_bounds__(512) void qkv_gemm(
    const __hip_bfloat16* __restrict__ x,    // [8192][512]
    const __hip_bfloat16* __restrict__ Wk,
    const __hip_bfloat16* __restrict__ Wq,
    const __hip_bfloat16* __restrict__ Wv,   // each [512][512] row-major
    __hip_bfloat16* __restrict__ Qo,   // [16][4096][64]
    __hip_bfloat16* __restrict__ Ko,   // [16][4096][64]
    __hip_bfloat16* __restrict__ Vt)   // [16][64][4096]
{
    __shared__ __hip_bfloat16 Xlds[2][128][64];
    __shared__ __hip_bfloat16 Wlds[2][128][64];

    const int mt = blockIdx.x;       // 0..63
    const int ni = blockIdx.y;       // 0..11
    const int z  = ni >> 2;          // 0=K 1=Q 2=V
    const int m0 = mt * 128;

    const __hip_bfloat16* Wz =
        (z == 0 ? Wk : (z == 1 ? Wq : Wv)) + (size_t)(ni & 3) * 128 * 512;

    const int tid  = threadIdx.x;
    const int w    = tid >> 6;        // 0..7
    const int lane = tid & 63;
    const int q31  = lane & 31;
    const int hi   = lane >> 5;
    const int wm   = w >> 1;          // 0..3 (m stripe)
    const int wn   = w & 1;           // 0..1 (n stripe)

    // ---- staging addresses (pre-swizzled source granule) ----
    const int r0l = w * 8 + (lane >> 3);          // 0..63
    const int cg  = (lane & 7) ^ (r0l & 7);
    const __hip_bfloat16* Xsrc = x  + (size_t)(m0 + r0l) * 512 + cg * 8;
    const __hip_bfloat16* Wsrc = Wz + (size_t)r0l * 512 + cg * 8;

    auto stage = [&](int buf, int k0) {
        gl_lds16(Xsrc + k0,                   &Xlds[buf][w * 8][0]);
        gl_lds16(Xsrc + k0 + (size_t)64 * 512, &Xlds[buf][w * 8 + 64][0]);
        gl_lds16(Wsrc + k0,                   &Wlds[buf][w * 8][0]);
        gl_lds16(Wsrc + k0 + (size_t)64 * 512, &Wlds[buf][w * 8 + 64][0]);
    };

    // swizzled granule offsets (elements) for fragment reads
    const int ra  = wm * 32 + q31;        // A row in tile
    const int rb0 = wn * 64 + q31;        // B row, col-frag 0
    const int rb1 = wn * 64 + 32 + q31;   // B row, col-frag 1
    int gA[4], gB0[4], gB1[4];
#pragma unroll
    for (int ks = 0; ks < 4; ++ks) {
        gA[ks]  = SWZ(2 * ks + hi, ra)  * 8;
        gB0[ks] = SWZ(2 * ks + hi, rb0) * 8;
        gB1[ks] = SWZ(2 * ks + hi, rb1) * 8;
    }

    f32x16 ac0 = {}, ac1 = {};
    stage(0, 0);

    for (int it = 0; it < 8; ++it) {
        const int buf = it & 1;
        asm volatile("s_waitcnt vmcnt(0)" ::: "memory");
        __syncthreads();
        if (it < 7) stage(buf ^ 1, (it + 1) * 64);

        const __hip_bfloat16* xa  = &Xlds[buf][ra][0];
        const __hip_bfloat16* wb0 = &Wlds[buf][rb0][0];
        const __hip_bfloat16* wb1 = &Wlds[buf][rb1][0];

        __builtin_amdgcn_s_setprio(1);
#pragma unroll
        for (int ks = 0; ks < 4; ++ks) {
            bf16x8 a  = *(const bf16x8*)(xa  + gA[ks]);
            bf16x8 b0 = *(const bf16x8*)(wb0 + gB0[ks]);
            bf16x8 b1 = *(const bf16x8*)(wb1 + gB1[ks]);
            ac0 = MFMA32(a, b0, ac0);
            ac1 = MFMA32(a, b1, ac1);
        }
        __builtin_amdgcn_s_setprio(0);
    }

    // ---- epilogue ----
    const int b     = m0 >> 12;
    const int sbase = (m0 & 4095) + wm * 32;
    const int hc0   = (ni & 3) * 128 + wn * 64;

    if (z == 2) {
        // V: Vt[bh][dh][s], 4 consecutive s per quad -> ushort4
        auto vstore = [&](const f32x16& ac, int cf) {
            const int hcol = hc0 + cf * 32 + q31;
            const int h = hcol >> 6, dh = hcol & 63;
            __hip_bfloat16* vbase =
                Vt + ((size_t)(b * 8 + h) * 64 + dh) * 4096;
#pragma unroll
            for (int q2 = 0; q2 < 4; ++q2) {
                ushort4 pk;
                pk.x = __bfloat16_as_ushort(tobf(ac[q2 * 4 + 0]));
                pk.y = __bfloat16_as_ushort(tobf(ac[q2 * 4 + 1]));
                pk.z = __bfloat16_as_ushort(tobf(ac[q2 * 4 + 2]));
                pk.w = __bfloat16_as_ushort(tobf(ac[q2 * 4 + 3]));
                *reinterpret_cast<ushort4*>(vbase + sbase + 8 * q2 + 4 * hi) = pk;
            }
        };
        vstore(ac0, 0);
        vstore(ac1, 1);
    } else {
        const float scale = (z == 1) ? 0.18033688f : 1.0f;  // 0.125/ln2 for Q
        __hip_bfloat16* O = (z == 0) ? Ko : Qo;
        auto kstore = [&](const f32x16& ac, int cf) {
            const int hcol = hc0 + cf * 32 + q31;
            const int h = hcol >> 6, dh = hcol & 63;
            __hip_bfloat16* obase =
                O + (size_t)(b * 8 + h) * 4096 * 64 + dh;
#pragma unroll
            for (int reg = 0; reg < 16; ++reg) {
                const int srow = sbase + (reg & 3) + 8 * (reg >> 2) + 4 * hi;
                obase[(size_t)srow * 64] = tobf(ac[reg] * scale);
            }
        };
        kstore(ac0, 0);
        kstore(ac1, 1);
    }
}

// ---------------------------------------------------------------------------
// attn_part: grid=(40, 16) flat deep-first (no empty blocks), 512 thr, 8 waves.
// Block = 256 q-rows (8 waves x 32). KV tile 64; chunk = up to 16 tiles.
// Rows with nc==1 (qi<=3) are normalized and written directly to Z.
// ---------------------------------------------------------------------------
__global__ __launch_bounds__(512) void attn_part(
    const __hip_bfloat16* __restrict__ Q,
    const __hip_bfloat16* __restrict__ K,
    const __hip_bfloat16* __restrict__ Vt,
    __hip_bfloat16* __restrict__ Zp,   // [slots][256 q][64 d] bf16
    float* __restrict__ ML,            // [slots][2][256]
    __hip_bfloat16* __restrict__ Z)    // [b][s][h*64] direct path
{
    __shared__ __hip_bfloat16 Klds[2][64][64];
    __shared__ __hip_bfloat16 Vlds[2][64][64];   // V^T tile: [d][p]
    __shared__ float als[8][32];

    // flat blockIdx.x -> (qi deep-first, chunk c)
    int rem = blockIdx.x, qi = 15, nc;
    for (;;) { nc = (qi >> 2) + 1; if (rem < nc) break; rem -= nc; --qi; }
    const int c  = rem;
    const int bh = blockIdx.y;

    const int w    = threadIdx.x >> 6;    // 0..7
    const int lane = threadIdx.x & 63;
    const int q31  = lane & 31;
    const int hi   = lane >> 5;

    const __hip_bfloat16* Qb = Q  + (size_t)bh * 4096 * 64;
    const __hip_bfloat16* Kb = K  + (size_t)bh * 4096 * 64;
    const __hip_bfloat16* Vb = Vt + (size_t)bh * 64 * 4096;

    const int wbase = qi * 256 + w * 32;   // wave's first q-row
    const int qrow  = wbase + q31;         // this lane's softmax q-row
    const int wqmax = wbase + 31;          // wave's deepest q-row

    // Q B-fragments (col=lane&31=q, k=d)
    bf16x8 qf[4];
#pragma unroll
    for (int ks = 0; ks < 4; ++ks)
        qf[ks] = ld8(Qb + (size_t)qrow * 64 + ks * 16 + hi * 8);

    f32x16 za0 = {}, za1 = {};
    float m_s  = -3.0e38f;
    float l_ln = 0.0f;

    const int t0   = c * 16;
    const int tend = min(t0 + 16, 4 * qi + 4);
    const int nt   = tend - t0;

    // hoisted swizzled LDS byte-granule offsets (loop-invariant)
    int gsx[4];
#pragma unroll
    for (int ks = 0; ks < 4; ++ks) gsx[ks] = SWZ(2 * ks + hi, q31) * 8;

    // ---- staging: wave w owns rows [w*8, w*8+8) of K and V^T tiles ----
    const int r0l = w * 8 + (lane >> 3);
    const int cg  = (lane & 7) ^ (r0l & 7);       // pre-swizzled source granule
    const __hip_bfloat16* Ksrc = Kb + (size_t)r0l * 64 + cg * 8;
    const __hip_bfloat16* Vsrc = Vb + (size_t)r0l * 4096 + cg * 8;

    auto stage = [&](int buf, int t) {
        const int p0 = t * 64;
        gl_lds16(Ksrc + (size_t)p0 * 64, &Klds[buf][w * 8][0]);
        gl_lds16(Vsrc + p0,              &Vlds[buf][w * 8][0]);
    };

    stage(0, t0);

    for (int it = 0; it < nt; ++it) {
        const int t   = t0 + it;
        const int buf = it & 1;

        asm volatile("s_waitcnt vmcnt(0)" ::: "memory");
        __syncthreads();
        if (it + 1 < nt) stage(buf ^ 1, t + 1);

        const int p0 = t * 64;
        if (p0 > wqmax) continue;   // wave fully masked (barriers stay uniform)

        const __hip_bfloat16* kb0 = &Klds[buf][q31][0];
        const __hip_bfloat16* kb1 = &Klds[buf][32 + q31][0];

        // ---- S^T = mfma(K, Q): 2 p-tiles x 4 k-slots ----
        f32x16 sa0 = {}, sa1 = {};
        __builtin_amdgcn_s_setprio(1);
#pragma unroll
        for (int ks = 0; ks < 4; ++ks) {
            bf16x8 k0 = *(const bf16x8*)(kb0 + gsx[ks]);
            bf16x8 k1 = *(const bf16x8*)(kb1 + gsx[ks]);
            sa0 = MFMA32(k0, qf[ks], sa0);
            sa1 = MFMA32(k1, qf[ks], sa1);
        }
        __builtin_amdgcn_s_setprio(0);

        // ---- causal mask (only where tile crosses this wave's diagonal) ----
        if (p0 + 63 > wbase) {
#pragma unroll
            for (int reg = 0; reg < 16; ++reg) {
                const int pl = (reg & 3) + 8 * (reg >> 2) + 4 * hi;
                const int p  = p0 + pl;
                sa0[reg] = (p      <= qrow) ? sa0[reg] : -1.0e30f;
                sa1[reg] = (p + 32 <= qrow) ? sa1[reg] : -1.0e30f;
            }
        }

        // ---- row max: tree reduce + cross-half ----
        float tm[8];
#pragma unroll
        for (int i = 0; i < 8; ++i)
            tm[i] = fmaxf(fmaxf(sa0[i], sa0[i + 8]), fmaxf(sa1[i], sa1[i + 8]));
#pragma unroll
        for (int s = 4; s; s >>= 1)
#pragma unroll
            for (int i = 0; i < s; ++i) tm[i] = fmaxf(tm[i], tm[i + s]);
        float mx = fmaxf(tm[0], __shfl_xor(tm[0], 32));

        // ---- defer-max: rescale only when max grew past threshold ----
        if (!__all(mx <= m_s + 8.0f)) {
            const float mnew  = fmaxf(m_s, mx);
            const float alpha = exp2_raw(m_s - mnew);
            m_s = mnew;
            l_ln *= alpha;
            if (hi == 0) als[w][q31] = alpha;
#pragma unroll
            for (int reg = 0; reg < 16; ++reg) {
                const int q = (reg & 3) + 8 * (reg >> 2) + 4 * hi;
                const float av = als[w][q];
                za0[reg] *= av;
                za1[reg] *= av;
            }
        }

        // ---- P = 2^(S - m), tree l-sum ----
#pragma unroll
        for (int reg = 0; reg < 16; ++reg) {
            sa0[reg] = exp2_raw(sa0[reg] - m_s);
            sa1[reg] = exp2_raw(sa1[reg] - m_s);
        }
        float ts[8];
#pragma unroll
        for (int i = 0; i < 8; ++i)
            ts[i] = (sa0[i] + sa0[i + 8]) + (sa1[i] + sa1[i + 8]);
#pragma unroll
        for (int s = 4; s; s >>= 1)
#pragma unroll
            for (int i = 0; i < s; ++i) ts[i] += ts[i + s];
        l_ln += ts[0];

        // ---- in-register P transpose -> A-frags (cvt_pk + permlane32_swap) --
        bf16x8 pfrag[4];
#pragma unroll
        for (int kb = 0; kb < 4; ++kb) {
            const int e = (kb & 1) * 8;
            unsigned px, py, pu, pv;
            if (kb < 2) {
                px = cvt_pk(sa0[e + 0], sa0[e + 1]);
                py = cvt_pk(sa0[e + 2], sa0[e + 3]);
                pu = cvt_pk(sa0[e + 4], sa0[e + 5]);
                pv = cvt_pk(sa0[e + 6], sa0[e + 7]);
            } else {
                px = cvt_pk(sa1[e + 0], sa1[e + 1]);
                py = cvt_pk(sa1[e + 2], sa1[e + 3]);
                pu = cvt_pk(sa1[e + 4], sa1[e + 5]);
                pv = cvt_pk(sa1[e + 6], sa1[e + 7]);
            }
            pl32swap(px, pu);
            pl32swap(py, pv);
            u32x4 fw;
            fw[0] = px; fw[1] = py; fw[2] = pu; fw[3] = pv;
            pfrag[kb] = __builtin_bit_cast(bf16x8, fw);
        }

        const __hip_bfloat16* vb0 = &Vlds[buf][q31][0];
        const __hip_bfloat16* vb1 = &Vlds[buf][32 + q31][0];

        // ---- Z += P V (A=P row=q, B=V^T col=d) ----
        __builtin_amdgcn_s_setprio(1);
#pragma unroll
        for (int kb = 0; kb < 4; ++kb) {
            bf16x8 v0 = *(const bf16x8*)(vb0 + gsx[kb]);
            bf16x8 v1 = *(const bf16x8*)(vb1 + gsx[kb]);
            za0 = MFMA32(pfrag[kb], v0, za0);
            za1 = MFMA32(pfrag[kb], v1, za1);
        }
        __builtin_amdgcn_s_setprio(0);
    }

    // ---- epilogue ----
    float lt = l_ln + __shfl_xor(l_ln, 32);

    if (nc == 1) {
        // single-chunk row: normalize and write straight to Z
        if (hi == 0) als[w][q31] = 1.0f / lt;
        const int b = bh >> 3, h = bh & 7;
#pragma unroll
        for (int reg = 0; reg < 16; ++reg) {
            const int q = (reg & 3) + 8 * (reg >> 2) + 4 * hi;
            const float inv = als[w][q];
            __hip_bfloat16* zo =
                Z + ((size_t)b * 4096 + qi * 256 + w * 32 + q) * 512 + h * 64 + q31;
            zo[0]  = tobf(za0[reg] * inv);
            zo[32] = tobf(za1[reg] * inv);
        }
    } else {
        const int slot = bh * SLOTS_BH + slot_off(qi) + c;
        if (hi == 0) {
            ML[(size_t)slot * 512 +       w * 32 + q31] = m_s;
            ML[(size_t)slot * 512 + 256 + w * 32 + q31] = lt;
        }
#pragma unroll
        for (int reg = 0; reg < 16; ++reg) {
            const int q = (reg & 3) + 8 * (reg >> 2) + 4 * hi;
            const size_t base =
                (size_t)slot * 16384 + (size_t)(w * 32 + q) * 64 + q31;
            Zp[base]      = tobf(za0[reg]);
            Zp[base + 32] = tobf(za1[reg]);
        }
    }
}

// ---------------------------------------------------------------------------
// attn_combine: grid=(12 qi-4, 16 bh), 512 thr. q = tid>>1, half = tid&1.
// ---------------------------------------------------------------------------
__global__ __launch_bounds__(512) void attn_combine(
    const __hip_bfloat16* __restrict__ Zp,
    const float* __restrict__ ML,
    __hip_bfloat16* __restrict__ Z)    // [b][s][h*64]
{
    const int qi = blockIdx.x + 4;
    const int bh = blockIdx.y;
    const int nc = (qi >> 2) + 1;
    const int q    = threadIdx.x >> 1;
    const int half = threadIdx.x & 1;

    const int slot0 = bh * SLOTS_BH + slot_off(qi);

    float M = -3.0e38f;
    for (int i = 0; i < nc; ++i)
        M = fmaxf(M, ML[(size_t)(slot0 + i) * 512 + q]);

    float L = 0.0f;
    float acc[32];
#pragma unroll
    for (int j = 0; j < 32; ++j) acc[j] = 0.0f;

    for (int i = 0; i < nc; ++i) {
        const float wgt = exp2_raw(ML[(size_t)(slot0 + i) * 512 + q] - M);
        L += wgt * ML[(size_t)(slot0 + i) * 512 + 256 + q];
        const __hip_bfloat16* zp =
            Zp + (size_t)(slot0 + i) * 16384 + (size_t)q * 64 + half * 32;
#pragma unroll
        for (int v = 0; v < 4; ++v) {
            bf16x8 z = ld8(zp + v * 8);
#pragma unroll
            for (int j = 0; j < 8; ++j) acc[v * 8 + j] += wgt * (float)z[j];
        }
    }

    const float inv = 1.0f / L;
    const int b = bh >> 3, h = bh & 7;
    __hip_bfloat16* zo =
        Z + ((size_t)b * 4096 + qi * 256 + q) * 512 + h * 64 + half * 32;
#pragma unroll
    for (int v = 0; v < 4; ++v) {
        u16x8 o;
#pragma unroll
        for (int j = 0; j < 8; ++j)
            o[j] = __bfloat16_as_ushort(tobf(acc[v * 8 + j] * inv));
        *reinterpret_cast<u16x8*>(zo + v * 8) = o;
    }
}

// ---------------------------------------------------------------------------
// out_proj: grid (128 mt, 2 ny), BN=256.
// ---------------------------------------------------------------------------
__global__ __launch_bounds__(256) void out_proj(
    const __hip_bfloat16* __restrict__ Zf,   // [8192][512]
    const __hip_bfloat16* __restrict__ Wo,   // [512][512] bf16
    float* __restrict__ out)                 // [8192][512] f32
{
    const int w    = threadIdx.x >> 6;
    const int lane = threadIdx.x & 63;
    const int l16  = lane & 15;
    const int lg   = lane >> 4;
    const int r0   = blockIdx.x * 64 + w * 16;
    const int n0   = blockIdx.y * 256;

    f32x4 acc[16] = {};
    const __hip_bfloat16* Ap = Zf + (size_t)(r0 + l16) * 512 + lg * 8;
    for (int k0 = 0; k0 < 512; k0 += 32) {
        bf16x8 a = ld8(Ap + k0);
        const size_t bo = k0 + lg * 8;
#pragma unroll
        for (int nf = 0; nf < 16; ++nf) {
            bf16x8 b = ld8(Wo + (size_t)(n0 + nf * 16 + l16) * 512 + bo);
            acc[nf] = MFMA16(a, b, acc[nf]);
        }
    }
#pragma unroll
    for (int nf = 0; nf < 16; ++nf)
#pragma unroll
        for (int r = 0; r < 4; ++r)
            out[(size_t)(r0 + lg * 4 + r) * 512 + n0 + nf * 16 + l16] = acc[nf][r];
}

// ---------------------------------------------------------------------------
extern "C" void kernel_launch(void* const* d_in, const int* in_sizes, int n_in,
                              void* d_out, int out_size, void* d_ws, size_t ws_size,
                              hipStream_t stream)
{
    const float* x_f  = (const float*)d_in[0];
    const float* Wk_f = (const float*)d_in[1];
    const float* Wq_f = (const float*)d_in[2];
    const float* Wv_f = (const float*)d_in[3];
    const float* Wo_f = (const float*)d_in[4];
    float* out = (float*)d_out;

    char* ws = (char*)d_ws;
    const size_t szQKV = (size_t)16 * 4096 * 64 * sizeof(__hip_bfloat16);   // 8.39 MB
    const size_t szX   = (size_t)8192 * 512 * sizeof(__hip_bfloat16);       // 8.39 MB
    const size_t szW   = (size_t)8 * 64 * 512 * sizeof(__hip_bfloat16);     // 0.5 MB
    const size_t szZp  = (size_t)16 * SLOTS_BH * 256 * 64 * sizeof(__hip_bfloat16); // 21 MB
    const size_t szML  = (size_t)16 * SLOTS_BH * 512 * sizeof(float);       // 1.3 MB

    // persistent region
    size_t off = 0;
    __hip_bfloat16* Qb  = (__hip_bfloat16*)(ws + off); off += szQKV;
    __hip_bfloat16* Kb  = (__hip_bfloat16*)(ws + off); off += szQKV;
    __hip_bfloat16* Vt  = (__hip_bfloat16*)(ws + off); off += szQKV;
    __hip_bfloat16* Zb  = (__hip_bfloat16*)(ws + off); off += szX;
    __hip_bfloat16* Wob = (__hip_bfloat16*)(ws + off); off += szW;
    // transient region 1 (dead after qkv_gemm): xb + Wk/Wq/Wv casts
    const size_t trans = off;
    __hip_bfloat16* xb  = (__hip_bfloat16*)(ws + trans);
    __hip_bfloat16* Wkb = (__hip_bfloat16*)(ws + trans + szX);
    __hip_bfloat16* Wqb = (__hip_bfloat16*)(ws + trans + szX + szW);
    __hip_bfloat16* Wvb = (__hip_bfloat16*)(ws + trans + szX + 2 * szW);
    // transient region 2 (attention partials) ALIASES region 1
    __hip_bfloat16* Zp  = (__hip_bfloat16*)(ws + trans);
    float*          ML  = (float*)(ws + trans + szZp);

    cast_all<<<2048 + 4 * 128, 256, 0, stream>>>(
        x_f, Wk_f, Wq_f, Wv_f, Wo_f, xb, Wkb, Wqb, Wvb, Wob);

    qkv_gemm<<<dim3(64, 12),   512, 0, stream>>>(xb, Wkb, Wqb, Wvb, Qb, Kb, Vt);
    attn_part<<<dim3(40, 16),  512, 0, stream>>>(Qb, Kb, Vt, Zp, ML, Zb);
    attn_combine<<<dim3(12, 16), 512, 0, stream>>>(Zp, ML, Zb);
    out_proj<<<dim3(128, 2),   256, 0, stream>>>(Zb, Wob, out);
}

// Round 10
// 135.457 us; speedup vs baseline: 4.5290x; 1.0578x over previous
//
#include <hip/hip_runtime.h>
#include <hip/hip_bf16.h>

// b=2, s=4096, d_model=512, heads=8, d_head=64. I/O f32; compute bf16 MFMA.
// qkv/out: LDS-staged 128x128x64 GEMMs (gload_lds, dbuf, XOR swizzle).
// attn: 8-wave 256-q blocks, 32x32x16 MFMA, 3-buffer K/V pipeline with
// counted vmcnt(2), swapped QK^T, in-register softmax (raw v_exp base-2,
// defer-max), P transpose via cvt_pk + permlane32_swap, l-sum via MFMA(ones),
// split-KV 16-tile chunks, direct write for single-chunk rows.

typedef __attribute__((ext_vector_type(4)))  float  f32x4;
typedef __attribute__((ext_vector_type(16))) float  f32x16;
typedef __attribute__((ext_vector_type(8)))  __bf16 bf16x8;
typedef __attribute__((ext_vector_type(8)))  unsigned short u16x8;
typedef __attribute__((ext_vector_type(4)))  unsigned int u32x4;

#define MFMA16(a, b, c) __builtin_amdgcn_mfma_f32_16x16x32_bf16((a), (b), (c), 0, 0, 0)
#define MFMA32(a, b, c) __builtin_amdgcn_mfma_f32_32x32x16_bf16((a), (b), (c), 0, 0, 0)
#define SWZ(g, r) ((g) ^ ((r) & 7))
#define SLOTS_BH 40   // sum over qi=0..15 of (qi>>2)+1

static __device__ __forceinline__ bf16x8 ld8(const __hip_bfloat16* p) {
    return *reinterpret_cast<const bf16x8*>(p);
}
static __device__ __forceinline__ __hip_bfloat16 tobf(float f) {
    return __float2bfloat16(f);
}
static __device__ __forceinline__ float exp2_raw(float x) {
    float r;
    asm("v_exp_f32 %0, %1" : "=v"(r) : "v"(x));
    return r;
}
static __device__ __forceinline__ unsigned cvt_pk(float lo, float hi) {
    unsigned r;
    asm("v_cvt_pk_bf16_f32 %0, %1, %2" : "=v"(r) : "v"(lo), "v"(hi));
    return r;
}
static __device__ __forceinline__ void pl32swap(unsigned& a, unsigned& b) {
    asm("v_permlane32_swap_b32 %0, %1" : "+v"(a), "+v"(b));
}
static __device__ __forceinline__ void gl_lds16(const __hip_bfloat16* g, __hip_bfloat16* l) {
    typedef __attribute__((address_space(1))) const unsigned int GU;
    typedef __attribute__((address_space(3))) unsigned int LU;
    __builtin_amdgcn_global_load_lds((GU*)(const void*)g, (LU*)(void*)l, 16, 0, 0);
}
static __device__ __forceinline__ bf16x8 ones8() {
    u16x8 o;
#pragma unroll
    for (int j = 0; j < 8; ++j) o[j] = 0x3F80;   // bf16 1.0
    return __builtin_bit_cast(bf16x8, o);
}
// chunks of 16 KV-tiles over 256-row q-tiles; nchunks(qi) = (qi>>2)+1
static __device__ __forceinline__ int slot_off(int qi) {
    const int a = qi >> 2;
    return qi + 2 * a * (a - 1) + a * (qi & 3);
}

// ---------------------------------------------------------------------------
// Fused cast: f32 -> bf16 for x (2048 blocks) + 4 weights (128 blocks each).
// ---------------------------------------------------------------------------
__global__ __launch_bounds__(256) void cast_all(
    const float* __restrict__ x,  const float* __restrict__ wk,
    const float* __restrict__ wq, const float* __restrict__ wv,
    const float* __restrict__ wo,
    __hip_bfloat16* __restrict__ xb,  __hip_bfloat16* __restrict__ wkb,
    __hip_bfloat16* __restrict__ wqb, __hip_bfloat16* __restrict__ wvb,
    __hip_bfloat16* __restrict__ wob)
{
    const int bid = blockIdx.x;
    const float* src;
    __hip_bfloat16* dst;
    int base;
    if (bid < 2048) { src = x; dst = xb; base = bid; }
    else {
        const int r = (bid - 2048) >> 7;
        base = (bid - 2048) & 127;
        src = (r == 0) ? wk : (r == 1) ? wq : (r == 2) ? wv : wo;
        dst = (r == 0) ? wkb : (r == 1) ? wqb : (r == 2) ? wvb : wob;
    }
    const size_t i = (size_t)base * 256 + threadIdx.x;
    const float4 a = *reinterpret_cast<const float4*>(src + i * 8);
    const float4 b = *reinterpret_cast<const float4*>(src + i * 8 + 4);
    u16x8 o;
    o[0] = __bfloat16_as_ushort(tobf(a.x));
    o[1] = __bfloat16_as_ushort(tobf(a.y));
    o[2] = __bfloat16_as_ushort(tobf(a.z));
    o[3] = __bfloat16_as_ushort(tobf(a.w));
    o[4] = __bfloat16_as_ushort(tobf(b.x));
    o[5] = __bfloat16_as_ushort(tobf(b.y));
    o[6] = __bfloat16_as_ushort(tobf(b.z));
    o[7] = __bfloat16_as_ushort(tobf(b.w));
    *reinterpret_cast<u16x8*>(dst + i * 8) = o;
}

// ---------------------------------------------------------------------------
// qkv_gemm: grid (64 mt, 12 ni), 512 thr (8 waves, 4m x 2n).
// ---------------------------------------------------------------------------
__global__ __launch_bounds__(512) void qkv_gemm(
    const __hip_bfloat16* __restrict__ x,    // [8192][512]
    const __hip_bfloat16* __restrict__ Wk,
    const __hip_bfloat16* __restrict__ Wq,
    const __hip_bfloat16* __restrict__ Wv,   // each [512][512] row-major
    __hip_bfloat16* __restrict__ Qo,   // [16][4096][64]
    __hip_bfloat16* __restrict__ Ko,   // [16][4096][64]
    __hip_bfloat16* __restrict__ Vt)   // [16][64][4096]
{
    __shared__ __hip_bfloat16 Xlds[2][128][64];
    __shared__ __hip_bfloat16 Wlds[2][128][64];

    const int mt = blockIdx.x;       // 0..63
    const int ni = blockIdx.y;       // 0..11
    const int z  = ni >> 2;          // 0=K 1=Q 2=V
    const int m0 = mt * 128;

    const __hip_bfloat16* Wz =
        (z == 0 ? Wk : (z == 1 ? Wq : Wv)) + (size_t)(ni & 3) * 128 * 512;

    const int tid  = threadIdx.x;
    const int w    = tid >> 6;        // 0..7
    const int lane = tid & 63;
    const int q31  = lane & 31;
    const int hi   = lane >> 5;
    const int wm   = w >> 1;          // 0..3 (m stripe)
    const int wn   = w & 1;           // 0..1 (n stripe)

    const int r0l = w * 8 + (lane >> 3);          // 0..63
    const int cg  = (lane & 7) ^ (r0l & 7);
    const __hip_bfloat16* Xsrc = x  + (size_t)(m0 + r0l) * 512 + cg * 8;
    const __hip_bfloat16* Wsrc = Wz + (size_t)r0l * 512 + cg * 8;

    auto stage = [&](int buf, int k0) {
        gl_lds16(Xsrc + k0,                    &Xlds[buf][w * 8][0]);
        gl_lds16(Xsrc + k0 + (size_t)64 * 512, &Xlds[buf][w * 8 + 64][0]);
        gl_lds16(Wsrc + k0,                    &Wlds[buf][w * 8][0]);
        gl_lds16(Wsrc + k0 + (size_t)64 * 512, &Wlds[buf][w * 8 + 64][0]);
    };

    const int ra  = wm * 32 + q31;
    const int rb0 = wn * 64 + q31;
    const int rb1 = wn * 64 + 32 + q31;
    int gA[4], gB0[4], gB1[4];
#pragma unroll
    for (int ks = 0; ks < 4; ++ks) {
        gA[ks]  = SWZ(2 * ks + hi, ra)  * 8;
        gB0[ks] = SWZ(2 * ks + hi, rb0) * 8;
        gB1[ks] = SWZ(2 * ks + hi, rb1) * 8;
    }

    f32x16 ac0 = {}, ac1 = {};
    stage(0, 0);

    for (int it = 0; it < 8; ++it) {
        const int buf = it & 1;
        asm volatile("s_waitcnt vmcnt(0)" ::: "memory");
        __syncthreads();
        if (it < 7) stage(buf ^ 1, (it + 1) * 64);

        const __hip_bfloat16* xa  = &Xlds[buf][ra][0];
        const __hip_bfloat16* wb0 = &Wlds[buf][rb0][0];
        const __hip_bfloat16* wb1 = &Wlds[buf][rb1][0];

        __builtin_amdgcn_s_setprio(1);
#pragma unroll
        for (int ks = 0; ks < 4; ++ks) {
            bf16x8 a  = *(const bf16x8*)(xa  + gA[ks]);
            bf16x8 b0 = *(const bf16x8*)(wb0 + gB0[ks]);
            bf16x8 b1 = *(const bf16x8*)(wb1 + gB1[ks]);
            ac0 = MFMA32(a, b0, ac0);
            ac1 = MFMA32(a, b1, ac1);
        }
        __builtin_amdgcn_s_setprio(0);
    }

    // ---- epilogue ----
    const int b     = m0 >> 12;
    const int sbase = (m0 & 4095) + wm * 32;
    const int hc0   = (ni & 3) * 128 + wn * 64;

    if (z == 2) {
        auto vstore = [&](const f32x16& ac, int cf) {
            const int hcol = hc0 + cf * 32 + q31;
            const int h = hcol >> 6, dh = hcol & 63;
            __hip_bfloat16* vbase =
                Vt + ((size_t)(b * 8 + h) * 64 + dh) * 4096;
#pragma unroll
            for (int q2 = 0; q2 < 4; ++q2) {
                ushort4 pk;
                pk.x = __bfloat16_as_ushort(tobf(ac[q2 * 4 + 0]));
                pk.y = __bfloat16_as_ushort(tobf(ac[q2 * 4 + 1]));
                pk.z = __bfloat16_as_ushort(tobf(ac[q2 * 4 + 2]));
                pk.w = __bfloat16_as_ushort(tobf(ac[q2 * 4 + 3]));
                *reinterpret_cast<ushort4*>(vbase + sbase + 8 * q2 + 4 * hi) = pk;
            }
        };
        vstore(ac0, 0);
        vstore(ac1, 1);
    } else {
        const float scale = (z == 1) ? 0.18033688f : 1.0f;  // 0.125/ln2 for Q
        __hip_bfloat16* O = (z == 0) ? Ko : Qo;
        auto kstore = [&](const f32x16& ac, int cf) {
            const int hcol = hc0 + cf * 32 + q31;
            const int h = hcol >> 6, dh = hcol & 63;
            __hip_bfloat16* obase =
                O + (size_t)(b * 8 + h) * 4096 * 64 + dh;
#pragma unroll
            for (int reg = 0; reg < 16; ++reg) {
                const int srow = sbase + (reg & 3) + 8 * (reg >> 2) + 4 * hi;
                obase[(size_t)srow * 64] = tobf(ac[reg] * scale);
            }
        };
        kstore(ac0, 0);
        kstore(ac1, 1);
    }
}

// ---------------------------------------------------------------------------
// attn_part: grid=(40, 16) flat deep-first, 512 thr, 8 waves.
// 3-buffer K/V pipeline, counted vmcnt(2) steady state.
// ---------------------------------------------------------------------------
__global__ __launch_bounds__(512) void attn_part(
    const __hip_bfloat16* __restrict__ Q,
    const __hip_bfloat16* __restrict__ K,
    const __hip_bfloat16* __restrict__ Vt,
    __hip_bfloat16* __restrict__ Zp,   // [slots][256 q][64 d] bf16
    float* __restrict__ ML,            // [slots][2][256]
    __hip_bfloat16* __restrict__ Z)    // [b][s][h*64] direct path
{
    __shared__ __hip_bfloat16 Klds[3][64][64];
    __shared__ __hip_bfloat16 Vlds[3][64][64];   // V^T tile: [d][p]
    __shared__ float als[8][32];

    // flat blockIdx.x -> (qi deep-first, chunk c)
    int rem = blockIdx.x, qi = 15, nc;
    for (;;) { nc = (qi >> 2) + 1; if (rem < nc) break; rem -= nc; --qi; }
    const int c  = rem;
    const int bh = blockIdx.y;

    const int w    = threadIdx.x >> 6;    // 0..7
    const int lane = threadIdx.x & 63;
    const int q31  = lane & 31;
    const int hi   = lane >> 5;

    const __hip_bfloat16* Qb = Q  + (size_t)bh * 4096 * 64;
    const __hip_bfloat16* Kb = K  + (size_t)bh * 4096 * 64;
    const __hip_bfloat16* Vb = Vt + (size_t)bh * 64 * 4096;

    const int wbase = qi * 256 + w * 32;   // wave's first q-row
    const int qrow  = wbase + q31;         // this lane's softmax q-row
    const int wqmax = wbase + 31;          // wave's deepest q-row

    // Q B-fragments (col=lane&31=q, k=d)
    bf16x8 qf[4];
#pragma unroll
    for (int ks = 0; ks < 4; ++ks)
        qf[ks] = ld8(Qb + (size_t)qrow * 64 + ks * 16 + hi * 8);

    const bf16x8 ones = ones8();

    f32x16 za0 = {}, za1 = {}, lacc = {};
    float m_s = -3.0e38f;

    const int t0   = c * 16;
    const int tend = min(t0 + 16, 4 * qi + 4);
    const int nt   = tend - t0;            // always >= 4, multiple of 4

    // hoisted swizzled LDS byte-granule offsets (loop-invariant)
    int gsx[4];
#pragma unroll
    for (int ks = 0; ks < 4; ++ks) gsx[ks] = SWZ(2 * ks + hi, q31) * 8;

    // ---- staging: wave w owns rows [w*8, w*8+8) of K and V^T tiles ----
    const int r0l = w * 8 + (lane >> 3);
    const int cg  = (lane & 7) ^ (r0l & 7);       // pre-swizzled source granule
    const __hip_bfloat16* Ksrc = Kb + (size_t)r0l * 64 + cg * 8;
    const __hip_bfloat16* Vsrc = Vb + (size_t)r0l * 4096 + cg * 8;

    auto stage = [&](int buf, int t) {
        const int p0 = t * 64;
        gl_lds16(Ksrc + (size_t)p0 * 64, &Klds[buf][w * 8][0]);
        gl_lds16(Vsrc + p0,              &Vlds[buf][w * 8][0]);
    };

    stage(0, t0);
    stage(1, t0 + 1);

    int cur = 0;
    for (int it = 0; it < nt; ++it) {
        // my tile-`it` loads done; barrier makes that true for ALL waves
        if (it + 1 < nt) asm volatile("s_waitcnt vmcnt(2)" ::: "memory");
        else             asm volatile("s_waitcnt vmcnt(0)" ::: "memory");
        __syncthreads();

        int s2 = cur + 2; if (s2 >= 3) s2 -= 3;
        if (it + 2 < nt) stage(s2, t0 + it + 2);   // overwrites buf of it-1

        const int t  = t0 + it;
        const int p0 = t * 64;
        if (p0 > wqmax) { cur = (cur == 2) ? 0 : cur + 1; continue; }

        const __hip_bfloat16* kb0 = &Klds[cur][q31][0];
        const __hip_bfloat16* kb1 = &Klds[cur][32 + q31][0];

        // ---- S^T = mfma(K, Q): 2 p-tiles x 4 k-slots ----
        f32x16 sa0 = {}, sa1 = {};
        __builtin_amdgcn_s_setprio(1);
#pragma unroll
        for (int ks = 0; ks < 4; ++ks) {
            bf16x8 k0 = *(const bf16x8*)(kb0 + gsx[ks]);
            bf16x8 k1 = *(const bf16x8*)(kb1 + gsx[ks]);
            sa0 = MFMA32(k0, qf[ks], sa0);
            sa1 = MFMA32(k1, qf[ks], sa1);
        }
        __builtin_amdgcn_s_setprio(0);

        // ---- causal mask (only where tile crosses this wave's diagonal) ----
        if (p0 + 63 > wbase) {
#pragma unroll
            for (int reg = 0; reg < 16; ++reg) {
                const int pl = (reg & 3) + 8 * (reg >> 2) + 4 * hi;
                const int p  = p0 + pl;
                sa0[reg] = (p      <= qrow) ? sa0[reg] : -1.0e30f;
                sa1[reg] = (p + 32 <= qrow) ? sa1[reg] : -1.0e30f;
            }
        }

        // ---- row max: max3-friendly tree + cross-half ----
        float tm[8];
#pragma unroll
        for (int i = 0; i < 8; ++i)
            tm[i] = fmaxf(fmaxf(sa0[i], sa0[i + 8]), fmaxf(sa1[i], sa1[i + 8]));
#pragma unroll
        for (int s = 4; s; s >>= 1)
#pragma unroll
            for (int i = 0; i < s; ++i) tm[i] = fmaxf(tm[i], tm[i + s]);
        float mx = fmaxf(tm[0], __shfl_xor(tm[0], 32));

        // ---- defer-max: rescale only when max grew past threshold ----
        if (!__all(mx <= m_s + 8.0f)) {
            const float mnew  = fmaxf(m_s, mx);
            const float alpha = exp2_raw(m_s - mnew);
            m_s = mnew;
            if (hi == 0) als[w][q31] = alpha;
#pragma unroll
            for (int reg = 0; reg < 16; ++reg) {
                const int q = (reg & 3) + 8 * (reg >> 2) + 4 * hi;
                const float av = als[w][q];
                za0[reg]  *= av;
                za1[reg]  *= av;
                lacc[reg] *= av;
            }
        }

        // ---- P = 2^(S - m) ----
#pragma unroll
        for (int reg = 0; reg < 16; ++reg) {
            sa0[reg] = exp2_raw(sa0[reg] - m_s);
            sa1[reg] = exp2_raw(sa1[reg] - m_s);
        }

        // ---- in-register P transpose -> A-frags (cvt_pk + permlane32_swap) --
        bf16x8 pfrag[4];
#pragma unroll
        for (int kb = 0; kb < 4; ++kb) {
            const int e = (kb & 1) * 8;
            unsigned px, py, pu, pv;
            if (kb < 2) {
                px = cvt_pk(sa0[e + 0], sa0[e + 1]);
                py = cvt_pk(sa0[e + 2], sa0[e + 3]);
                pu = cvt_pk(sa0[e + 4], sa0[e + 5]);
                pv = cvt_pk(sa0[e + 6], sa0[e + 7]);
            } else {
                px = cvt_pk(sa1[e + 0], sa1[e + 1]);
                py = cvt_pk(sa1[e + 2], sa1[e + 3]);
                pu = cvt_pk(sa1[e + 4], sa1[e + 5]);
                pv = cvt_pk(sa1[e + 6], sa1[e + 7]);
            }
            pl32swap(px, pu);
            pl32swap(py, pv);
            u32x4 fw;
            fw[0] = px; fw[1] = py; fw[2] = pu; fw[3] = pv;
            pfrag[kb] = __builtin_bit_cast(bf16x8, fw);
        }

        const __hip_bfloat16* vb0 = &Vlds[cur][q31][0];
        const __hip_bfloat16* vb1 = &Vlds[cur][32 + q31][0];

        // ---- Z += P V; l += P 1 (l-sum on the MFMA pipe, za C-layout) ----
        __builtin_amdgcn_s_setprio(1);
#pragma unroll
        for (int kb = 0; kb < 4; ++kb) {
            bf16x8 v0 = *(const bf16x8*)(vb0 + gsx[kb]);
            bf16x8 v1 = *(const bf16x8*)(vb1 + gsx[kb]);
            za0  = MFMA32(pfrag[kb], v0, za0);
            za1  = MFMA32(pfrag[kb], v1, za1);
            lacc = MFMA32(pfrag[kb], ones, lacc);
        }
        __builtin_amdgcn_s_setprio(0);

        cur = (cur == 2) ? 0 : cur + 1;
    }

    // ---- epilogue: lacc[reg] is l for the SAME row as za[reg] ----
    if (nc == 1) {
        const int b = bh >> 3, h = bh & 7;
#pragma unroll
        for (int reg = 0; reg < 16; ++reg) {
            const int q = (reg & 3) + 8 * (reg >> 2) + 4 * hi;
            const float inv = 1.0f / lacc[reg];
            __hip_bfloat16* zo =
                Z + ((size_t)b * 4096 + qi * 256 + w * 32 + q) * 512 + h * 64 + q31;
            zo[0]  = tobf(za0[reg] * inv);
            zo[32] = tobf(za1[reg] * inv);
        }
    } else {
        const int slot = bh * SLOTS_BH + slot_off(qi) + c;
        if (hi == 0)
            ML[(size_t)slot * 512 + w * 32 + q31] = m_s;
        if (q31 == 0) {
#pragma unroll
            for (int reg = 0; reg < 16; ++reg) {
                const int q = (reg & 3) + 8 * (reg >> 2) + 4 * hi;
                ML[(size_t)slot * 512 + 256 + w * 32 + q] = lacc[reg];
            }
        }
#pragma unroll
        for (int reg = 0; reg < 16; ++reg) {
            const int q = (reg & 3) + 8 * (reg >> 2) + 4 * hi;
            const size_t base =
                (size_t)slot * 16384 + (size_t)(w * 32 + q) * 64 + q31;
            Zp[base]      = tobf(za0[reg]);
            Zp[base + 32] = tobf(za1[reg]);
        }
    }
}

// ---------------------------------------------------------------------------
// attn_combine: grid=(12 qi-4, 16 bh), 512 thr. q = tid>>1, half = tid&1.
// ---------------------------------------------------------------------------
__global__ __launch_bounds__(512) void attn_combine(
    const __hip_bfloat16* __restrict__ Zp,
    const float* __restrict__ ML,
    __hip_bfloat16* __restrict__ Z)    // [b][s][h*64]
{
    const int qi = blockIdx.x + 4;
    const int bh = blockIdx.y;
    const int nc = (qi >> 2) + 1;
    const int q    = threadIdx.x >> 1;
    const int half = threadIdx.x & 1;

    const int slot0 = bh * SLOTS_BH + slot_off(qi);

    float M = -3.0e38f;
    for (int i = 0; i < nc; ++i)
        M = fmaxf(M, ML[(size_t)(slot0 + i) * 512 + q]);

    float L = 0.0f;
    float acc[32];
#pragma unroll
    for (int j = 0; j < 32; ++j) acc[j] = 0.0f;

    for (int i = 0; i < nc; ++i) {
        const float wgt = exp2_raw(ML[(size_t)(slot0 + i) * 512 + q] - M);
        L += wgt * ML[(size_t)(slot0 + i) * 512 + 256 + q];
        const __hip_bfloat16* zp =
            Zp + (size_t)(slot0 + i) * 16384 + (size_t)q * 64 + half * 32;
#pragma unroll
        for (int v = 0; v < 4; ++v) {
            bf16x8 z = ld8(zp + v * 8);
#pragma unroll
            for (int j = 0; j < 8; ++j) acc[v * 8 + j] += wgt * (float)z[j];
        }
    }

    const float inv = 1.0f / L;
    const int b = bh >> 3, h = bh & 7;
    __hip_bfloat16* zo =
        Z + ((size_t)b * 4096 + qi * 256 + q) * 512 + h * 64 + half * 32;
#pragma unroll
    for (int v = 0; v < 4; ++v) {
        u16x8 o;
#pragma unroll
        for (int j = 0; j < 8; ++j)
            o[j] = __bfloat16_as_ushort(tobf(acc[v * 8 + j] * inv));
        *reinterpret_cast<u16x8*>(zo + v * 8) = o;
    }
}

// ---------------------------------------------------------------------------
// out_gemm: grid (64 mt, 4 ni), 512 thr. LDS-staged 128x128x64 GEMM.
// out[8192][512] f32 = Z[8192][512] @ Wo^T. Coalesced f32 epilogue.
// ---------------------------------------------------------------------------
__global__ __launch_bounds__(512) void out_gemm(
    const __hip_bfloat16* __restrict__ Zf,   // [8192][512]
    const __hip_bfloat16* __restrict__ Wo,   // [512][512] bf16
    float* __restrict__ out)                 // [8192][512] f32
{
    __shared__ __hip_bfloat16 Alds[2][128][64];
    __shared__ __hip_bfloat16 Blds[2][128][64];

    const int mt = blockIdx.x;       // 0..63
    const int ni = blockIdx.y;       // 0..3
    const int m0 = mt * 128;
    const int n0 = ni * 128;

    const int tid  = threadIdx.x;
    const int w    = tid >> 6;
    const int lane = tid & 63;
    const int q31  = lane & 31;
    const int hi   = lane >> 5;
    const int wm   = w >> 1;
    const int wn   = w & 1;

    const int r0l = w * 8 + (lane >> 3);
    const int cg  = (lane & 7) ^ (r0l & 7);
    const __hip_bfloat16* Asrc = Zf + (size_t)(m0 + r0l) * 512 + cg * 8;
    const __hip_bfloat16* Bsrc = Wo + (size_t)(n0 + r0l) * 512 + cg * 8;

    auto stage = [&](int buf, int k0) {
        gl_lds16(Asrc + k0,                    &Alds[buf][w * 8][0]);
        gl_lds16(Asrc + k0 + (size_t)64 * 512, &Alds[buf][w * 8 + 64][0]);
        gl_lds16(Bsrc + k0,                    &Blds[buf][w * 8][0]);
        gl_lds16(Bsrc + k0 + (size_t)64 * 512, &Blds[buf][w * 8 + 64][0]);
    };

    const int ra  = wm * 32 + q31;
    const int rb0 = wn * 64 + q31;
    const int rb1 = wn * 64 + 32 + q31;
    int gA[4], gB0[4], gB1[4];
#pragma unroll
    for (int ks = 0; ks < 4; ++ks) {
        gA[ks]  = SWZ(2 * ks + hi, ra)  * 8;
        gB0[ks] = SWZ(2 * ks + hi, rb0) * 8;
        gB1[ks] = SWZ(2 * ks + hi, rb1) * 8;
    }

    f32x16 ac0 = {}, ac1 = {};
    stage(0, 0);

    for (int it = 0; it < 8; ++it) {
        const int buf = it & 1;
        asm volatile("s_waitcnt vmcnt(0)" ::: "memory");
        __syncthreads();
        if (it < 7) stage(buf ^ 1, (it + 1) * 64);

        const __hip_bfloat16* xa  = &Alds[buf][ra][0];
        const __hip_bfloat16* wb0 = &Blds[buf][rb0][0];
        const __hip_bfloat16* wb1 = &Blds[buf][rb1][0];

        __builtin_amdgcn_s_setprio(1);
#pragma unroll
        for (int ks = 0; ks < 4; ++ks) {
            bf16x8 a  = *(const bf16x8*)(xa  + gA[ks]);
            bf16x8 b0 = *(const bf16x8*)(wb0 + gB0[ks]);
            bf16x8 b1 = *(const bf16x8*)(wb1 + gB1[ks]);
            ac0 = MFMA32(a, b0, ac0);
            ac1 = MFMA32(a, b1, ac1);
        }
        __builtin_amdgcn_s_setprio(0);
    }

    // ---- epilogue: f32, lanes = consecutive cols -> coalesced ----
    const int row0 = m0 + wm * 32;
    const int col0 = n0 + wn * 64;
#pragma unroll
    for (int reg = 0; reg < 16; ++reg) {
        const int r = row0 + (reg & 3) + 8 * (reg >> 2) + 4 * hi;
        out[(size_t)r * 512 + col0 + q31]      = ac0[reg];
        out[(size_t)r * 512 + col0 + 32 + q31] = ac1[reg];
    }
}

// ---------------------------------------------------------------------------
extern "C" void kernel_launch(void* const* d_in, const int* in_sizes, int n_in,
                              void* d_out, int out_size, void* d_ws, size_t ws_size,
                              hipStream_t stream)
{
    const float* x_f  = (const float*)d_in[0];
    const float* Wk_f = (const float*)d_in[1];
    const float* Wq_f = (const float*)d_in[2];
    const float* Wv_f = (const float*)d_in[3];
    const float* Wo_f = (const float*)d_in[4];
    float* out = (float*)d_out;

    char* ws = (char*)d_ws;
    const size_t szQKV = (size_t)16 * 4096 * 64 * sizeof(__hip_bfloat16);   // 8.39 MB
    const size_t szX   = (size_t)8192 * 512 * sizeof(__hip_bfloat16);       // 8.39 MB
    const size_t szW   = (size_t)8 * 64 * 512 * sizeof(__hip_bfloat16);     // 0.5 MB
    const size_t szZp  = (size_t)16 * SLOTS_BH * 256 * 64 * sizeof(__hip_bfloat16); // 21 MB
    const size_t szML  = (size_t)16 * SLOTS_BH * 512 * sizeof(float);       // 1.3 MB

    // persistent region
    size_t off = 0;
    __hip_bfloat16* Qb  = (__hip_bfloat16*)(ws + off); off += szQKV;
    __hip_bfloat16* Kb  = (__hip_bfloat16*)(ws + off); off += szQKV;
    __hip_bfloat16* Vt  = (__hip_bfloat16*)(ws + off); off += szQKV;
    __hip_bfloat16* Zb  = (__hip_bfloat16*)(ws + off); off += szX;
    __hip_bfloat16* Wob = (__hip_bfloat16*)(ws + off); off += szW;
    // transient region 1 (dead after qkv_gemm): xb + Wk/Wq/Wv casts
    const size_t trans = off;
    __hip_bfloat16* xb  = (__hip_bfloat16*)(ws + trans);
    __hip_bfloat16* Wkb = (__hip_bfloat16*)(ws + trans + szX);
    __hip_bfloat16* Wqb = (__hip_bfloat16*)(ws + trans + szX + szW);
    __hip_bfloat16* Wvb = (__hip_bfloat16*)(ws + trans + szX + 2 * szW);
    // transient region 2 (attention partials) ALIASES region 1
    __hip_bfloat16* Zp  = (__hip_bfloat16*)(ws + trans);
    float*          ML  = (float*)(ws + trans + szZp);

    cast_all<<<2048 + 4 * 128, 256, 0, stream>>>(
        x_f, Wk_f, Wq_f, Wv_f, Wo_f, xb, Wkb, Wqb, Wvb, Wob);

    qkv_gemm<<<dim3(64, 12),   512, 0, stream>>>(xb, Wkb, Wqb, Wvb, Qb, Kb, Vt);
    attn_part<<<dim3(40, 16),  512, 0, stream>>>(Qb, Kb, Vt, Zp, ML, Zb);
    attn_combine<<<dim3(12, 16), 512, 0, stream>>>(Zp, ML, Zb);
    out_gemm<<<dim3(64, 4),    512, 0, stream>>>(Zb, Wob, out);
}

// Round 11
// 120.741 us; speedup vs baseline: 5.0810x; 1.1219x over previous
//
#include <hip/hip_runtime.h>
#include <hip/hip_bf16.h>

// b=2, s=4096, d_model=512, heads=8, d_head=64. I/O f32; compute bf16 MFMA.
// qkv/out: LDS-staged 128x128x64 GEMMs (gload_lds, dbuf, XOR swizzle).
// attn: 8-wave 256-q blocks, 32x32x16 MFMA, 2-buffer K/V (round-8 proven),
// swapped QK^T, in-register softmax (raw v_exp base-2, tree reduce, defer-max),
// P transpose via cvt_pk + permlane32_swap, split-KV 16-tile chunks.

typedef __attribute__((ext_vector_type(4)))  float  f32x4;
typedef __attribute__((ext_vector_type(16))) float  f32x16;
typedef __attribute__((ext_vector_type(8)))  __bf16 bf16x8;
typedef __attribute__((ext_vector_type(8)))  unsigned short u16x8;
typedef __attribute__((ext_vector_type(4)))  unsigned int u32x4;

#define MFMA16(a, b, c) __builtin_amdgcn_mfma_f32_16x16x32_bf16((a), (b), (c), 0, 0, 0)
#define MFMA32(a, b, c) __builtin_amdgcn_mfma_f32_32x32x16_bf16((a), (b), (c), 0, 0, 0)
#define SWZ(g, r) ((g) ^ ((r) & 7))
#define SLOTS_BH 40   // sum over qi=0..15 of (qi>>2)+1

static __device__ __forceinline__ bf16x8 ld8(const __hip_bfloat16* p) {
    return *reinterpret_cast<const bf16x8*>(p);
}
static __device__ __forceinline__ __hip_bfloat16 tobf(float f) {
    return __float2bfloat16(f);
}
static __device__ __forceinline__ float exp2_raw(float x) {
    float r;
    asm("v_exp_f32 %0, %1" : "=v"(r) : "v"(x));
    return r;
}
static __device__ __forceinline__ unsigned cvt_pk(float lo, float hi) {
    unsigned r;
    asm("v_cvt_pk_bf16_f32 %0, %1, %2" : "=v"(r) : "v"(lo), "v"(hi));
    return r;
}
static __device__ __forceinline__ void pl32swap(unsigned& a, unsigned& b) {
    asm("v_permlane32_swap_b32 %0, %1" : "+v"(a), "+v"(b));
}
static __device__ __forceinline__ void gl_lds16(const __hip_bfloat16* g, __hip_bfloat16* l) {
    typedef __attribute__((address_space(1))) const unsigned int GU;
    typedef __attribute__((address_space(3))) unsigned int LU;
    __builtin_amdgcn_global_load_lds((GU*)(const void*)g, (LU*)(void*)l, 16, 0, 0);
}
// chunks of 16 KV-tiles over 256-row q-tiles; nchunks(qi) = (qi>>2)+1
static __device__ __forceinline__ int slot_off(int qi) {
    const int a = qi >> 2;
    return qi + 2 * a * (a - 1) + a * (qi & 3);
}

// ---------------------------------------------------------------------------
// Fused cast: f32 -> bf16 for x (2048 blocks) + 4 weights (128 blocks each).
// ---------------------------------------------------------------------------
__global__ __launch_bounds__(256) void cast_all(
    const float* __restrict__ x,  const float* __restrict__ wk,
    const float* __restrict__ wq, const float* __restrict__ wv,
    const float* __restrict__ wo,
    __hip_bfloat16* __restrict__ xb,  __hip_bfloat16* __restrict__ wkb,
    __hip_bfloat16* __restrict__ wqb, __hip_bfloat16* __restrict__ wvb,
    __hip_bfloat16* __restrict__ wob)
{
    const int bid = blockIdx.x;
    const float* src;
    __hip_bfloat16* dst;
    int base;
    if (bid < 2048) { src = x; dst = xb; base = bid; }
    else {
        const int r = (bid - 2048) >> 7;
        base = (bid - 2048) & 127;
        src = (r == 0) ? wk : (r == 1) ? wq : (r == 2) ? wv : wo;
        dst = (r == 0) ? wkb : (r == 1) ? wqb : (r == 2) ? wvb : wob;
    }
    const size_t i = (size_t)base * 256 + threadIdx.x;
    const float4 a = *reinterpret_cast<const float4*>(src + i * 8);
    const float4 b = *reinterpret_cast<const float4*>(src + i * 8 + 4);
    u16x8 o;
    o[0] = __bfloat16_as_ushort(tobf(a.x));
    o[1] = __bfloat16_as_ushort(tobf(a.y));
    o[2] = __bfloat16_as_ushort(tobf(a.z));
    o[3] = __bfloat16_as_ushort(tobf(a.w));
    o[4] = __bfloat16_as_ushort(tobf(b.x));
    o[5] = __bfloat16_as_ushort(tobf(b.y));
    o[6] = __bfloat16_as_ushort(tobf(b.z));
    o[7] = __bfloat16_as_ushort(tobf(b.w));
    *reinterpret_cast<u16x8*>(dst + i * 8) = o;
}

// ---------------------------------------------------------------------------
// qkv_gemm: grid (64 mt, 12 ni), 512 thr (8 waves, 4m x 2n).
// ---------------------------------------------------------------------------
__global__ __launch_bounds__(512) void qkv_gemm(
    const __hip_bfloat16* __restrict__ x,    // [8192][512]
    const __hip_bfloat16* __restrict__ Wk,
    const __hip_bfloat16* __restrict__ Wq,
    const __hip_bfloat16* __restrict__ Wv,   // each [512][512] row-major
    __hip_bfloat16* __restrict__ Qo,   // [16][4096][64]
    __hip_bfloat16* __restrict__ Ko,   // [16][4096][64]
    __hip_bfloat16* __restrict__ Vt)   // [16][64][4096]
{
    __shared__ __hip_bfloat16 Xlds[2][128][64];
    __shared__ __hip_bfloat16 Wlds[2][128][64];

    const int mt = blockIdx.x;       // 0..63
    const int ni = blockIdx.y;       // 0..11
    const int z  = ni >> 2;          // 0=K 1=Q 2=V
    const int m0 = mt * 128;

    const __hip_bfloat16* Wz =
        (z == 0 ? Wk : (z == 1 ? Wq : Wv)) + (size_t)(ni & 3) * 128 * 512;

    const int tid  = threadIdx.x;
    const int w    = tid >> 6;        // 0..7
    const int lane = tid & 63;
    const int q31  = lane & 31;
    const int hi   = lane >> 5;
    const int wm   = w >> 1;          // 0..3 (m stripe)
    const int wn   = w & 1;           // 0..1 (n stripe)

    const int r0l = w * 8 + (lane >> 3);          // 0..63
    const int cg  = (lane & 7) ^ (r0l & 7);
    const __hip_bfloat16* Xsrc = x  + (size_t)(m0 + r0l) * 512 + cg * 8;
    const __hip_bfloat16* Wsrc = Wz + (size_t)r0l * 512 + cg * 8;

    auto stage = [&](int buf, int k0) {
        gl_lds16(Xsrc + k0,                    &Xlds[buf][w * 8][0]);
        gl_lds16(Xsrc + k0 + (size_t)64 * 512, &Xlds[buf][w * 8 + 64][0]);
        gl_lds16(Wsrc + k0,                    &Wlds[buf][w * 8][0]);
        gl_lds16(Wsrc + k0 + (size_t)64 * 512, &Wlds[buf][w * 8 + 64][0]);
    };

    const int ra  = wm * 32 + q31;
    const int rb0 = wn * 64 + q31;
    const int rb1 = wn * 64 + 32 + q31;
    int gA[4], gB0[4], gB1[4];
#pragma unroll
    for (int ks = 0; ks < 4; ++ks) {
        gA[ks]  = SWZ(2 * ks + hi, ra)  * 8;
        gB0[ks] = SWZ(2 * ks + hi, rb0) * 8;
        gB1[ks] = SWZ(2 * ks + hi, rb1) * 8;
    }

    f32x16 ac0 = {}, ac1 = {};
    stage(0, 0);

    for (int it = 0; it < 8; ++it) {
        const int buf = it & 1;
        asm volatile("s_waitcnt vmcnt(0)" ::: "memory");
        __syncthreads();
        if (it < 7) stage(buf ^ 1, (it + 1) * 64);

        const __hip_bfloat16* xa  = &Xlds[buf][ra][0];
        const __hip_bfloat16* wb0 = &Wlds[buf][rb0][0];
        const __hip_bfloat16* wb1 = &Wlds[buf][rb1][0];

        __builtin_amdgcn_s_setprio(1);
#pragma unroll
        for (int ks = 0; ks < 4; ++ks) {
            bf16x8 a  = *(const bf16x8*)(xa  + gA[ks]);
            bf16x8 b0 = *(const bf16x8*)(wb0 + gB0[ks]);
            bf16x8 b1 = *(const bf16x8*)(wb1 + gB1[ks]);
            ac0 = MFMA32(a, b0, ac0);
            ac1 = MFMA32(a, b1, ac1);
        }
        __builtin_amdgcn_s_setprio(0);
    }

    // ---- epilogue ----
    const int b     = m0 >> 12;
    const int sbase = (m0 & 4095) + wm * 32;
    const int hc0   = (ni & 3) * 128 + wn * 64;

    if (z == 2) {
        auto vstore = [&](const f32x16& ac, int cf) {
            const int hcol = hc0 + cf * 32 + q31;
            const int h = hcol >> 6, dh = hcol & 63;
            __hip_bfloat16* vbase =
                Vt + ((size_t)(b * 8 + h) * 64 + dh) * 4096;
#pragma unroll
            for (int q2 = 0; q2 < 4; ++q2) {
                ushort4 pk;
                pk.x = __bfloat16_as_ushort(tobf(ac[q2 * 4 + 0]));
                pk.y = __bfloat16_as_ushort(tobf(ac[q2 * 4 + 1]));
                pk.z = __bfloat16_as_ushort(tobf(ac[q2 * 4 + 2]));
                pk.w = __bfloat16_as_ushort(tobf(ac[q2 * 4 + 3]));
                *reinterpret_cast<ushort4*>(vbase + sbase + 8 * q2 + 4 * hi) = pk;
            }
        };
        vstore(ac0, 0);
        vstore(ac1, 1);
    } else {
        const float scale = (z == 1) ? 0.18033688f : 1.0f;  // 0.125/ln2 for Q
        __hip_bfloat16* O = (z == 0) ? Ko : Qo;
        auto kstore = [&](const f32x16& ac, int cf) {
            const int hcol = hc0 + cf * 32 + q31;
            const int h = hcol >> 6, dh = hcol & 63;
            __hip_bfloat16* obase =
                O + (size_t)(b * 8 + h) * 4096 * 64 + dh;
#pragma unroll
            for (int reg = 0; reg < 16; ++reg) {
                const int srow = sbase + (reg & 3) + 8 * (reg >> 2) + 4 * hi;
                obase[(size_t)srow * 64] = tobf(ac[reg] * scale);
            }
        };
        kstore(ac0, 0);
        kstore(ac1, 1);
    }
}

// ---------------------------------------------------------------------------
// attn_part: grid=(40, 16) flat deep-first, 512 thr, 8 waves.
// Round-8 proven structure: 2-buffer K/V, vmcnt(0)+barrier per iter.
// ---------------------------------------------------------------------------
__global__ __launch_bounds__(512) void attn_part(
    const __hip_bfloat16* __restrict__ Q,
    const __hip_bfloat16* __restrict__ K,
    const __hip_bfloat16* __restrict__ Vt,
    __hip_bfloat16* __restrict__ Zp,   // [slots][256 q][64 d] bf16
    float* __restrict__ ML,            // [slots][2][256]
    __hip_bfloat16* __restrict__ Z)    // [b][s][h*64] direct path
{
    __shared__ __hip_bfloat16 Klds[2][64][64];
    __shared__ __hip_bfloat16 Vlds[2][64][64];   // V^T tile: [d][p]
    __shared__ float als[8][32];

    // flat blockIdx.x -> (qi deep-first, chunk c)
    int rem = blockIdx.x, qi = 15, nc;
    for (;;) { nc = (qi >> 2) + 1; if (rem < nc) break; rem -= nc; --qi; }
    const int c  = rem;
    const int bh = blockIdx.y;

    const int w    = threadIdx.x >> 6;    // 0..7
    const int lane = threadIdx.x & 63;
    const int q31  = lane & 31;
    const int hi   = lane >> 5;

    const __hip_bfloat16* Qb = Q  + (size_t)bh * 4096 * 64;
    const __hip_bfloat16* Kb = K  + (size_t)bh * 4096 * 64;
    const __hip_bfloat16* Vb = Vt + (size_t)bh * 64 * 4096;

    const int wbase = qi * 256 + w * 32;   // wave's first q-row
    const int qrow  = wbase + q31;         // this lane's softmax q-row
    const int wqmax = wbase + 31;          // wave's deepest q-row

    // Q B-fragments (col=lane&31=q, k=d)
    bf16x8 qf[4];
#pragma unroll
    for (int ks = 0; ks < 4; ++ks)
        qf[ks] = ld8(Qb + (size_t)qrow * 64 + ks * 16 + hi * 8);

    f32x16 za0 = {}, za1 = {};
    float m_s  = -3.0e38f;
    float l_ln = 0.0f;

    const int t0   = c * 16;
    const int tend = min(t0 + 16, 4 * qi + 4);
    const int nt   = tend - t0;

    // hoisted swizzled LDS byte-granule offsets (loop-invariant)
    int gsx[4];
#pragma unroll
    for (int ks = 0; ks < 4; ++ks) gsx[ks] = SWZ(2 * ks + hi, q31) * 8;

    // ---- staging: wave w owns rows [w*8, w*8+8) of K and V^T tiles ----
    const int r0l = w * 8 + (lane >> 3);
    const int cg  = (lane & 7) ^ (r0l & 7);       // pre-swizzled source granule
    const __hip_bfloat16* Ksrc = Kb + (size_t)r0l * 64 + cg * 8;
    const __hip_bfloat16* Vsrc = Vb + (size_t)r0l * 4096 + cg * 8;

    auto stage = [&](int buf, int t) {
        const int p0 = t * 64;
        gl_lds16(Ksrc + (size_t)p0 * 64, &Klds[buf][w * 8][0]);
        gl_lds16(Vsrc + p0,              &Vlds[buf][w * 8][0]);
    };

    stage(0, t0);

    for (int it = 0; it < nt; ++it) {
        const int t   = t0 + it;
        const int buf = it & 1;

        asm volatile("s_waitcnt vmcnt(0)" ::: "memory");
        __syncthreads();
        if (it + 1 < nt) stage(buf ^ 1, t + 1);

        const int p0 = t * 64;
        if (p0 > wqmax) continue;   // wave fully masked (barriers stay uniform)

        const __hip_bfloat16* kb0 = &Klds[buf][q31][0];
        const __hip_bfloat16* kb1 = &Klds[buf][32 + q31][0];

        // ---- S^T = mfma(K, Q): 2 p-tiles x 4 k-slots ----
        f32x16 sa0 = {}, sa1 = {};
        __builtin_amdgcn_s_setprio(1);
#pragma unroll
        for (int ks = 0; ks < 4; ++ks) {
            bf16x8 k0 = *(const bf16x8*)(kb0 + gsx[ks]);
            bf16x8 k1 = *(const bf16x8*)(kb1 + gsx[ks]);
            sa0 = MFMA32(k0, qf[ks], sa0);
            sa1 = MFMA32(k1, qf[ks], sa1);
        }
        __builtin_amdgcn_s_setprio(0);

        // ---- causal mask (only where tile crosses this wave's diagonal) ----
        if (p0 + 63 > wbase) {
#pragma unroll
            for (int reg = 0; reg < 16; ++reg) {
                const int pl = (reg & 3) + 8 * (reg >> 2) + 4 * hi;
                const int p  = p0 + pl;
                sa0[reg] = (p      <= qrow) ? sa0[reg] : -1.0e30f;
                sa1[reg] = (p + 32 <= qrow) ? sa1[reg] : -1.0e30f;
            }
        }

        // ---- row max: tree reduce + cross-half ----
        float tm[8];
#pragma unroll
        for (int i = 0; i < 8; ++i)
            tm[i] = fmaxf(fmaxf(sa0[i], sa0[i + 8]), fmaxf(sa1[i], sa1[i + 8]));
#pragma unroll
        for (int s = 4; s; s >>= 1)
#pragma unroll
            for (int i = 0; i < s; ++i) tm[i] = fmaxf(tm[i], tm[i + s]);
        float mx = fmaxf(tm[0], __shfl_xor(tm[0], 32));

        // ---- defer-max: rescale only when max grew past threshold ----
        if (!__all(mx <= m_s + 8.0f)) {
            const float mnew  = fmaxf(m_s, mx);
            const float alpha = exp2_raw(m_s - mnew);
            m_s = mnew;
            l_ln *= alpha;
            if (hi == 0) als[w][q31] = alpha;
#pragma unroll
            for (int reg = 0; reg < 16; ++reg) {
                const int q = (reg & 3) + 8 * (reg >> 2) + 4 * hi;
                const float av = als[w][q];
                za0[reg] *= av;
                za1[reg] *= av;
            }
        }

        // ---- P = 2^(S - m), tree l-sum ----
#pragma unroll
        for (int reg = 0; reg < 16; ++reg) {
            sa0[reg] = exp2_raw(sa0[reg] - m_s);
            sa1[reg] = exp2_raw(sa1[reg] - m_s);
        }
        float ts[8];
#pragma unroll
        for (int i = 0; i < 8; ++i)
            ts[i] = (sa0[i] + sa0[i + 8]) + (sa1[i] + sa1[i + 8]);
#pragma unroll
        for (int s = 4; s; s >>= 1)
#pragma unroll
            for (int i = 0; i < s; ++i) ts[i] += ts[i + s];
        l_ln += ts[0];

        // ---- in-register P transpose -> A-frags (cvt_pk + permlane32_swap) --
        bf16x8 pfrag[4];
#pragma unroll
        for (int kb = 0; kb < 4; ++kb) {
            const int e = (kb & 1) * 8;
            unsigned px, py, pu, pv;
            if (kb < 2) {
                px = cvt_pk(sa0[e + 0], sa0[e + 1]);
                py = cvt_pk(sa0[e + 2], sa0[e + 3]);
                pu = cvt_pk(sa0[e + 4], sa0[e + 5]);
                pv = cvt_pk(sa0[e + 6], sa0[e + 7]);
            } else {
                px = cvt_pk(sa1[e + 0], sa1[e + 1]);
                py = cvt_pk(sa1[e + 2], sa1[e + 3]);
                pu = cvt_pk(sa1[e + 4], sa1[e + 5]);
                pv = cvt_pk(sa1[e + 6], sa1[e + 7]);
            }
            pl32swap(px, pu);
            pl32swap(py, pv);
            u32x4 fw;
            fw[0] = px; fw[1] = py; fw[2] = pu; fw[3] = pv;
            pfrag[kb] = __builtin_bit_cast(bf16x8, fw);
        }

        const __hip_bfloat16* vb0 = &Vlds[buf][q31][0];
        const __hip_bfloat16* vb1 = &Vlds[buf][32 + q31][0];

        // ---- Z += P V (A=P row=q, B=V^T col=d) ----
        __builtin_amdgcn_s_setprio(1);
#pragma unroll
        for (int kb = 0; kb < 4; ++kb) {
            bf16x8 v0 = *(const bf16x8*)(vb0 + gsx[kb]);
            bf16x8 v1 = *(const bf16x8*)(vb1 + gsx[kb]);
            za0 = MFMA32(pfrag[kb], v0, za0);
            za1 = MFMA32(pfrag[kb], v1, za1);
        }
        __builtin_amdgcn_s_setprio(0);
    }

    // ---- epilogue ----
    float lt = l_ln + __shfl_xor(l_ln, 32);

    if (nc == 1) {
        // single-chunk row: normalize and write straight to Z
        if (hi == 0) als[w][q31] = 1.0f / lt;
        const int b = bh >> 3, h = bh & 7;
#pragma unroll
        for (int reg = 0; reg < 16; ++reg) {
            const int q = (reg & 3) + 8 * (reg >> 2) + 4 * hi;
            const float inv = als[w][q];
            __hip_bfloat16* zo =
                Z + ((size_t)b * 4096 + qi * 256 + w * 32 + q) * 512 + h * 64 + q31;
            zo[0]  = tobf(za0[reg] * inv);
            zo[32] = tobf(za1[reg] * inv);
        }
    } else {
        const int slot = bh * SLOTS_BH + slot_off(qi) + c;
        if (hi == 0) {
            ML[(size_t)slot * 512 +       w * 32 + q31] = m_s;
            ML[(size_t)slot * 512 + 256 + w * 32 + q31] = lt;
        }
#pragma unroll
        for (int reg = 0; reg < 16; ++reg) {
            const int q = (reg & 3) + 8 * (reg >> 2) + 4 * hi;
            const size_t base =
                (size_t)slot * 16384 + (size_t)(w * 32 + q) * 64 + q31;
            Zp[base]      = tobf(za0[reg]);
            Zp[base + 32] = tobf(za1[reg]);
        }
    }
}

// ---------------------------------------------------------------------------
// attn_combine: grid=(12 qi-4, 16 bh), 512 thr. q = tid>>1, half = tid&1.
// ---------------------------------------------------------------------------
__global__ __launch_bounds__(512) void attn_combine(
    const __hip_bfloat16* __restrict__ Zp,
    const float* __restrict__ ML,
    __hip_bfloat16* __restrict__ Z)    // [b][s][h*64]
{
    const int qi = blockIdx.x + 4;
    const int bh = blockIdx.y;
    const int nc = (qi >> 2) + 1;
    const int q    = threadIdx.x >> 1;
    const int half = threadIdx.x & 1;

    const int slot0 = bh * SLOTS_BH + slot_off(qi);

    float M = -3.0e38f;
    for (int i = 0; i < nc; ++i)
        M = fmaxf(M, ML[(size_t)(slot0 + i) * 512 + q]);

    float L = 0.0f;
    float acc[32];
#pragma unroll
    for (int j = 0; j < 32; ++j) acc[j] = 0.0f;

    for (int i = 0; i < nc; ++i) {
        const float wgt = exp2_raw(ML[(size_t)(slot0 + i) * 512 + q] - M);
        L += wgt * ML[(size_t)(slot0 + i) * 512 + 256 + q];
        const __hip_bfloat16* zp =
            Zp + (size_t)(slot0 + i) * 16384 + (size_t)q * 64 + half * 32;
#pragma unroll
        for (int v = 0; v < 4; ++v) {
            bf16x8 z = ld8(zp + v * 8);
#pragma unroll
            for (int j = 0; j < 8; ++j) acc[v * 8 + j] += wgt * (float)z[j];
        }
    }

    const float inv = 1.0f / L;
    const int b = bh >> 3, h = bh & 7;
    __hip_bfloat16* zo =
        Z + ((size_t)b * 4096 + qi * 256 + q) * 512 + h * 64 + half * 32;
#pragma unroll
    for (int v = 0; v < 4; ++v) {
        u16x8 o;
#pragma unroll
        for (int j = 0; j < 8; ++j)
            o[j] = __bfloat16_as_ushort(tobf(acc[v * 8 + j] * inv));
        *reinterpret_cast<u16x8*>(zo + v * 8) = o;
    }
}

// ---------------------------------------------------------------------------
// out_gemm: grid (64 mt, 4 ni), 512 thr. LDS-staged 128x128x64 GEMM.
// out[8192][512] f32 = Z[8192][512] @ Wo^T. Coalesced f32 epilogue.
// ---------------------------------------------------------------------------
__global__ __launch_bounds__(512) void out_gemm(
    const __hip_bfloat16* __restrict__ Zf,   // [8192][512]
    const __hip_bfloat16* __restrict__ Wo,   // [512][512] bf16
    float* __restrict__ out)                 // [8192][512] f32
{
    __shared__ __hip_bfloat16 Alds[2][128][64];
    __shared__ __hip_bfloat16 Blds[2][128][64];

    const int mt = blockIdx.x;       // 0..63
    const int ni = blockIdx.y;       // 0..3
    const int m0 = mt * 128;
    const int n0 = ni * 128;

    const int tid  = threadIdx.x;
    const int w    = tid >> 6;
    const int lane = tid & 63;
    const int q31  = lane & 31;
    const int hi   = lane >> 5;
    const int wm   = w >> 1;
    const int wn   = w & 1;

    const int r0l = w * 8 + (lane >> 3);
    const int cg  = (lane & 7) ^ (r0l & 7);
    const __hip_bfloat16* Asrc = Zf + (size_t)(m0 + r0l) * 512 + cg * 8;
    const __hip_bfloat16* Bsrc = Wo + (size_t)(n0 + r0l) * 512 + cg * 8;

    auto stage = [&](int buf, int k0) {
        gl_lds16(Asrc + k0,                    &Alds[buf][w * 8][0]);
        gl_lds16(Asrc + k0 + (size_t)64 * 512, &Alds[buf][w * 8 + 64][0]);
        gl_lds16(Bsrc + k0,                    &Blds[buf][w * 8][0]);
        gl_lds16(Bsrc + k0 + (size_t)64 * 512, &Blds[buf][w * 8 + 64][0]);
    };

    const int ra  = wm * 32 + q31;
    const int rb0 = wn * 64 + q31;
    const int rb1 = wn * 64 + 32 + q31;
    int gA[4], gB0[4], gB1[4];
#pragma unroll
    for (int ks = 0; ks < 4; ++ks) {
        gA[ks]  = SWZ(2 * ks + hi, ra)  * 8;
        gB0[ks] = SWZ(2 * ks + hi, rb0) * 8;
        gB1[ks] = SWZ(2 * ks + hi, rb1) * 8;
    }

    f32x16 ac0 = {}, ac1 = {};
    stage(0, 0);

    for (int it = 0; it < 8; ++it) {
        const int buf = it & 1;
        asm volatile("s_waitcnt vmcnt(0)" ::: "memory");
        __syncthreads();
        if (it < 7) stage(buf ^ 1, (it + 1) * 64);

        const __hip_bfloat16* xa  = &Alds[buf][ra][0];
        const __hip_bfloat16* wb0 = &Blds[buf][rb0][0];
        const __hip_bfloat16* wb1 = &Blds[buf][rb1][0];

        __builtin_amdgcn_s_setprio(1);
#pragma unroll
        for (int ks = 0; ks < 4; ++ks) {
            bf16x8 a  = *(const bf16x8*)(xa  + gA[ks]);
            bf16x8 b0 = *(const bf16x8*)(wb0 + gB0[ks]);
            bf16x8 b1 = *(const bf16x8*)(wb1 + gB1[ks]);
            ac0 = MFMA32(a, b0, ac0);
            ac1 = MFMA32(a, b1, ac1);
        }
        __builtin_amdgcn_s_setprio(0);
    }

    // ---- epilogue: f32, lanes = consecutive cols -> coalesced ----
    const int row0 = m0 + wm * 32;
    const int col0 = n0 + wn * 64;
#pragma unroll
    for (int reg = 0; reg < 16; ++reg) {
        const int r = row0 + (reg & 3) + 8 * (reg >> 2) + 4 * hi;
        out[(size_t)r * 512 + col0 + q31]      = ac0[reg];
        out[(size_t)r * 512 + col0 + 32 + q31] = ac1[reg];
    }
}

// ---------------------------------------------------------------------------
extern "C" void kernel_launch(void* const* d_in, const int* in_sizes, int n_in,
                              void* d_out, int out_size, void* d_ws, size_t ws_size,
                              hipStream_t stream)
{
    const float* x_f  = (const float*)d_in[0];
    const float* Wk_f = (const float*)d_in[1];
    const float* Wq_f = (const float*)d_in[2];
    const float* Wv_f = (const float*)d_in[3];
    const float* Wo_f = (const float*)d_in[4];
    float* out = (float*)d_out;

    char* ws = (char*)d_ws;
    const size_t szQKV = (size_t)16 * 4096 * 64 * sizeof(__hip_bfloat16);   // 8.39 MB
    const size_t szX   = (size_t)8192 * 512 * sizeof(__hip_bfloat16);       // 8.39 MB
    const size_t szW   = (size_t)8 * 64 * 512 * sizeof(__hip_bfloat16);     // 0.5 MB
    const size_t szZp  = (size_t)16 * SLOTS_BH * 256 * 64 * sizeof(__hip_bfloat16); // 21 MB
    const size_t szML  = (size_t)16 * SLOTS_BH * 512 * sizeof(float);       // 1.3 MB

    // persistent region
    size_t off = 0;
    __hip_bfloat16* Qb  = (__hip_bfloat16*)(ws + off); off += szQKV;
    __hip_bfloat16* Kb  = (__hip_bfloat16*)(ws + off); off += szQKV;
    __hip_bfloat16* Vt  = (__hip_bfloat16*)(ws + off); off += szQKV;
    __hip_bfloat16* Zb  = (__hip_bfloat16*)(ws + off); off += szX;
    __hip_bfloat16* Wob = (__hip_bfloat16*)(ws + off); off += szW;
    // transient region 1 (dead after qkv_gemm): xb + Wk/Wq/Wv casts
    const size_t trans = off;
    __hip_bfloat16* xb  = (__hip_bfloat16*)(ws + trans);
    __hip_bfloat16* Wkb = (__hip_bfloat16*)(ws + trans + szX);
    __hip_bfloat16* Wqb = (__hip_bfloat16*)(ws + trans + szX + szW);
    __hip_bfloat16* Wvb = (__hip_bfloat16*)(ws + trans + szX + 2 * szW);
    // transient region 2 (attention partials) ALIASES region 1
    __hip_bfloat16* Zp  = (__hip_bfloat16*)(ws + trans);
    float*          ML  = (float*)(ws + trans + szZp);

    cast_all<<<2048 + 4 * 128, 256, 0, stream>>>(
        x_f, Wk_f, Wq_f, Wv_f, Wo_f, xb, Wkb, Wqb, Wvb, Wob);

    qkv_gemm<<<dim3(64, 12),   512, 0, stream>>>(xb, Wkb, Wqb, Wvb, Qb, Kb, Vt);
    attn_part<<<dim3(40, 16),  512, 0, stream>>>(Qb, Kb, Vt, Zp, ML, Zb);
    attn_combine<<<dim3(12, 16), 512, 0, stream>>>(Zp, ML, Zb);
    out_gemm<<<dim3(64, 4),    512, 0, stream>>>(Zb, Wob, out);
}

// Round 12
// 109.208 us; speedup vs baseline: 5.6176x; 1.1056x over previous
//
#include <hip/hip_runtime.h>
#include <hip/hip_bf16.h>

// b=2, s=4096, d_model=512, heads=8, d_head=64. I/O f32; compute bf16 MFMA.
// qkv/out: LDS-staged 128x128x64 GEMMs (gload_lds, dbuf, XOR swizzle).
// attn: 8-wave 256-q blocks, 32x32x16 MFMA, 2-buffer K/V, swapped QK^T,
// in-register softmax (raw v_exp base-2, tree reduce, defer-max), P transpose
// via cvt_pk + permlane32_swap. Split-KV with UNIFORM 8-tile chunks and
// bh->XCD locality swizzle (each XCD owns 2 bh -> K/V L2-resident).

typedef __attribute__((ext_vector_type(4)))  float  f32x4;
typedef __attribute__((ext_vector_type(16))) float  f32x16;
typedef __attribute__((ext_vector_type(8)))  __bf16 bf16x8;
typedef __attribute__((ext_vector_type(8)))  unsigned short u16x8;
typedef __attribute__((ext_vector_type(4)))  unsigned int u32x4;

#define MFMA16(a, b, c) __builtin_amdgcn_mfma_f32_16x16x32_bf16((a), (b), (c), 0, 0, 0)
#define MFMA32(a, b, c) __builtin_amdgcn_mfma_f32_32x32x16_bf16((a), (b), (c), 0, 0, 0)
#define SWZ(g, r) ((g) ^ ((r) & 7))
#define SLOTS_BH 72   // sum over qi=0..15 of ceil((4qi+4)/8)

static __device__ __forceinline__ bf16x8 ld8(const __hip_bfloat16* p) {
    return *reinterpret_cast<const bf16x8*>(p);
}
static __device__ __forceinline__ __hip_bfloat16 tobf(float f) {
    return __float2bfloat16(f);
}
static __device__ __forceinline__ float exp2_raw(float x) {
    float r;
    asm("v_exp_f32 %0, %1" : "=v"(r) : "v"(x));
    return r;
}
static __device__ __forceinline__ unsigned cvt_pk(float lo, float hi) {
    unsigned r;
    asm("v_cvt_pk_bf16_f32 %0, %1, %2" : "=v"(r) : "v"(lo), "v"(hi));
    return r;
}
static __device__ __forceinline__ void pl32swap(unsigned& a, unsigned& b) {
    asm("v_permlane32_swap_b32 %0, %1" : "+v"(a), "+v"(b));
}
static __device__ __forceinline__ void gl_lds16(const __hip_bfloat16* g, __hip_bfloat16* l) {
    typedef __attribute__((address_space(1))) const unsigned int GU;
    typedef __attribute__((address_space(3))) unsigned int LU;
    __builtin_amdgcn_global_load_lds((GU*)(const void*)g, (LU*)(void*)l, 16, 0, 0);
}
// chunks of 8 KV-tiles over 256-row q-tiles; nchunks(qi) = (qi+2)>>1
static __device__ __forceinline__ int nchunks(int qi) { return (qi + 2) >> 1; }
static __device__ __forceinline__ int slot_off(int qi) {
    const int a = qi >> 1;
    return (qi & 1) ? (a + 1) * (a + 1) : a * a + a;
}

// ---------------------------------------------------------------------------
// Fused cast: f32 -> bf16 for x (2048 blocks) + 4 weights (128 blocks each).
// ---------------------------------------------------------------------------
__global__ __launch_bounds__(256) void cast_all(
    const float* __restrict__ x,  const float* __restrict__ wk,
    const float* __restrict__ wq, const float* __restrict__ wv,
    const float* __restrict__ wo,
    __hip_bfloat16* __restrict__ xb,  __hip_bfloat16* __restrict__ wkb,
    __hip_bfloat16* __restrict__ wqb, __hip_bfloat16* __restrict__ wvb,
    __hip_bfloat16* __restrict__ wob)
{
    const int bid = blockIdx.x;
    const float* src;
    __hip_bfloat16* dst;
    int base;
    if (bid < 2048) { src = x; dst = xb; base = bid; }
    else {
        const int r = (bid - 2048) >> 7;
        base = (bid - 2048) & 127;
        src = (r == 0) ? wk : (r == 1) ? wq : (r == 2) ? wv : wo;
        dst = (r == 0) ? wkb : (r == 1) ? wqb : (r == 2) ? wvb : wob;
    }
    const size_t i = (size_t)base * 256 + threadIdx.x;
    const float4 a = *reinterpret_cast<const float4*>(src + i * 8);
    const float4 b = *reinterpret_cast<const float4*>(src + i * 8 + 4);
    u16x8 o;
    o[0] = __bfloat16_as_ushort(tobf(a.x));
    o[1] = __bfloat16_as_ushort(tobf(a.y));
    o[2] = __bfloat16_as_ushort(tobf(a.z));
    o[3] = __bfloat16_as_ushort(tobf(a.w));
    o[4] = __bfloat16_as_ushort(tobf(b.x));
    o[5] = __bfloat16_as_ushort(tobf(b.y));
    o[6] = __bfloat16_as_ushort(tobf(b.z));
    o[7] = __bfloat16_as_ushort(tobf(b.w));
    *reinterpret_cast<u16x8*>(dst + i * 8) = o;
}

// ---------------------------------------------------------------------------
// qkv_gemm: grid (64 mt, 12 ni), 512 thr (8 waves, 4m x 2n).
// ---------------------------------------------------------------------------
__global__ __launch_bounds__(512) void qkv_gemm(
    const __hip_bfloat16* __restrict__ x,    // [8192][512]
    const __hip_bfloat16* __restrict__ Wk,
    const __hip_bfloat16* __restrict__ Wq,
    const __hip_bfloat16* __restrict__ Wv,   // each [512][512] row-major
    __hip_bfloat16* __restrict__ Qo,   // [16][4096][64]
    __hip_bfloat16* __restrict__ Ko,   // [16][4096][64]
    __hip_bfloat16* __restrict__ Vt)   // [16][64][4096]
{
    __shared__ __hip_bfloat16 Xlds[2][128][64];
    __shared__ __hip_bfloat16 Wlds[2][128][64];

    const int mt = blockIdx.x;       // 0..63
    const int ni = blockIdx.y;       // 0..11
    const int z  = ni >> 2;          // 0=K 1=Q 2=V
    const int m0 = mt * 128;

    const __hip_bfloat16* Wz =
        (z == 0 ? Wk : (z == 1 ? Wq : Wv)) + (size_t)(ni & 3) * 128 * 512;

    const int tid  = threadIdx.x;
    const int w    = tid >> 6;        // 0..7
    const int lane = tid & 63;
    const int q31  = lane & 31;
    const int hi   = lane >> 5;
    const int wm   = w >> 1;          // 0..3 (m stripe)
    const int wn   = w & 1;           // 0..1 (n stripe)

    const int r0l = w * 8 + (lane >> 3);          // 0..63
    const int cg  = (lane & 7) ^ (r0l & 7);
    const __hip_bfloat16* Xsrc = x  + (size_t)(m0 + r0l) * 512 + cg * 8;
    const __hip_bfloat16* Wsrc = Wz + (size_t)r0l * 512 + cg * 8;

    auto stage = [&](int buf, int k0) {
        gl_lds16(Xsrc + k0,                    &Xlds[buf][w * 8][0]);
        gl_lds16(Xsrc + k0 + (size_t)64 * 512, &Xlds[buf][w * 8 + 64][0]);
        gl_lds16(Wsrc + k0,                    &Wlds[buf][w * 8][0]);
        gl_lds16(Wsrc + k0 + (size_t)64 * 512, &Wlds[buf][w * 8 + 64][0]);
    };

    const int ra  = wm * 32 + q31;
    const int rb0 = wn * 64 + q31;
    const int rb1 = wn * 64 + 32 + q31;
    int gA[4], gB0[4], gB1[4];
#pragma unroll
    for (int ks = 0; ks < 4; ++ks) {
        gA[ks]  = SWZ(2 * ks + hi, ra)  * 8;
        gB0[ks] = SWZ(2 * ks + hi, rb0) * 8;
        gB1[ks] = SWZ(2 * ks + hi, rb1) * 8;
    }

    f32x16 ac0 = {}, ac1 = {};
    stage(0, 0);

    for (int it = 0; it < 8; ++it) {
        const int buf = it & 1;
        asm volatile("s_waitcnt vmcnt(0)" ::: "memory");
        __syncthreads();
        if (it < 7) stage(buf ^ 1, (it + 1) * 64);

        const __hip_bfloat16* xa  = &Xlds[buf][ra][0];
        const __hip_bfloat16* wb0 = &Wlds[buf][rb0][0];
        const __hip_bfloat16* wb1 = &Wlds[buf][rb1][0];

        __builtin_amdgcn_s_setprio(1);
#pragma unroll
        for (int ks = 0; ks < 4; ++ks) {
            bf16x8 a  = *(const bf16x8*)(xa  + gA[ks]);
            bf16x8 b0 = *(const bf16x8*)(wb0 + gB0[ks]);
            bf16x8 b1 = *(const bf16x8*)(wb1 + gB1[ks]);
            ac0 = MFMA32(a, b0, ac0);
            ac1 = MFMA32(a, b1, ac1);
        }
        __builtin_amdgcn_s_setprio(0);
    }

    // ---- epilogue ----
    const int b     = m0 >> 12;
    const int sbase = (m0 & 4095) + wm * 32;
    const int hc0   = (ni & 3) * 128 + wn * 64;

    if (z == 2) {
        auto vstore = [&](const f32x16& ac, int cf) {
            const int hcol = hc0 + cf * 32 + q31;
            const int h = hcol >> 6, dh = hcol & 63;
            __hip_bfloat16* vbase =
                Vt + ((size_t)(b * 8 + h) * 64 + dh) * 4096;
#pragma unroll
            for (int q2 = 0; q2 < 4; ++q2) {
                ushort4 pk;
                pk.x = __bfloat16_as_ushort(tobf(ac[q2 * 4 + 0]));
                pk.y = __bfloat16_as_ushort(tobf(ac[q2 * 4 + 1]));
                pk.z = __bfloat16_as_ushort(tobf(ac[q2 * 4 + 2]));
                pk.w = __bfloat16_as_ushort(tobf(ac[q2 * 4 + 3]));
                *reinterpret_cast<ushort4*>(vbase + sbase + 8 * q2 + 4 * hi) = pk;
            }
        };
        vstore(ac0, 0);
        vstore(ac1, 1);
    } else {
        const float scale = (z == 1) ? 0.18033688f : 1.0f;  // 0.125/ln2 for Q
        __hip_bfloat16* O = (z == 0) ? Ko : Qo;
        auto kstore = [&](const f32x16& ac, int cf) {
            const int hcol = hc0 + cf * 32 + q31;
            const int h = hcol >> 6, dh = hcol & 63;
            __hip_bfloat16* obase =
                O + (size_t)(b * 8 + h) * 4096 * 64 + dh;
#pragma unroll
            for (int reg = 0; reg < 16; ++reg) {
                const int srow = sbase + (reg & 3) + 8 * (reg >> 2) + 4 * hi;
                obase[(size_t)srow * 64] = tobf(ac[reg] * scale);
            }
        };
        kstore(ac0, 0);
        kstore(ac1, 1);
    }
}

// ---------------------------------------------------------------------------
// attn_part: 1D grid of 1152 blocks, 512 thr, 8 waves.
// id -> (bh, chunk): bh = ((id&7)<<1)|((id>>3)&1) so each XCD (id%8) works
// 2 bh only (K/V L2-resident); chunk = id>>4 deep-first (qi=15 first).
// Uniform chunks of <=8 KV tiles. Rows with nc==1 (qi<=1) write Z directly.
// ---------------------------------------------------------------------------
__global__ __launch_bounds__(512) void attn_part(
    const __hip_bfloat16* __restrict__ Q,
    const __hip_bfloat16* __restrict__ K,
    const __hip_bfloat16* __restrict__ Vt,
    __hip_bfloat16* __restrict__ Zp,   // [slots][256 q][64 d] bf16
    float* __restrict__ ML,            // [slots][2][256]
    __hip_bfloat16* __restrict__ Z)    // [b][s][h*64] direct path
{
    __shared__ __hip_bfloat16 Klds[2][64][64];
    __shared__ __hip_bfloat16 Vlds[2][64][64];   // V^T tile: [d][p]
    __shared__ float als[8][32];

    const int id = blockIdx.x;
    const int bh = ((id & 7) << 1) | ((id >> 3) & 1);
    int rem = id >> 4;               // chunk index within bh, deep-first
    int qi = 15;
    for (;;) { const int ncq = nchunks(qi); if (rem < ncq) break; rem -= ncq; --qi; }
    const int c  = rem;
    const int nc = nchunks(qi);

    const int w    = threadIdx.x >> 6;    // 0..7
    const int lane = threadIdx.x & 63;
    const int q31  = lane & 31;
    const int hi   = lane >> 5;

    const __hip_bfloat16* Qb = Q  + (size_t)bh * 4096 * 64;
    const __hip_bfloat16* Kb = K  + (size_t)bh * 4096 * 64;
    const __hip_bfloat16* Vb = Vt + (size_t)bh * 64 * 4096;

    const int wbase = qi * 256 + w * 32;   // wave's first q-row
    const int qrow  = wbase + q31;         // this lane's softmax q-row
    const int wqmax = wbase + 31;          // wave's deepest q-row

    // Q B-fragments (col=lane&31=q, k=d)
    bf16x8 qf[4];
#pragma unroll
    for (int ks = 0; ks < 4; ++ks)
        qf[ks] = ld8(Qb + (size_t)qrow * 64 + ks * 16 + hi * 8);

    f32x16 za0 = {}, za1 = {};
    float m_s  = -3.0e38f;
    float l_ln = 0.0f;

    const int t0   = c * 8;
    const int tend = min(t0 + 8, 4 * qi + 4);
    const int nt   = tend - t0;

    // hoisted swizzled LDS byte-granule offsets (loop-invariant)
    int gsx[4];
#pragma unroll
    for (int ks = 0; ks < 4; ++ks) gsx[ks] = SWZ(2 * ks + hi, q31) * 8;

    // ---- staging: wave w owns rows [w*8, w*8+8) of K and V^T tiles ----
    const int r0l = w * 8 + (lane >> 3);
    const int cg  = (lane & 7) ^ (r0l & 7);       // pre-swizzled source granule
    const __hip_bfloat16* Ksrc = Kb + (size_t)r0l * 64 + cg * 8;
    const __hip_bfloat16* Vsrc = Vb + (size_t)r0l * 4096 + cg * 8;

    auto stage = [&](int buf, int t) {
        const int p0 = t * 64;
        gl_lds16(Ksrc + (size_t)p0 * 64, &Klds[buf][w * 8][0]);
        gl_lds16(Vsrc + p0,              &Vlds[buf][w * 8][0]);
    };

    stage(0, t0);

    for (int it = 0; it < nt; ++it) {
        const int t   = t0 + it;
        const int buf = it & 1;

        asm volatile("s_waitcnt vmcnt(0)" ::: "memory");
        __syncthreads();
        if (it + 1 < nt) stage(buf ^ 1, t + 1);

        const int p0 = t * 64;
        if (p0 > wqmax) continue;   // wave fully masked (barriers stay uniform)

        const __hip_bfloat16* kb0 = &Klds[buf][q31][0];
        const __hip_bfloat16* kb1 = &Klds[buf][32 + q31][0];

        // ---- S^T = mfma(K, Q): 2 p-tiles x 4 k-slots ----
        f32x16 sa0 = {}, sa1 = {};
        __builtin_amdgcn_s_setprio(1);
#pragma unroll
        for (int ks = 0; ks < 4; ++ks) {
            bf16x8 k0 = *(const bf16x8*)(kb0 + gsx[ks]);
            bf16x8 k1 = *(const bf16x8*)(kb1 + gsx[ks]);
            sa0 = MFMA32(k0, qf[ks], sa0);
            sa1 = MFMA32(k1, qf[ks], sa1);
        }
        __builtin_amdgcn_s_setprio(0);

        // ---- causal mask (only where tile crosses this wave's diagonal) ----
        if (p0 + 63 > wbase) {
#pragma unroll
            for (int reg = 0; reg < 16; ++reg) {
                const int pl = (reg & 3) + 8 * (reg >> 2) + 4 * hi;
                const int p  = p0 + pl;
                sa0[reg] = (p      <= qrow) ? sa0[reg] : -1.0e30f;
                sa1[reg] = (p + 32 <= qrow) ? sa1[reg] : -1.0e30f;
            }
        }

        // ---- row max: tree reduce + cross-half ----
        float tm[8];
#pragma unroll
        for (int i = 0; i < 8; ++i)
            tm[i] = fmaxf(fmaxf(sa0[i], sa0[i + 8]), fmaxf(sa1[i], sa1[i + 8]));
#pragma unroll
        for (int s = 4; s; s >>= 1)
#pragma unroll
            for (int i = 0; i < s; ++i) tm[i] = fmaxf(tm[i], tm[i + s]);
        float mx = fmaxf(tm[0], __shfl_xor(tm[0], 32));

        // ---- defer-max: rescale only when max grew past threshold ----
        if (!__all(mx <= m_s + 8.0f)) {
            const float mnew  = fmaxf(m_s, mx);
            const float alpha = exp2_raw(m_s - mnew);
            m_s = mnew;
            l_ln *= alpha;
            if (hi == 0) als[w][q31] = alpha;
#pragma unroll
            for (int reg = 0; reg < 16; ++reg) {
                const int q = (reg & 3) + 8 * (reg >> 2) + 4 * hi;
                const float av = als[w][q];
                za0[reg] *= av;
                za1[reg] *= av;
            }
        }

        // ---- P = 2^(S - m), tree l-sum ----
#pragma unroll
        for (int reg = 0; reg < 16; ++reg) {
            sa0[reg] = exp2_raw(sa0[reg] - m_s);
            sa1[reg] = exp2_raw(sa1[reg] - m_s);
        }
        float ts[8];
#pragma unroll
        for (int i = 0; i < 8; ++i)
            ts[i] = (sa0[i] + sa0[i + 8]) + (sa1[i] + sa1[i + 8]);
#pragma unroll
        for (int s = 4; s; s >>= 1)
#pragma unroll
            for (int i = 0; i < s; ++i) ts[i] += ts[i + s];
        l_ln += ts[0];

        // ---- in-register P transpose -> A-frags (cvt_pk + permlane32_swap) --
        bf16x8 pfrag[4];
#pragma unroll
        for (int kb = 0; kb < 4; ++kb) {
            const int e = (kb & 1) * 8;
            unsigned px, py, pu, pv;
            if (kb < 2) {
                px = cvt_pk(sa0[e + 0], sa0[e + 1]);
                py = cvt_pk(sa0[e + 2], sa0[e + 3]);
                pu = cvt_pk(sa0[e + 4], sa0[e + 5]);
                pv = cvt_pk(sa0[e + 6], sa0[e + 7]);
            } else {
                px = cvt_pk(sa1[e + 0], sa1[e + 1]);
                py = cvt_pk(sa1[e + 2], sa1[e + 3]);
                pu = cvt_pk(sa1[e + 4], sa1[e + 5]);
                pv = cvt_pk(sa1[e + 6], sa1[e + 7]);
            }
            pl32swap(px, pu);
            pl32swap(py, pv);
            u32x4 fw;
            fw[0] = px; fw[1] = py; fw[2] = pu; fw[3] = pv;
            pfrag[kb] = __builtin_bit_cast(bf16x8, fw);
        }

        const __hip_bfloat16* vb0 = &Vlds[buf][q31][0];
        const __hip_bfloat16* vb1 = &Vlds[buf][32 + q31][0];

        // ---- Z += P V (A=P row=q, B=V^T col=d) ----
        __builtin_amdgcn_s_setprio(1);
#pragma unroll
        for (int kb = 0; kb < 4; ++kb) {
            bf16x8 v0 = *(const bf16x8*)(vb0 + gsx[kb]);
            bf16x8 v1 = *(const bf16x8*)(vb1 + gsx[kb]);
            za0 = MFMA32(pfrag[kb], v0, za0);
            za1 = MFMA32(pfrag[kb], v1, za1);
        }
        __builtin_amdgcn_s_setprio(0);
    }

    // ---- epilogue ----
    float lt = l_ln + __shfl_xor(l_ln, 32);

    if (nc == 1) {
        // single-chunk row (qi<=1): normalize and write straight to Z
        if (hi == 0) als[w][q31] = 1.0f / lt;
        const int b = bh >> 3, h = bh & 7;
#pragma unroll
        for (int reg = 0; reg < 16; ++reg) {
            const int q = (reg & 3) + 8 * (reg >> 2) + 4 * hi;
            const float inv = als[w][q];
            __hip_bfloat16* zo =
                Z + ((size_t)b * 4096 + qi * 256 + w * 32 + q) * 512 + h * 64 + q31;
            zo[0]  = tobf(za0[reg] * inv);
            zo[32] = tobf(za1[reg] * inv);
        }
    } else {
        const int slot = bh * SLOTS_BH + slot_off(qi) + c;
        if (hi == 0) {
            ML[(size_t)slot * 512 +       w * 32 + q31] = m_s;
            ML[(size_t)slot * 512 + 256 + w * 32 + q31] = lt;
        }
#pragma unroll
        for (int reg = 0; reg < 16; ++reg) {
            const int q = (reg & 3) + 8 * (reg >> 2) + 4 * hi;
            const size_t base =
                (size_t)slot * 16384 + (size_t)(w * 32 + q) * 64 + q31;
            Zp[base]      = tobf(za0[reg]);
            Zp[base + 32] = tobf(za1[reg]);
        }
    }
}

// ---------------------------------------------------------------------------
// attn_combine: grid=(14 qi-2, 16 bh), 512 thr. q = tid>>1, half = tid&1.
// ---------------------------------------------------------------------------
__global__ __launch_bounds__(512) void attn_combine(
    const __hip_bfloat16* __restrict__ Zp,
    const float* __restrict__ ML,
    __hip_bfloat16* __restrict__ Z)    // [b][s][h*64]
{
    const int qi = blockIdx.x + 2;
    const int bh = blockIdx.y;
    const int nc = nchunks(qi);
    const int q    = threadIdx.x >> 1;
    const int half = threadIdx.x & 1;

    const int slot0 = bh * SLOTS_BH + slot_off(qi);

    float M = -3.0e38f;
    for (int i = 0; i < nc; ++i)
        M = fmaxf(M, ML[(size_t)(slot0 + i) * 512 + q]);

    float L = 0.0f;
    float acc[32];
#pragma unroll
    for (int j = 0; j < 32; ++j) acc[j] = 0.0f;

    for (int i = 0; i < nc; ++i) {
        const float wgt = exp2_raw(ML[(size_t)(slot0 + i) * 512 + q] - M);
        L += wgt * ML[(size_t)(slot0 + i) * 512 + 256 + q];
        const __hip_bfloat16* zp =
            Zp + (size_t)(slot0 + i) * 16384 + (size_t)q * 64 + half * 32;
#pragma unroll
        for (int v = 0; v < 4; ++v) {
            bf16x8 z = ld8(zp + v * 8);
#pragma unroll
            for (int j = 0; j < 8; ++j) acc[v * 8 + j] += wgt * (float)z[j];
        }
    }

    const float inv = 1.0f / L;
    const int b = bh >> 3, h = bh & 7;
    __hip_bfloat16* zo =
        Z + ((size_t)b * 4096 + qi * 256 + q) * 512 + h * 64 + half * 32;
#pragma unroll
    for (int v = 0; v < 4; ++v) {
        u16x8 o;
#pragma unroll
        for (int j = 0; j < 8; ++j)
            o[j] = __bfloat16_as_ushort(tobf(acc[v * 8 + j] * inv));
        *reinterpret_cast<u16x8*>(zo + v * 8) = o;
    }
}

// ---------------------------------------------------------------------------
// out_gemm: grid (64 mt, 4 ni), 512 thr. LDS-staged 128x128x64 GEMM.
// ---------------------------------------------------------------------------
__global__ __launch_bounds__(512) void out_gemm(
    const __hip_bfloat16* __restrict__ Zf,   // [8192][512]
    const __hip_bfloat16* __restrict__ Wo,   // [512][512] bf16
    float* __restrict__ out)                 // [8192][512] f32
{
    __shared__ __hip_bfloat16 Alds[2][128][64];
    __shared__ __hip_bfloat16 Blds[2][128][64];

    const int mt = blockIdx.x;       // 0..63
    const int ni = blockIdx.y;       // 0..3
    const int m0 = mt * 128;
    const int n0 = ni * 128;

    const int tid  = threadIdx.x;
    const int w    = tid >> 6;
    const int lane = tid & 63;
    const int q31  = lane & 31;
    const int hi   = lane >> 5;
    const int wm   = w >> 1;
    const int wn   = w & 1;

    const int r0l = w * 8 + (lane >> 3);
    const int cg  = (lane & 7) ^ (r0l & 7);
    const __hip_bfloat16* Asrc = Zf + (size_t)(m0 + r0l) * 512 + cg * 8;
    const __hip_bfloat16* Bsrc = Wo + (size_t)(n0 + r0l) * 512 + cg * 8;

    auto stage = [&](int buf, int k0) {
        gl_lds16(Asrc + k0,                    &Alds[buf][w * 8][0]);
        gl_lds16(Asrc + k0 + (size_t)64 * 512, &Alds[buf][w * 8 + 64][0]);
        gl_lds16(Bsrc + k0,                    &Blds[buf][w * 8][0]);
        gl_lds16(Bsrc + k0 + (size_t)64 * 512, &Blds[buf][w * 8 + 64][0]);
    };

    const int ra  = wm * 32 + q31;
    const int rb0 = wn * 64 + q31;
    const int rb1 = wn * 64 + 32 + q31;
    int gA[4], gB0[4], gB1[4];
#pragma unroll
    for (int ks = 0; ks < 4; ++ks) {
        gA[ks]  = SWZ(2 * ks + hi, ra)  * 8;
        gB0[ks] = SWZ(2 * ks + hi, rb0) * 8;
        gB1[ks] = SWZ(2 * ks + hi, rb1) * 8;
    }

    f32x16 ac0 = {}, ac1 = {};
    stage(0, 0);

    for (int it = 0; it < 8; ++it) {
        const int buf = it & 1;
        asm volatile("s_waitcnt vmcnt(0)" ::: "memory");
        __syncthreads();
        if (it < 7) stage(buf ^ 1, (it + 1) * 64);

        const __hip_bfloat16* xa  = &Alds[buf][ra][0];
        const __hip_bfloat16* wb0 = &Blds[buf][rb0][0];
        const __hip_bfloat16* wb1 = &Blds[buf][rb1][0];

        __builtin_amdgcn_s_setprio(1);
#pragma unroll
        for (int ks = 0; ks < 4; ++ks) {
            bf16x8 a  = *(const bf16x8*)(xa  + gA[ks]);
            bf16x8 b0 = *(const bf16x8*)(wb0 + gB0[ks]);
            bf16x8 b1 = *(const bf16x8*)(wb1 + gB1[ks]);
            ac0 = MFMA32(a, b0, ac0);
            ac1 = MFMA32(a, b1, ac1);
        }
        __builtin_amdgcn_s_setprio(0);
    }

    // ---- epilogue: f32, lanes = consecutive cols -> coalesced ----
    const int row0 = m0 + wm * 32;
    const int col0 = n0 + wn * 64;
#pragma unroll
    for (int reg = 0; reg < 16; ++reg) {
        const int r = row0 + (reg & 3) + 8 * (reg >> 2) + 4 * hi;
        out[(size_t)r * 512 + col0 + q31]      = ac0[reg];
        out[(size_t)r * 512 + col0 + 32 + q31] = ac1[reg];
    }
}

// ---------------------------------------------------------------------------
extern "C" void kernel_launch(void* const* d_in, const int* in_sizes, int n_in,
                              void* d_out, int out_size, void* d_ws, size_t ws_size,
                              hipStream_t stream)
{
    const float* x_f  = (const float*)d_in[0];
    const float* Wk_f = (const float*)d_in[1];
    const float* Wq_f = (const float*)d_in[2];
    const float* Wv_f = (const float*)d_in[3];
    const float* Wo_f = (const float*)d_in[4];
    float* out = (float*)d_out;

    char* ws = (char*)d_ws;
    const size_t szQKV = (size_t)16 * 4096 * 64 * sizeof(__hip_bfloat16);   // 8.39 MB
    const size_t szX   = (size_t)8192 * 512 * sizeof(__hip_bfloat16);       // 8.39 MB
    const size_t szW   = (size_t)8 * 64 * 512 * sizeof(__hip_bfloat16);     // 0.5 MB
    const size_t szZp  = (size_t)16 * SLOTS_BH * 256 * 64 * sizeof(__hip_bfloat16); // 37.7 MB
    const size_t szML  = (size_t)16 * SLOTS_BH * 512 * sizeof(float);       // 2.4 MB

    // persistent region
    size_t off = 0;
    __hip_bfloat16* Qb  = (__hip_bfloat16*)(ws + off); off += szQKV;
    __hip_bfloat16* Kb  = (__hip_bfloat16*)(ws + off); off += szQKV;
    __hip_bfloat16* Vt  = (__hip_bfloat16*)(ws + off); off += szQKV;
    __hip_bfloat16* Zb  = (__hip_bfloat16*)(ws + off); off += szX;
    __hip_bfloat16* Wob = (__hip_bfloat16*)(ws + off); off += szW;
    // transient region 1 (dead after qkv_gemm): xb + Wk/Wq/Wv casts
    const size_t trans = off;
    __hip_bfloat16* xb  = (__hip_bfloat16*)(ws + trans);
    __hip_bfloat16* Wkb = (__hip_bfloat16*)(ws + trans + szX);
    __hip_bfloat16* Wqb = (__hip_bfloat16*)(ws + trans + szX + szW);
    __hip_bfloat16* Wvb = (__hip_bfloat16*)(ws + trans + szX + 2 * szW);
    // transient region 2 (attention partials) ALIASES region 1
    __hip_bfloat16* Zp  = (__hip_bfloat16*)(ws + trans);
    float*          ML  = (float*)(ws + trans + szZp);

    cast_all<<<2048 + 4 * 128, 256, 0, stream>>>(
        x_f, Wk_f, Wq_f, Wv_f, Wo_f, xb, Wkb, Wqb, Wvb, Wob);

    qkv_gemm<<<dim3(64, 12),    512, 0, stream>>>(xb, Wkb, Wqb, Wvb, Qb, Kb, Vt);
    attn_part<<<dim3(1152),     512, 0, stream>>>(Qb, Kb, Vt, Zp, ML, Zb);
    attn_combine<<<dim3(14, 16), 512, 0, stream>>>(Zp, ML, Zb);
    out_gemm<<<dim3(64, 4),     512, 0, stream>>>(Zb, Wob, out);
}